// Round 2
// baseline (5454.584 us; speedup 1.0000x reference)
//
#include <hip/hip_runtime.h>
#include <float.h>
#include <math.h>

#define NPTS 4096
#define NBATCH 4
#define BN (NBATCH * NPTS)   // 16384
#define EPSC 1e-12f
#define JS 4                 // j-dimension splits for the distance kernels

__device__ __forceinline__ bool dless(float d1, int i1, float d2, int i2) {
  return (d1 < d2) || ((d1 == d2) && (i1 < i2));
}

// ---------------------------------------------------------------------------
// Kernel 1: fused MLP — e, logits, sq, nd.  512 blocks x 256 thr, 32 pts/block
// ---------------------------------------------------------------------------
__device__ __forceinline__ void gemm32x128(const float (*A)[64], const float* W,
                                           const float* bias, float (*O)[128], int tid) {
  const int pi = (tid >> 5) << 2;   // point quad
  const int ci = (tid & 31) << 2;   // col quad
  float acc[4][4] = {};
  for (int k0 = 0; k0 < 64; k0 += 4) {
    alignas(16) float av[4][4], wv[4][4];
#pragma unroll
    for (int r = 0; r < 4; ++r) *(float4*)av[r] = *(const float4*)&A[pi + r][k0];
#pragma unroll
    for (int kk = 0; kk < 4; ++kk) *(float4*)wv[kk] = *(const float4*)&W[(k0 + kk) * 128 + ci];
#pragma unroll
    for (int kk = 0; kk < 4; ++kk)
#pragma unroll
      for (int r = 0; r < 4; ++r)
#pragma unroll
        for (int c = 0; c < 4; ++c)
          acc[r][c] = fmaf(av[r][kk], wv[kk][c], acc[r][c]);
  }
#pragma unroll
  for (int r = 0; r < 4; ++r)
#pragma unroll
    for (int c = 0; c < 4; ++c)
      O[pi + r][ci + c] = fmaxf(acc[r][c] + bias[ci + c], 0.f);
}

__global__ __launch_bounds__(256) void mlp_kernel(
    const float* __restrict__ conf, const float* __restrict__ native,
    const float* __restrict__ We1, const float* __restrict__ be1,
    const float* __restrict__ We2, const float* __restrict__ be2,
    const float* __restrict__ We3, const float* __restrict__ be3,
    const float* __restrict__ Ws1, const float* __restrict__ bs1,
    const float* __restrict__ Ws2, const float* __restrict__ bs2,
    float* __restrict__ e_out, float* __restrict__ logits_out,
    float* __restrict__ sq_ws, float* __restrict__ nd_ws) {
  __shared__ __align__(16) float Wbuf[8192];       // 32 KB (We1 / We2 / Ws1)
  __shared__ __align__(16) float confs[32][64];    // 8 KB (later reused for h2)
  __shared__ __align__(16) float hbuf[32][128];    // 16 KB (g then h1)
  __shared__ float nat[64];
  __shared__ float b1s[128], b2s[64], w3s[64], bs1s[128], ws2s[768], bs2s[6];
  __shared__ float be3s;

  const int tid = threadIdx.x;
  const int blk = blockIdx.x;       // 0..511
  const int b = blk >> 7;           // 128 blocks per batch
  const int pbase = (blk & 127) * 32;
  const float* confb = conf + ((size_t)b * NPTS + pbase) * 64;

  for (int q = tid; q < 512; q += 256) {
    float4 v = *(const float4*)(confb + q * 4);
    *(float4*)&confs[q >> 4][(q & 15) << 2] = v;
  }
  if (tid < 64) nat[tid] = native[b * 64 + tid];
  if (tid < 128) b1s[tid] = be1[tid];
  if (tid < 64) b2s[tid] = be2[tid];
  if (tid < 64) w3s[tid] = We3[tid];
  if (tid < 128) bs1s[tid] = bs1[tid];
  for (int q = tid; q < 768; q += 256) ws2s[q] = Ws2[q];
  if (tid < 6) bs2s[tid] = bs2[tid];
  if (tid == 0) be3s = be3[0];
  for (int q = tid; q < 2048; q += 256)
    *(float4*)&Wbuf[q * 4] = *(const float4*)(Ws1 + q * 4);
  __syncthreads();

  // sq & nd — numpy-pairwise style: rounded products, 8 accumulators
  if (tid < 32) {
    float rs_[8], rn_[8];
#pragma unroll
    for (int u = 0; u < 8; ++u) {
      float c = confs[tid][u];
      rs_[u] = c * c;
      float d = c - nat[u];
      rn_[u] = d * d;
    }
    for (int d0 = 8; d0 < 64; d0 += 8) {
#pragma unroll
      for (int u = 0; u < 8; ++u) {
        float c = confs[tid][d0 + u];
        rs_[u] += c * c;
        float d = c - nat[d0 + u];
        rn_[u] += d * d;
      }
    }
    float s = ((rs_[0] + rs_[1]) + (rs_[2] + rs_[3])) + ((rs_[4] + rs_[5]) + (rs_[6] + rs_[7]));
    float n = ((rn_[0] + rn_[1]) + (rn_[2] + rn_[3])) + ((rn_[4] + rn_[5]) + (rn_[6] + rn_[7]));
    sq_ws[(size_t)b * NPTS + pbase + tid] = s;
    nd_ws[(size_t)b * NPTS + pbase + tid] = sqrtf(n);
  }

  gemm32x128(confs, Wbuf, bs1s, hbuf, tid);     // g = relu(conf @ Ws1 + bs1)
  __syncthreads();

  for (int q = tid; q < 2048; q += 256)         // reload Wbuf <- We1
    *(float4*)&Wbuf[q * 4] = *(const float4*)(We1 + q * 4);
  if (tid < 192) {
    int p = tid / 6, s = tid % 6;
    float acc = 0.f;
#pragma unroll 8
    for (int h = 0; h < 128; ++h)
      acc = fmaf(hbuf[p][h], ws2s[h * 6 + s], acc);
    logits_out[((size_t)b * NPTS + pbase + p) * 6 + s] = acc + bs2s[s];
  }
  __syncthreads();

  gemm32x128(confs, Wbuf, b1s, hbuf, tid);      // h1 = relu(conf @ We1 + be1)
  __syncthreads();

  for (int q = tid; q < 2048; q += 256)
    *(float4*)&Wbuf[q * 4] = *(const float4*)(We2 + q * 4);
  __syncthreads();

  // h2 = relu(h1 @ We2 + be2) -> confs
  if (tid < 128) {
    const int pi = (tid >> 4) << 2;
    const int ci = (tid & 15) << 2;
    float acc[4][4] = {};
    for (int k0 = 0; k0 < 128; k0 += 4) {
      alignas(16) float av[4][4], wv[4][4];
#pragma unroll
      for (int r = 0; r < 4; ++r) *(float4*)av[r] = *(const float4*)&hbuf[pi + r][k0];
#pragma unroll
      for (int kk = 0; kk < 4; ++kk) *(float4*)wv[kk] = *(const float4*)&Wbuf[(k0 + kk) * 64 + ci];
#pragma unroll
      for (int kk = 0; kk < 4; ++kk)
#pragma unroll
        for (int r = 0; r < 4; ++r)
#pragma unroll
          for (int c = 0; c < 4; ++c)
            acc[r][c] = fmaf(av[r][kk], wv[kk][c], acc[r][c]);
    }
#pragma unroll
    for (int r = 0; r < 4; ++r)
#pragma unroll
      for (int c = 0; c < 4; ++c)
        confs[pi + r][ci + c] = fmaxf(acc[r][c] + b2s[ci + c], 0.f);
  }
  __syncthreads();

  if (tid < 32) {                               // e = h2 @ We3 + be3
    float acc = 0.f;
#pragma unroll
    for (int k = 0; k < 64; ++k)
      acc = fmaf(confs[tid][k], w3s[k], acc);
    e_out[(size_t)b * NPTS + pbase + tid] = acc + be3s;
  }
}

// ---------------------------------------------------------------------------
// Distance pass 1 (split-j): per (64-row block, 1024-col chunk) top-10
// ---------------------------------------------------------------------------
#define TOP10_INSERT(d_, j_)                                                  \
  do {                                                                        \
    if (dless((d_), (j_), ld[9], li[9])) {                                    \
      float cd = (d_); int ci = (j_); bool placed = false;                    \
      _Pragma("unroll")                                                       \
      for (int k = 9; k >= 1; --k) {                                          \
        bool up = !placed && dless(cd, ci, ld[k - 1], li[k - 1]);             \
        bool here = !placed && !up;                                           \
        float pd = ld[k - 1]; int pi_ = li[k - 1];                            \
        if (up) { ld[k] = pd; li[k] = pi_; }                                  \
        if (here) { ld[k] = cd; li[k] = ci; placed = true; }                  \
      }                                                                       \
      if (!placed) { ld[0] = cd; li[0] = ci; }                                \
    }                                                                         \
  } while (0)

__global__ __launch_bounds__(256, 4) void topk_part_kernel(
    const float* __restrict__ conf, const float* __restrict__ sq_ws,
    float* __restrict__ topd, unsigned short* __restrict__ topi) {
  __shared__ __align__(16) float As[64][68];   // 17.4 KB (reused as mrgD)
  __shared__ __align__(16) float Bs[64][68];   // 17.4 KB (conf tile -> dist; reused as mrgI)
  __shared__ float sqa[64], sqjs[64];

  const int tid = threadIdx.x;
  const int b = blockIdx.z;
  const int i0 = blockIdx.x * 64;
  const int jbase = blockIdx.y * (NPTS / JS);
  const float* confb = conf + (size_t)b * NPTS * 64;
  const float* sqb = sq_ws + (size_t)b * NPTS;

  for (int q = tid; q < 1024; q += 256) {
    int row = q >> 4, k4 = (q & 15) << 2;
    *(float4*)&As[row][k4] = *(const float4*)(confb + (size_t)(i0 + row) * 64 + k4);
  }
  if (tid < 64) sqa[tid] = sqb[i0 + tid];

  const int tc = tid & 15, tr = tid >> 4;
  float ld[10];
  int li[10];
#pragma unroll
  for (int k = 0; k < 10; ++k) { ld[k] = FLT_MAX; li[k] = 0x7fffffff; }

  for (int jt = 0; jt < NPTS / JS / 64; ++jt) {   // 16 tiles of 64
    __syncthreads();   // As ready (jt=0) / previous tile fully consumed
    const int j0 = jbase + jt * 64;
    for (int q = tid; q < 1024; q += 256) {
      int row = q >> 4, k4 = (q & 15) << 2;
      *(float4*)&Bs[row][k4] = *(const float4*)(confb + (size_t)(j0 + row) * 64 + k4);
    }
    if (tid < 64) sqjs[tid] = sqb[j0 + tid];
    __syncthreads();

    float acc[4][4] = {};
    for (int k0 = 0; k0 < 64; k0 += 4) {
      alignas(16) float av[4][4], bv[4][4];
#pragma unroll
      for (int r = 0; r < 4; ++r) *(float4*)av[r] = *(const float4*)&As[tr + 16 * r][k0];
#pragma unroll
      for (int c = 0; c < 4; ++c) *(float4*)bv[c] = *(const float4*)&Bs[tc + 16 * c][k0];
#pragma unroll
      for (int kk = 0; kk < 4; ++kk)
#pragma unroll
        for (int r = 0; r < 4; ++r)
#pragma unroll
          for (int c = 0; c < 4; ++c)
            acc[r][c] = fmaf(av[r][kk], bv[c][kk], acc[r][c]);
    }
    __syncthreads();  // everyone done reading Bs(conf)
#pragma unroll
    for (int r = 0; r < 4; ++r)
#pragma unroll
      for (int c = 0; c < 4; ++c) {
        int row = tr + 16 * r, col = tc + 16 * c;
        float d2 = sqa[row] + sqjs[col] - 2.f * acc[r][c];
        Bs[row][col] = sqrtf(fmaxf(d2, EPSC));
      }
    __syncthreads();
    {
      const int row = tid >> 2, q4 = tid & 3;
#pragma unroll
      for (int cc = 0; cc < 4; ++cc) {
        float4 v = *(const float4*)&Bs[row][q4 * 16 + cc * 4];
        const int jb = j0 + q4 * 16 + cc * 4;
        TOP10_INSERT(v.x, jb + 0);
        TOP10_INSERT(v.y, jb + 1);
        TOP10_INSERT(v.z, jb + 2);
        TOP10_INSERT(v.w, jb + 3);
      }
    }
  }
  __syncthreads();

  // merge 4 per-thread sorted lists per row -> chunk top-10, write to ws
  float* mrgD = &As[0][0];       // 64*40 floats
  int* mrgI = (int*)&Bs[0][0];   // 64*40 ints
  {
    const int row = tid >> 2, q4 = tid & 3;
#pragma unroll
    for (int k = 0; k < 10; ++k) {
      mrgD[row * 40 + q4 * 10 + k] = ld[k];
      mrgI[row * 40 + q4 * 10 + k] = li[k];
    }
  }
  __syncthreads();
  if (tid < 64) {
    const int base = tid * 40;
    int h0 = 0, h1 = 0, h2 = 0, h3 = 0;
    const size_t obase = (((size_t)b * NPTS + i0 + tid) * JS + blockIdx.y) * 10;
    for (int k = 0; k < 10; ++k) {
      float bd = FLT_MAX; int bi = 0x7fffffff; int bl = -1;
      { float d = mrgD[base + h0];      int ii = mrgI[base + h0];      if (dless(d, ii, bd, bi)) { bd = d; bi = ii; bl = 0; } }
      { float d = mrgD[base + 10 + h1]; int ii = mrgI[base + 10 + h1]; if (dless(d, ii, bd, bi)) { bd = d; bi = ii; bl = 1; } }
      { float d = mrgD[base + 20 + h2]; int ii = mrgI[base + 20 + h2]; if (dless(d, ii, bd, bi)) { bd = d; bi = ii; bl = 2; } }
      { float d = mrgD[base + 30 + h3]; int ii = mrgI[base + 30 + h3]; if (dless(d, ii, bd, bi)) { bd = d; bi = ii; bl = 3; } }
      h0 += (bl == 0); h1 += (bl == 1); h2 += (bl == 2); h3 += (bl == 3);
      topd[obase + k] = bd;
      topi[obase + k] = (unsigned short)bi;
    }
  }
}

// ---------------------------------------------------------------------------
// Merge JS chunk top-10s per row -> r, is_basin
// ---------------------------------------------------------------------------
__global__ __launch_bounds__(256) void topk_merge_kernel(
    const float* __restrict__ topd, const unsigned short* __restrict__ topi,
    const float* __restrict__ e_in, float* __restrict__ basin_out,
    float* __restrict__ rs_ws) {
  const int g = blockIdx.x * 256 + threadIdx.x;   // 0..16383
  const int b = g >> 12;
  const float* eb = e_in + (size_t)b * NPTS;
  const float* td = topd + (size_t)g * (JS * 10);
  const unsigned short* ti = topi + (size_t)g * (JS * 10);
  const float e_i = eb[g & (NPTS - 1)];
  int h0 = 0, h1 = 0, h2 = 0, h3 = 0;
  bool basin = true;
  float rr = 0.f;
  for (int k = 0; k < 10; ++k) {
    float bd = FLT_MAX; int bi = 0x7fffffff; int bl = -1;
    { float d = td[h0];      int ii = ti[h0];      if (dless(d, ii, bd, bi)) { bd = d; bi = ii; bl = 0; } }
    { float d = td[10 + h1]; int ii = ti[10 + h1]; if (dless(d, ii, bd, bi)) { bd = d; bi = ii; bl = 1; } }
    { float d = td[20 + h2]; int ii = ti[20 + h2]; if (dless(d, ii, bd, bi)) { bd = d; bi = ii; bl = 2; } }
    { float d = td[30 + h3]; int ii = ti[30 + h3]; if (dless(d, ii, bd, bi)) { bd = d; bi = ii; bl = 3; } }
    h0 += (bl == 0); h1 += (bl == 1); h2 += (bl == 2); h3 += (bl == 3);
    rr = bd;
    if (k >= 1) basin = basin && (e_i <= eb[bi]);
  }
  rs_ws[g] = rr;
  basin_out[g] = basin ? 1.f : 0.f;
}

// ---------------------------------------------------------------------------
// Distance pass 2 (split-j): partial masked reductions per chunk
// ---------------------------------------------------------------------------
__global__ __launch_bounds__(256, 4) void mask_part_kernel(
    const float* __restrict__ conf, const float* __restrict__ sq_ws,
    const float* __restrict__ e_in, const float* __restrict__ rs_ws,
    float* __restrict__ pmax, float* __restrict__ psum, float* __restrict__ pcnt) {
  __shared__ __align__(16) float As[64][68];
  __shared__ __align__(16) float Bs[64][68];
  __shared__ float sqa[64], sqjs[64], ejs[64], rsh[64];

  const int tid = threadIdx.x;
  const int b = blockIdx.z;
  const int i0 = blockIdx.x * 64;
  const int jbase = blockIdx.y * (NPTS / JS);
  const float* confb = conf + (size_t)b * NPTS * 64;
  const float* sqb = sq_ws + (size_t)b * NPTS;
  const float* eb = e_in + (size_t)b * NPTS;

  for (int q = tid; q < 1024; q += 256) {
    int row = q >> 4, k4 = (q & 15) << 2;
    *(float4*)&As[row][k4] = *(const float4*)(confb + (size_t)(i0 + row) * 64 + k4);
  }
  if (tid < 64) {
    sqa[tid] = sqb[i0 + tid];
    rsh[tid] = rs_ws[(size_t)b * NPTS + i0 + tid];
  }
  __syncthreads();

  const int tc = tid & 15, tr = tid >> 4;
  float rsl[4];
#pragma unroll
  for (int r = 0; r < 4; ++r) rsl[r] = rsh[tr + 16 * r];

  float mxe[4], sd[4];
  int cnt[4];
#pragma unroll
  for (int r = 0; r < 4; ++r) { mxe[r] = -FLT_MAX; sd[r] = 0.f; cnt[r] = 0; }

  for (int jt = 0; jt < NPTS / JS / 64; ++jt) {
    const int j0 = jbase + jt * 64;
    for (int q = tid; q < 1024; q += 256) {
      int row = q >> 4, k4 = (q & 15) << 2;
      *(float4*)&Bs[row][k4] = *(const float4*)(confb + (size_t)(j0 + row) * 64 + k4);
    }
    if (tid < 64) { sqjs[tid] = sqb[j0 + tid]; ejs[tid] = eb[j0 + tid]; }
    __syncthreads();

    float acc[4][4] = {};
    for (int k0 = 0; k0 < 64; k0 += 4) {
      alignas(16) float av[4][4], bv[4][4];
#pragma unroll
      for (int r = 0; r < 4; ++r) *(float4*)av[r] = *(const float4*)&As[tr + 16 * r][k0];
#pragma unroll
      for (int c = 0; c < 4; ++c) *(float4*)bv[c] = *(const float4*)&Bs[tc + 16 * c][k0];
#pragma unroll
      for (int kk = 0; kk < 4; ++kk)
#pragma unroll
        for (int r = 0; r < 4; ++r)
#pragma unroll
          for (int c = 0; c < 4; ++c)
            acc[r][c] = fmaf(av[r][kk], bv[c][kk], acc[r][c]);
    }
#pragma unroll
    for (int r = 0; r < 4; ++r)
#pragma unroll
      for (int c = 0; c < 4; ++c) {
        int row = tr + 16 * r, col = tc + 16 * c;
        float d2 = sqa[row] + sqjs[col] - 2.f * acc[r][c];
        float d = sqrtf(fmaxf(d2, EPSC));
        if (d < rsl[r]) {
          mxe[r] = fmaxf(mxe[r], ejs[col]);
          sd[r] += d;
          cnt[r] += 1;
        }
      }
    __syncthreads();   // Bs/sqjs/ejs consumed; next stage safe
  }

  // 16 threads (tc) share each row and are consecutive lanes: shfl-reduce
#pragma unroll
  for (int r = 0; r < 4; ++r) {
    float m = mxe[r], s = sd[r], c = (float)cnt[r];
#pragma unroll
    for (int off = 8; off >= 1; off >>= 1) {
      m = fmaxf(m, __shfl_xor(m, off, 16));
      s += __shfl_xor(s, off, 16);
      c += __shfl_xor(c, off, 16);
    }
    if (tc == 0) {
      const size_t o = ((size_t)b * NPTS + i0 + tr + 16 * r) * JS + blockIdx.y;
      pmax[o] = m;
      psum[o] = s;
      pcnt[o] = c;
    }
  }
}

__global__ __launch_bounds__(256) void finalize_kernel(
    const float* __restrict__ pmax, const float* __restrict__ psum,
    const float* __restrict__ pcnt, const float* __restrict__ e_in,
    float* __restrict__ depth_out, float* __restrict__ width_out) {
  const int g = blockIdx.x * 256 + threadIdx.x;
  float m = -FLT_MAX, s = 0.f, c = 0.f;
#pragma unroll
  for (int j = 0; j < JS; ++j) {
    m = fmaxf(m, pmax[(size_t)g * JS + j]);
    s += psum[(size_t)g * JS + j];
    c += pcnt[(size_t)g * JS + j];
  }
  depth_out[g] = m - e_in[g];
  width_out[g] = s / c;
}

// ---------------------------------------------------------------------------
// Kernel 3: rank by nd (stable), scatter e into sorted order
// ---------------------------------------------------------------------------
__global__ __launch_bounds__(256) void rank_kernel(
    const float* __restrict__ nd_ws, const float* __restrict__ e_in,
    float* __restrict__ se_ws) {
  __shared__ __align__(16) float ndl[4096];
  const int tid = threadIdx.x;
  const int b = blockIdx.y;
  const int i0 = blockIdx.x * 256;
  const float* ndb = nd_ws + (size_t)b * NPTS;
  for (int q = tid; q < 1024; q += 256)
    *(float4*)&ndl[q * 4] = *(const float4*)(ndb + q * 4);
  __syncthreads();
  const int i = i0 + tid;
  const float ndi = ndl[i];
  int rank = 0;
  for (int j = 0; j < 4096; j += 4) {
    float4 v = *(const float4*)&ndl[j];
    rank += (v.x < ndi) || (v.x == ndi && (j + 0) < i);
    rank += (v.y < ndi) || (v.y == ndi && (j + 1) < i);
    rank += (v.z < ndi) || (v.z == ndi && (j + 2) < i);
    rank += (v.w < ndi) || (v.w == ndi && (j + 3) < i);
  }
  se_ws[(size_t)b * NPTS + rank] = e_in[(size_t)b * NPTS + i];
}

// ---------------------------------------------------------------------------
// Kernel 4: per-batch scalar metrics
// ---------------------------------------------------------------------------
__device__ __forceinline__ float block_sum(float v, float* red, int tid) {
  red[tid] = v;
  __syncthreads();
  for (int s = 512; s > 0; s >>= 1) {
    if (tid < s) red[tid] += red[tid + s];
    __syncthreads();
  }
  float r = red[0];
  __syncthreads();
  return r;
}
__device__ __forceinline__ float block_max(float v, float* red, int tid) {
  red[tid] = v;
  __syncthreads();
  for (int s = 512; s > 0; s >>= 1) {
    if (tid < s) red[tid] = fmaxf(red[tid], red[tid + s]);
    __syncthreads();
  }
  float r = red[0];
  __syncthreads();
  return r;
}

__global__ __launch_bounds__(1024) void metrics_kernel(
    const float* __restrict__ e_in, const float* __restrict__ nd_ws,
    const float* __restrict__ se_ws, float* __restrict__ metrics_out) {
  __shared__ __align__(16) float el[4096], ndl[4096], sel[4096];
  __shared__ float red[1024];
  __shared__ int redi[1024];
  const int tid = threadIdx.x;
  const int b = blockIdx.x;
  const float* eb = e_in + (size_t)b * NPTS;
  const float* ndb = nd_ws + (size_t)b * NPTS;
  const float* seb = se_ws + (size_t)b * NPTS;
  *(float4*)&el[tid * 4] = *(const float4*)(eb + tid * 4);
  *(float4*)&ndl[tid * 4] = *(const float4*)(ndb + tid * 4);
  *(float4*)&sel[tid * 4] = *(const float4*)(seb + tid * 4);
  __syncthreads();

  float pe = 0.f, pnd = 0.f;
  for (int p = tid; p < 4096; p += 1024) { pe += el[p]; pnd += ndl[p]; }
  float me = block_sum(pe, red, tid) / 4096.f;
  float mnd = block_sum(pnd, red, tid) / 4096.f;

  float sxx = 0.f, syy = 0.f, sxy = 0.f, mx = -FLT_MAX;
  float bestv = FLT_MAX;
  int besti = 0x7fffffff;
  for (int p = tid; p < 4096; p += 1024) {
    float de = el[p] - me, dn = ndl[p] - mnd;
    syy += de * de;
    sxx += dn * dn;
    sxy += de * dn;
    mx = fmaxf(mx, el[p]);
    if (ndl[p] < bestv || (ndl[p] == bestv && p < besti)) { bestv = ndl[p]; besti = p; }
  }
  float fr = 0.f;
  for (int p = tid; p < 4095; p += 1024) fr += (sel[p + 1] > sel[p]) ? 1.f : 0.f;

  sxx = block_sum(sxx, red, tid);
  syy = block_sum(syy, red, tid);
  sxy = block_sum(sxy, red, tid);
  mx = block_max(mx, red, tid);
  fr = block_sum(fr, red, tid);

  red[tid] = bestv;
  redi[tid] = besti;
  __syncthreads();
  for (int s = 512; s > 0; s >>= 1) {
    if (tid < s) {
      float ov = red[tid + s];
      int oi = redi[tid + s];
      if (ov < red[tid] || (ov == red[tid] && oi < redi[tid])) { red[tid] = ov; redi[tid] = oi; }
    }
    __syncthreads();
  }
  if (tid == 0) {
    float ne = el[redi[0]];
    metrics_out[b * 5 + 0] = mx - ne;
    metrics_out[b * 5 + 1] = sqrtf(syy / 4095.f);
    metrics_out[b * 5 + 2] = sxy / sqrtf(sxx * syy);
    metrics_out[b * 5 + 3] = fr / 4095.f;
    metrics_out[b * 5 + 4] = ne;
  }
}

// ---------------------------------------------------------------------------
extern "C" void kernel_launch(void* const* d_in, const int* in_sizes, int n_in,
                              void* d_out, int out_size, void* d_ws, size_t ws_size,
                              hipStream_t stream) {
  const float* conf = (const float*)d_in[0];
  const float* native = (const float*)d_in[1];
  const float* We1 = (const float*)d_in[2];
  const float* be1 = (const float*)d_in[3];
  const float* We2 = (const float*)d_in[4];
  const float* be2 = (const float*)d_in[5];
  const float* We3 = (const float*)d_in[6];
  const float* be3 = (const float*)d_in[7];
  const float* Ws1 = (const float*)d_in[8];
  const float* bs1 = (const float*)d_in[9];
  const float* Ws2 = (const float*)d_in[10];
  const float* bs2 = (const float*)d_in[11];

  float* out = (float*)d_out;
  float* e_out = out;                 // [0, 16384)
  float* basin_out = out + BN;        // [16384, 32768)
  float* depth_out = out + 2 * BN;    // [32768, 49152)
  float* width_out = out + 3 * BN;    // [49152, 65536)
  float* logits_out = out + 4 * BN;   // [65536, 163840)
  float* metrics_out = out + 10 * BN; // [163840, 163860)

  // ws layout (floats): sq | nd | se | rs | pmax(4BN) | psum(4BN) | pcnt(4BN)
  //                     | topd(40BN) | topi(40BN ushort = 20BN floats)  = 76*BN floats ≈ 5 MB
  float* wsf = (float*)d_ws;
  float* sq_ws = wsf;
  float* nd_ws = wsf + BN;
  float* se_ws = wsf + 2 * (size_t)BN;
  float* rs_ws = wsf + 3 * (size_t)BN;
  float* pmax = wsf + 4 * (size_t)BN;
  float* psum = wsf + 8 * (size_t)BN;
  float* pcnt = wsf + 12 * (size_t)BN;
  float* topd = wsf + 16 * (size_t)BN;
  unsigned short* topi = (unsigned short*)(wsf + 56 * (size_t)BN);

  mlp_kernel<<<dim3(512), dim3(256), 0, stream>>>(
      conf, native, We1, be1, We2, be2, We3, be3, Ws1, bs1, Ws2, bs2,
      e_out, logits_out, sq_ws, nd_ws);
  topk_part_kernel<<<dim3(64, JS, NBATCH), dim3(256), 0, stream>>>(
      conf, sq_ws, topd, topi);
  topk_merge_kernel<<<dim3(BN / 256), dim3(256), 0, stream>>>(
      topd, topi, e_out, basin_out, rs_ws);
  mask_part_kernel<<<dim3(64, JS, NBATCH), dim3(256), 0, stream>>>(
      conf, sq_ws, e_out, rs_ws, pmax, psum, pcnt);
  finalize_kernel<<<dim3(BN / 256), dim3(256), 0, stream>>>(
      pmax, psum, pcnt, e_out, depth_out, width_out);
  rank_kernel<<<dim3(16, NBATCH), dim3(256), 0, stream>>>(nd_ws, e_out, se_ws);
  metrics_kernel<<<dim3(NBATCH), dim3(1024), 0, stream>>>(e_out, nd_ws, se_ws, metrics_out);
}

// Round 3
// 3566.164 us; speedup vs baseline: 1.5295x; 1.5295x over previous
//
#include <hip/hip_runtime.h>
#include <float.h>
#include <math.h>

#define NPTS 4096
#define NBATCH 4
#define BN (NBATCH * NPTS)   // 16384
#define EPSC 1e-12f
#define JS 4                 // j-dimension splits for the distance kernels

__device__ __forceinline__ bool dless(float d1, int i1, float d2, int i2) {
  return (d1 < d2) || ((d1 == d2) && (i1 < i2));
}

// ---------------------------------------------------------------------------
// Kernel 1: fused MLP — e, logits, sq, nd.  512 blocks x 256 thr, 32 pts/block
// ---------------------------------------------------------------------------
__device__ __forceinline__ void gemm32x128(const float (*A)[64], const float* W,
                                           const float* bias, float (*O)[128], int tid) {
  const int pi = (tid >> 5) << 2;   // point quad
  const int ci = (tid & 31) << 2;   // col quad
  float acc[4][4] = {};
  for (int k0 = 0; k0 < 64; k0 += 4) {
    alignas(16) float av[4][4], wv[4][4];
#pragma unroll
    for (int r = 0; r < 4; ++r) *(float4*)av[r] = *(const float4*)&A[pi + r][k0];
#pragma unroll
    for (int kk = 0; kk < 4; ++kk) *(float4*)wv[kk] = *(const float4*)&W[(k0 + kk) * 128 + ci];
#pragma unroll
    for (int kk = 0; kk < 4; ++kk)
#pragma unroll
      for (int r = 0; r < 4; ++r)
#pragma unroll
        for (int c = 0; c < 4; ++c)
          acc[r][c] = fmaf(av[r][kk], wv[kk][c], acc[r][c]);
  }
#pragma unroll
  for (int r = 0; r < 4; ++r)
#pragma unroll
    for (int c = 0; c < 4; ++c)
      O[pi + r][ci + c] = fmaxf(acc[r][c] + bias[ci + c], 0.f);
}

__global__ __launch_bounds__(256) void mlp_kernel(
    const float* __restrict__ conf, const float* __restrict__ native,
    const float* __restrict__ We1, const float* __restrict__ be1,
    const float* __restrict__ We2, const float* __restrict__ be2,
    const float* __restrict__ We3, const float* __restrict__ be3,
    const float* __restrict__ Ws1, const float* __restrict__ bs1,
    const float* __restrict__ Ws2, const float* __restrict__ bs2,
    float* __restrict__ e_out, float* __restrict__ logits_out,
    float* __restrict__ sq_ws, float* __restrict__ nd_ws) {
  __shared__ __align__(16) float Wbuf[8192];       // 32 KB (We1 / We2 / Ws1)
  __shared__ __align__(16) float confs[32][64];    // 8 KB (later reused for h2)
  __shared__ __align__(16) float hbuf[32][128];    // 16 KB (g then h1)
  __shared__ float nat[64];
  __shared__ float b1s[128], b2s[64], w3s[64], bs1s[128], ws2s[768], bs2s[6];
  __shared__ float be3s;

  const int tid = threadIdx.x;
  const int blk = blockIdx.x;       // 0..511
  const int b = blk >> 7;           // 128 blocks per batch
  const int pbase = (blk & 127) * 32;
  const float* confb = conf + ((size_t)b * NPTS + pbase) * 64;

  for (int q = tid; q < 512; q += 256) {
    float4 v = *(const float4*)(confb + q * 4);
    *(float4*)&confs[q >> 4][(q & 15) << 2] = v;
  }
  if (tid < 64) nat[tid] = native[b * 64 + tid];
  if (tid < 128) b1s[tid] = be1[tid];
  if (tid < 64) b2s[tid] = be2[tid];
  if (tid < 64) w3s[tid] = We3[tid];
  if (tid < 128) bs1s[tid] = bs1[tid];
  for (int q = tid; q < 768; q += 256) ws2s[q] = Ws2[q];
  if (tid < 6) bs2s[tid] = bs2[tid];
  if (tid == 0) be3s = be3[0];
  for (int q = tid; q < 2048; q += 256)
    *(float4*)&Wbuf[q * 4] = *(const float4*)(Ws1 + q * 4);
  __syncthreads();

  // sq & nd — numpy-pairwise style: rounded products, 8 accumulators
  if (tid < 32) {
    float rs_[8], rn_[8];
#pragma unroll
    for (int u = 0; u < 8; ++u) {
      float c = confs[tid][u];
      rs_[u] = c * c;
      float d = c - nat[u];
      rn_[u] = d * d;
    }
    for (int d0 = 8; d0 < 64; d0 += 8) {
#pragma unroll
      for (int u = 0; u < 8; ++u) {
        float c = confs[tid][d0 + u];
        rs_[u] += c * c;
        float d = c - nat[d0 + u];
        rn_[u] += d * d;
      }
    }
    float s = ((rs_[0] + rs_[1]) + (rs_[2] + rs_[3])) + ((rs_[4] + rs_[5]) + (rs_[6] + rs_[7]));
    float n = ((rn_[0] + rn_[1]) + (rn_[2] + rn_[3])) + ((rn_[4] + rn_[5]) + (rn_[6] + rn_[7]));
    sq_ws[(size_t)b * NPTS + pbase + tid] = s;
    nd_ws[(size_t)b * NPTS + pbase + tid] = sqrtf(n);
  }

  gemm32x128(confs, Wbuf, bs1s, hbuf, tid);     // g = relu(conf @ Ws1 + bs1)
  __syncthreads();

  for (int q = tid; q < 2048; q += 256)         // reload Wbuf <- We1
    *(float4*)&Wbuf[q * 4] = *(const float4*)(We1 + q * 4);
  if (tid < 192) {
    int p = tid / 6, s = tid % 6;
    float acc = 0.f;
#pragma unroll 8
    for (int h = 0; h < 128; ++h)
      acc = fmaf(hbuf[p][h], ws2s[h * 6 + s], acc);
    logits_out[((size_t)b * NPTS + pbase + p) * 6 + s] = acc + bs2s[s];
  }
  __syncthreads();

  gemm32x128(confs, Wbuf, b1s, hbuf, tid);      // h1 = relu(conf @ We1 + be1)
  __syncthreads();

  for (int q = tid; q < 2048; q += 256)
    *(float4*)&Wbuf[q * 4] = *(const float4*)(We2 + q * 4);
  __syncthreads();

  // h2 = relu(h1 @ We2 + be2) -> confs
  if (tid < 128) {
    const int pi = (tid >> 4) << 2;
    const int ci = (tid & 15) << 2;
    float acc[4][4] = {};
    for (int k0 = 0; k0 < 128; k0 += 4) {
      alignas(16) float av[4][4], wv[4][4];
#pragma unroll
      for (int r = 0; r < 4; ++r) *(float4*)av[r] = *(const float4*)&hbuf[pi + r][k0];
#pragma unroll
      for (int kk = 0; kk < 4; ++kk) *(float4*)wv[kk] = *(const float4*)&Wbuf[(k0 + kk) * 64 + ci];
#pragma unroll
      for (int kk = 0; kk < 4; ++kk)
#pragma unroll
        for (int r = 0; r < 4; ++r)
#pragma unroll
          for (int c = 0; c < 4; ++c)
            acc[r][c] = fmaf(av[r][kk], wv[kk][c], acc[r][c]);
    }
#pragma unroll
    for (int r = 0; r < 4; ++r)
#pragma unroll
      for (int c = 0; c < 4; ++c)
        confs[pi + r][ci + c] = fmaxf(acc[r][c] + b2s[ci + c], 0.f);
  }
  __syncthreads();

  if (tid < 32) {                               // e = h2 @ We3 + be3
    float acc = 0.f;
#pragma unroll
    for (int k = 0; k < 64; ++k)
      acc = fmaf(confs[tid][k], w3s[k], acc);
    e_out[(size_t)b * NPTS + pbase + tid] = acc + be3s;
  }
}

// ---------------------------------------------------------------------------
// Distance pass 1 (split-j): per (64-row block, 1024-col chunk) top-10
// launch_bounds(256,2): empirically arg N -> VGPR cap 512/(2N); N=2 -> 128.
// ---------------------------------------------------------------------------
#define TOP10_INSERT(d_, j_)                                                  \
  do {                                                                        \
    if (dless((d_), (j_), ld[9], li[9])) {                                    \
      float cd = (d_); int ci = (j_); bool placed = false;                    \
      _Pragma("unroll")                                                       \
      for (int k = 9; k >= 1; --k) {                                          \
        bool up = !placed && dless(cd, ci, ld[k - 1], li[k - 1]);             \
        bool here = !placed && !up;                                           \
        float pd = ld[k - 1]; int pi_ = li[k - 1];                            \
        if (up) { ld[k] = pd; li[k] = pi_; }                                  \
        if (here) { ld[k] = cd; li[k] = ci; placed = true; }                  \
      }                                                                       \
      if (!placed) { ld[0] = cd; li[0] = ci; }                                \
    }                                                                         \
  } while (0)

// micro-GEMM: 4x4 outputs, av staged 16 regs, bv staged 4 regs per column.
// fmaf order (k0 asc, kk asc) identical across all kernels -> bit-identical d.
#define DIST_GEMM(ACC)                                                        \
  do {                                                                        \
    for (int k0 = 0; k0 < 64; k0 += 4) {                                      \
      alignas(16) float av[4][4];                                             \
      _Pragma("unroll")                                                       \
      for (int r = 0; r < 4; ++r)                                             \
        *(float4*)av[r] = *(const float4*)&As[tr + 16 * r][k0];               \
      _Pragma("unroll")                                                       \
      for (int c = 0; c < 4; ++c) {                                           \
        alignas(16) float bv[4];                                              \
        *(float4*)bv = *(const float4*)&Bs[tc + 16 * c][k0];                  \
        _Pragma("unroll")                                                     \
        for (int kk = 0; kk < 4; ++kk)                                        \
          _Pragma("unroll")                                                   \
          for (int r = 0; r < 4; ++r)                                         \
            ACC[r][c] = fmaf(av[r][kk], bv[kk], ACC[r][c]);                   \
      }                                                                       \
    }                                                                         \
  } while (0)

__global__ __launch_bounds__(256, 2) void topk_part_kernel(
    const float* __restrict__ conf, const float* __restrict__ sq_ws,
    float* __restrict__ topd, unsigned short* __restrict__ topi) {
  __shared__ __align__(16) float As[64][68];   // 17.4 KB (reused as mrgD)
  __shared__ __align__(16) float Bs[64][68];   // 17.4 KB (conf tile -> dist; reused as mrgI)
  __shared__ float sqa[64], sqjs[64];

  const int tid = threadIdx.x;
  const int b = blockIdx.z;
  const int i0 = blockIdx.x * 64;
  const int jbase = blockIdx.y * (NPTS / JS);
  const float* confb = conf + (size_t)b * NPTS * 64;
  const float* sqb = sq_ws + (size_t)b * NPTS;

  for (int q = tid; q < 1024; q += 256) {
    int row = q >> 4, k4 = (q & 15) << 2;
    *(float4*)&As[row][k4] = *(const float4*)(confb + (size_t)(i0 + row) * 64 + k4);
  }
  if (tid < 64) sqa[tid] = sqb[i0 + tid];

  const int tc = tid & 15, tr = tid >> 4;
  float ld[10];
  int li[10];
#pragma unroll
  for (int k = 0; k < 10; ++k) { ld[k] = FLT_MAX; li[k] = 0x7fffffff; }

  for (int jt = 0; jt < NPTS / JS / 64; ++jt) {   // 16 tiles of 64
    __syncthreads();   // As ready (jt=0) / previous tile fully consumed
    const int j0 = jbase + jt * 64;
    for (int q = tid; q < 1024; q += 256) {
      int row = q >> 4, k4 = (q & 15) << 2;
      *(float4*)&Bs[row][k4] = *(const float4*)(confb + (size_t)(j0 + row) * 64 + k4);
    }
    if (tid < 64) sqjs[tid] = sqb[j0 + tid];
    __syncthreads();

    float acc[4][4] = {};
    DIST_GEMM(acc);
    __syncthreads();  // everyone done reading Bs(conf)
#pragma unroll
    for (int r = 0; r < 4; ++r)
#pragma unroll
      for (int c = 0; c < 4; ++c) {
        int row = tr + 16 * r, col = tc + 16 * c;
        float d2 = sqa[row] + sqjs[col] - 2.f * acc[r][c];
        Bs[row][col] = sqrtf(fmaxf(d2, EPSC));
      }
    __syncthreads();
    {
      const int row = tid >> 2, q4 = tid & 3;
#pragma unroll
      for (int cc = 0; cc < 4; ++cc) {
        float4 v = *(const float4*)&Bs[row][q4 * 16 + cc * 4];
        const int jb = j0 + q4 * 16 + cc * 4;
        TOP10_INSERT(v.x, jb + 0);
        TOP10_INSERT(v.y, jb + 1);
        TOP10_INSERT(v.z, jb + 2);
        TOP10_INSERT(v.w, jb + 3);
      }
    }
  }
  __syncthreads();

  // merge 4 per-thread sorted lists per row -> chunk top-10, write to ws
  float* mrgD = &As[0][0];       // 64*40 floats
  int* mrgI = (int*)&Bs[0][0];   // 64*40 ints
  {
    const int row = tid >> 2, q4 = tid & 3;
#pragma unroll
    for (int k = 0; k < 10; ++k) {
      mrgD[row * 40 + q4 * 10 + k] = ld[k];
      mrgI[row * 40 + q4 * 10 + k] = li[k];
    }
  }
  __syncthreads();
  if (tid < 64) {
    const int base = tid * 40;
    int h0 = 0, h1 = 0, h2 = 0, h3 = 0;
    const size_t obase = (((size_t)b * NPTS + i0 + tid) * JS + blockIdx.y) * 10;
    for (int k = 0; k < 10; ++k) {
      float bd = FLT_MAX; int bi = 0x7fffffff; int bl = -1;
      { float d = mrgD[base + h0];      int ii = mrgI[base + h0];      if (dless(d, ii, bd, bi)) { bd = d; bi = ii; bl = 0; } }
      { float d = mrgD[base + 10 + h1]; int ii = mrgI[base + 10 + h1]; if (dless(d, ii, bd, bi)) { bd = d; bi = ii; bl = 1; } }
      { float d = mrgD[base + 20 + h2]; int ii = mrgI[base + 20 + h2]; if (dless(d, ii, bd, bi)) { bd = d; bi = ii; bl = 2; } }
      { float d = mrgD[base + 30 + h3]; int ii = mrgI[base + 30 + h3]; if (dless(d, ii, bd, bi)) { bd = d; bi = ii; bl = 3; } }
      h0 += (bl == 0); h1 += (bl == 1); h2 += (bl == 2); h3 += (bl == 3);
      topd[obase + k] = bd;
      topi[obase + k] = (unsigned short)bi;
    }
  }
}

// ---------------------------------------------------------------------------
// Merge JS chunk top-10s per row -> r, is_basin
// ---------------------------------------------------------------------------
__global__ __launch_bounds__(256) void topk_merge_kernel(
    const float* __restrict__ topd, const unsigned short* __restrict__ topi,
    const float* __restrict__ e_in, float* __restrict__ basin_out,
    float* __restrict__ rs_ws) {
  const int g = blockIdx.x * 256 + threadIdx.x;   // 0..16383
  const int b = g >> 12;
  const float* eb = e_in + (size_t)b * NPTS;
  const float* td = topd + (size_t)g * (JS * 10);
  const unsigned short* ti = topi + (size_t)g * (JS * 10);
  const float e_i = eb[g & (NPTS - 1)];
  int h0 = 0, h1 = 0, h2 = 0, h3 = 0;
  bool basin = true;
  float rr = 0.f;
  for (int k = 0; k < 10; ++k) {
    float bd = FLT_MAX; int bi = 0x7fffffff; int bl = -1;
    { float d = td[h0];      int ii = ti[h0];      if (dless(d, ii, bd, bi)) { bd = d; bi = ii; bl = 0; } }
    { float d = td[10 + h1]; int ii = ti[10 + h1]; if (dless(d, ii, bd, bi)) { bd = d; bi = ii; bl = 1; } }
    { float d = td[20 + h2]; int ii = ti[20 + h2]; if (dless(d, ii, bd, bi)) { bd = d; bi = ii; bl = 2; } }
    { float d = td[30 + h3]; int ii = ti[30 + h3]; if (dless(d, ii, bd, bi)) { bd = d; bi = ii; bl = 3; } }
    h0 += (bl == 0); h1 += (bl == 1); h2 += (bl == 2); h3 += (bl == 3);
    rr = bd;
    if (k >= 1) basin = basin && (e_i <= eb[bi]);
  }
  rs_ws[g] = rr;
  basin_out[g] = basin ? 1.f : 0.f;
}

// ---------------------------------------------------------------------------
// Distance pass 2 (split-j): partial masked reductions per chunk
// ---------------------------------------------------------------------------
__global__ __launch_bounds__(256, 2) void mask_part_kernel(
    const float* __restrict__ conf, const float* __restrict__ sq_ws,
    const float* __restrict__ e_in, const float* __restrict__ rs_ws,
    float* __restrict__ pmax, float* __restrict__ psum, float* __restrict__ pcnt) {
  __shared__ __align__(16) float As[64][68];
  __shared__ __align__(16) float Bs[64][68];
  __shared__ float sqa[64], sqjs[64], ejs[64], rsh[64];

  const int tid = threadIdx.x;
  const int b = blockIdx.z;
  const int i0 = blockIdx.x * 64;
  const int jbase = blockIdx.y * (NPTS / JS);
  const float* confb = conf + (size_t)b * NPTS * 64;
  const float* sqb = sq_ws + (size_t)b * NPTS;
  const float* eb = e_in + (size_t)b * NPTS;

  for (int q = tid; q < 1024; q += 256) {
    int row = q >> 4, k4 = (q & 15) << 2;
    *(float4*)&As[row][k4] = *(const float4*)(confb + (size_t)(i0 + row) * 64 + k4);
  }
  if (tid < 64) {
    sqa[tid] = sqb[i0 + tid];
    rsh[tid] = rs_ws[(size_t)b * NPTS + i0 + tid];
  }
  __syncthreads();

  const int tc = tid & 15, tr = tid >> 4;
  float rsl[4];
#pragma unroll
  for (int r = 0; r < 4; ++r) rsl[r] = rsh[tr + 16 * r];

  float mxe[4], sd[4];
  int cnt[4];
#pragma unroll
  for (int r = 0; r < 4; ++r) { mxe[r] = -FLT_MAX; sd[r] = 0.f; cnt[r] = 0; }

  for (int jt = 0; jt < NPTS / JS / 64; ++jt) {
    const int j0 = jbase + jt * 64;
    for (int q = tid; q < 1024; q += 256) {
      int row = q >> 4, k4 = (q & 15) << 2;
      *(float4*)&Bs[row][k4] = *(const float4*)(confb + (size_t)(j0 + row) * 64 + k4);
    }
    if (tid < 64) { sqjs[tid] = sqb[j0 + tid]; ejs[tid] = eb[j0 + tid]; }
    __syncthreads();

    float acc[4][4] = {};
    DIST_GEMM(acc);
#pragma unroll
    for (int r = 0; r < 4; ++r)
#pragma unroll
      for (int c = 0; c < 4; ++c) {
        int row = tr + 16 * r, col = tc + 16 * c;
        float d2 = sqa[row] + sqjs[col] - 2.f * acc[r][c];
        float d = sqrtf(fmaxf(d2, EPSC));
        if (d < rsl[r]) {
          mxe[r] = fmaxf(mxe[r], ejs[col]);
          sd[r] += d;
          cnt[r] += 1;
        }
      }
    __syncthreads();   // Bs/sqjs/ejs consumed; next stage safe
  }

  // 16 threads (tc) share each row and are consecutive lanes: shfl-reduce
#pragma unroll
  for (int r = 0; r < 4; ++r) {
    float m = mxe[r], s = sd[r], c = (float)cnt[r];
#pragma unroll
    for (int off = 8; off >= 1; off >>= 1) {
      m = fmaxf(m, __shfl_xor(m, off, 16));
      s += __shfl_xor(s, off, 16);
      c += __shfl_xor(c, off, 16);
    }
    if (tc == 0) {
      const size_t o = ((size_t)b * NPTS + i0 + tr + 16 * r) * JS + blockIdx.y;
      pmax[o] = m;
      psum[o] = s;
      pcnt[o] = c;
    }
  }
}

__global__ __launch_bounds__(256) void finalize_kernel(
    const float* __restrict__ pmax, const float* __restrict__ psum,
    const float* __restrict__ pcnt, const float* __restrict__ e_in,
    float* __restrict__ depth_out, float* __restrict__ width_out) {
  const int g = blockIdx.x * 256 + threadIdx.x;
  float m = -FLT_MAX, s = 0.f, c = 0.f;
#pragma unroll
  for (int j = 0; j < JS; ++j) {
    m = fmaxf(m, pmax[(size_t)g * JS + j]);
    s += psum[(size_t)g * JS + j];
    c += pcnt[(size_t)g * JS + j];
  }
  depth_out[g] = m - e_in[g];
  width_out[g] = s / c;
}

// ---------------------------------------------------------------------------
// Kernel 3: rank by nd (stable), scatter e into sorted order
// ---------------------------------------------------------------------------
__global__ __launch_bounds__(256) void rank_kernel(
    const float* __restrict__ nd_ws, const float* __restrict__ e_in,
    float* __restrict__ se_ws) {
  __shared__ __align__(16) float ndl[4096];
  const int tid = threadIdx.x;
  const int b = blockIdx.y;
  const int i0 = blockIdx.x * 256;
  const float* ndb = nd_ws + (size_t)b * NPTS;
  for (int q = tid; q < 1024; q += 256)
    *(float4*)&ndl[q * 4] = *(const float4*)(ndb + q * 4);
  __syncthreads();
  const int i = i0 + tid;
  const float ndi = ndl[i];
  int rank = 0;
  for (int j = 0; j < 4096; j += 4) {
    float4 v = *(const float4*)&ndl[j];
    rank += (v.x < ndi) || (v.x == ndi && (j + 0) < i);
    rank += (v.y < ndi) || (v.y == ndi && (j + 1) < i);
    rank += (v.z < ndi) || (v.z == ndi && (j + 2) < i);
    rank += (v.w < ndi) || (v.w == ndi && (j + 3) < i);
  }
  se_ws[(size_t)b * NPTS + rank] = e_in[(size_t)b * NPTS + i];
}

// ---------------------------------------------------------------------------
// Kernel 4: per-batch scalar metrics
// ---------------------------------------------------------------------------
__device__ __forceinline__ float block_sum(float v, float* red, int tid) {
  red[tid] = v;
  __syncthreads();
  for (int s = 512; s > 0; s >>= 1) {
    if (tid < s) red[tid] += red[tid + s];
    __syncthreads();
  }
  float r = red[0];
  __syncthreads();
  return r;
}
__device__ __forceinline__ float block_max(float v, float* red, int tid) {
  red[tid] = v;
  __syncthreads();
  for (int s = 512; s > 0; s >>= 1) {
    if (tid < s) red[tid] = fmaxf(red[tid], red[tid + s]);
    __syncthreads();
  }
  float r = red[0];
  __syncthreads();
  return r;
}

__global__ __launch_bounds__(1024) void metrics_kernel(
    const float* __restrict__ e_in, const float* __restrict__ nd_ws,
    const float* __restrict__ se_ws, float* __restrict__ metrics_out) {
  __shared__ __align__(16) float el[4096], ndl[4096], sel[4096];
  __shared__ float red[1024];
  __shared__ int redi[1024];
  const int tid = threadIdx.x;
  const int b = blockIdx.x;
  const float* eb = e_in + (size_t)b * NPTS;
  const float* ndb = nd_ws + (size_t)b * NPTS;
  const float* seb = se_ws + (size_t)b * NPTS;
  *(float4*)&el[tid * 4] = *(const float4*)(eb + tid * 4);
  *(float4*)&ndl[tid * 4] = *(const float4*)(ndb + tid * 4);
  *(float4*)&sel[tid * 4] = *(const float4*)(seb + tid * 4);
  __syncthreads();

  float pe = 0.f, pnd = 0.f;
  for (int p = tid; p < 4096; p += 1024) { pe += el[p]; pnd += ndl[p]; }
  float me = block_sum(pe, red, tid) / 4096.f;
  float mnd = block_sum(pnd, red, tid) / 4096.f;

  float sxx = 0.f, syy = 0.f, sxy = 0.f, mx = -FLT_MAX;
  float bestv = FLT_MAX;
  int besti = 0x7fffffff;
  for (int p = tid; p < 4096; p += 1024) {
    float de = el[p] - me, dn = ndl[p] - mnd;
    syy += de * de;
    sxx += dn * dn;
    sxy += de * dn;
    mx = fmaxf(mx, el[p]);
    if (ndl[p] < bestv || (ndl[p] == bestv && p < besti)) { bestv = ndl[p]; besti = p; }
  }
  float fr = 0.f;
  for (int p = tid; p < 4095; p += 1024) fr += (sel[p + 1] > sel[p]) ? 1.f : 0.f;

  sxx = block_sum(sxx, red, tid);
  syy = block_sum(syy, red, tid);
  sxy = block_sum(sxy, red, tid);
  mx = block_max(mx, red, tid);
  fr = block_sum(fr, red, tid);

  red[tid] = bestv;
  redi[tid] = besti;
  __syncthreads();
  for (int s = 512; s > 0; s >>= 1) {
    if (tid < s) {
      float ov = red[tid + s];
      int oi = redi[tid + s];
      if (ov < red[tid] || (ov == red[tid] && oi < redi[tid])) { red[tid] = ov; redi[tid] = oi; }
    }
    __syncthreads();
  }
  if (tid == 0) {
    float ne = el[redi[0]];
    metrics_out[b * 5 + 0] = mx - ne;
    metrics_out[b * 5 + 1] = sqrtf(syy / 4095.f);
    metrics_out[b * 5 + 2] = sxy / sqrtf(sxx * syy);
    metrics_out[b * 5 + 3] = fr / 4095.f;
    metrics_out[b * 5 + 4] = ne;
  }
}

// ---------------------------------------------------------------------------
extern "C" void kernel_launch(void* const* d_in, const int* in_sizes, int n_in,
                              void* d_out, int out_size, void* d_ws, size_t ws_size,
                              hipStream_t stream) {
  const float* conf = (const float*)d_in[0];
  const float* native = (const float*)d_in[1];
  const float* We1 = (const float*)d_in[2];
  const float* be1 = (const float*)d_in[3];
  const float* We2 = (const float*)d_in[4];
  const float* be2 = (const float*)d_in[5];
  const float* We3 = (const float*)d_in[6];
  const float* be3 = (const float*)d_in[7];
  const float* Ws1 = (const float*)d_in[8];
  const float* bs1 = (const float*)d_in[9];
  const float* Ws2 = (const float*)d_in[10];
  const float* bs2 = (const float*)d_in[11];

  float* out = (float*)d_out;
  float* e_out = out;                 // [0, 16384)
  float* basin_out = out + BN;        // [16384, 32768)
  float* depth_out = out + 2 * BN;    // [32768, 49152)
  float* width_out = out + 3 * BN;    // [49152, 65536)
  float* logits_out = out + 4 * BN;   // [65536, 163840)
  float* metrics_out = out + 10 * BN; // [163840, 163860)

  // ws layout (floats): sq | nd | se | rs | pmax(4BN) | psum(4BN) | pcnt(4BN)
  //                     | topd(40BN) | topi(40BN ushort = 20BN floats)  = 76*BN floats ≈ 5 MB
  float* wsf = (float*)d_ws;
  float* sq_ws = wsf;
  float* nd_ws = wsf + BN;
  float* se_ws = wsf + 2 * (size_t)BN;
  float* rs_ws = wsf + 3 * (size_t)BN;
  float* pmax = wsf + 4 * (size_t)BN;
  float* psum = wsf + 8 * (size_t)BN;
  float* pcnt = wsf + 12 * (size_t)BN;
  float* topd = wsf + 16 * (size_t)BN;
  unsigned short* topi = (unsigned short*)(wsf + 56 * (size_t)BN);

  mlp_kernel<<<dim3(512), dim3(256), 0, stream>>>(
      conf, native, We1, be1, We2, be2, We3, be3, Ws1, bs1, Ws2, bs2,
      e_out, logits_out, sq_ws, nd_ws);
  topk_part_kernel<<<dim3(64, JS, NBATCH), dim3(256), 0, stream>>>(
      conf, sq_ws, topd, topi);
  topk_merge_kernel<<<dim3(BN / 256), dim3(256), 0, stream>>>(
      topd, topi, e_out, basin_out, rs_ws);
  mask_part_kernel<<<dim3(64, JS, NBATCH), dim3(256), 0, stream>>>(
      conf, sq_ws, e_out, rs_ws, pmax, psum, pcnt);
  finalize_kernel<<<dim3(BN / 256), dim3(256), 0, stream>>>(
      pmax, psum, pcnt, e_out, depth_out, width_out);
  rank_kernel<<<dim3(16, NBATCH), dim3(256), 0, stream>>>(nd_ws, e_out, se_ws);
  metrics_kernel<<<dim3(NBATCH), dim3(1024), 0, stream>>>(e_out, nd_ws, se_ws, metrics_out);
}

// Round 4
// 709.357 us; speedup vs baseline: 7.6895x; 5.0273x over previous
//
#include <hip/hip_runtime.h>
#include <float.h>
#include <math.h>

#define NPTS 4096
#define NBATCH 4
#define BN (NBATCH * NPTS)   // 16384
#define EPSC 1e-12f
#define JS 4                 // j-dimension splits for the distance kernels

__device__ __forceinline__ bool dless(float d1, int i1, float d2, int i2) {
  return (d1 < d2) || ((d1 == d2) && (i1 < i2));
}

// ---------------------------------------------------------------------------
// Kernel 1: fused MLP — e, logits, sq, nd.  512 blocks x 256 thr, 32 pts/block
// ---------------------------------------------------------------------------
__device__ __forceinline__ void gemm32x128(const float (*A)[64], const float* W,
                                           const float* bias, float (*O)[128], int tid) {
  const int pi = (tid >> 5) << 2;   // point quad
  const int ci = (tid & 31) << 2;   // col quad
  float acc[4][4] = {};
  for (int k0 = 0; k0 < 64; k0 += 4) {
    alignas(16) float av[4][4], wv[4][4];
#pragma unroll
    for (int r = 0; r < 4; ++r) *(float4*)av[r] = *(const float4*)&A[pi + r][k0];
#pragma unroll
    for (int kk = 0; kk < 4; ++kk) *(float4*)wv[kk] = *(const float4*)&W[(k0 + kk) * 128 + ci];
#pragma unroll
    for (int kk = 0; kk < 4; ++kk)
#pragma unroll
      for (int r = 0; r < 4; ++r)
#pragma unroll
        for (int c = 0; c < 4; ++c)
          acc[r][c] = fmaf(av[r][kk], wv[kk][c], acc[r][c]);
  }
#pragma unroll
  for (int r = 0; r < 4; ++r)
#pragma unroll
    for (int c = 0; c < 4; ++c)
      O[pi + r][ci + c] = fmaxf(acc[r][c] + bias[ci + c], 0.f);
}

__global__ __launch_bounds__(256) void mlp_kernel(
    const float* __restrict__ conf, const float* __restrict__ native,
    const float* __restrict__ We1, const float* __restrict__ be1,
    const float* __restrict__ We2, const float* __restrict__ be2,
    const float* __restrict__ We3, const float* __restrict__ be3,
    const float* __restrict__ Ws1, const float* __restrict__ bs1,
    const float* __restrict__ Ws2, const float* __restrict__ bs2,
    float* __restrict__ e_out, float* __restrict__ logits_out,
    float* __restrict__ sq_ws, float* __restrict__ nd_ws) {
  __shared__ __align__(16) float Wbuf[8192];       // 32 KB (We1 / We2 / Ws1)
  __shared__ __align__(16) float confs[32][64];    // 8 KB (later reused for h2)
  __shared__ __align__(16) float hbuf[32][128];    // 16 KB (g then h1)
  __shared__ float nat[64];
  __shared__ float b1s[128], b2s[64], w3s[64], bs1s[128], ws2s[768], bs2s[6];
  __shared__ float be3s;

  const int tid = threadIdx.x;
  const int blk = blockIdx.x;       // 0..511
  const int b = blk >> 7;           // 128 blocks per batch
  const int pbase = (blk & 127) * 32;
  const float* confb = conf + ((size_t)b * NPTS + pbase) * 64;

  for (int q = tid; q < 512; q += 256) {
    float4 v = *(const float4*)(confb + q * 4);
    *(float4*)&confs[q >> 4][(q & 15) << 2] = v;
  }
  if (tid < 64) nat[tid] = native[b * 64 + tid];
  if (tid < 128) b1s[tid] = be1[tid];
  if (tid < 64) b2s[tid] = be2[tid];
  if (tid < 64) w3s[tid] = We3[tid];
  if (tid < 128) bs1s[tid] = bs1[tid];
  for (int q = tid; q < 768; q += 256) ws2s[q] = Ws2[q];
  if (tid < 6) bs2s[tid] = bs2[tid];
  if (tid == 0) be3s = be3[0];
  for (int q = tid; q < 2048; q += 256)
    *(float4*)&Wbuf[q * 4] = *(const float4*)(Ws1 + q * 4);
  __syncthreads();

  // sq & nd — numpy-pairwise style: rounded products, 8 accumulators
  if (tid < 32) {
    float rs_[8], rn_[8];
#pragma unroll
    for (int u = 0; u < 8; ++u) {
      float c = confs[tid][u];
      rs_[u] = c * c;
      float d = c - nat[u];
      rn_[u] = d * d;
    }
    for (int d0 = 8; d0 < 64; d0 += 8) {
#pragma unroll
      for (int u = 0; u < 8; ++u) {
        float c = confs[tid][d0 + u];
        rs_[u] += c * c;
        float d = c - nat[d0 + u];
        rn_[u] += d * d;
      }
    }
    float s = ((rs_[0] + rs_[1]) + (rs_[2] + rs_[3])) + ((rs_[4] + rs_[5]) + (rs_[6] + rs_[7]));
    float n = ((rn_[0] + rn_[1]) + (rn_[2] + rn_[3])) + ((rn_[4] + rn_[5]) + (rn_[6] + rn_[7]));
    sq_ws[(size_t)b * NPTS + pbase + tid] = s;
    nd_ws[(size_t)b * NPTS + pbase + tid] = sqrtf(n);
  }

  gemm32x128(confs, Wbuf, bs1s, hbuf, tid);     // g = relu(conf @ Ws1 + bs1)
  __syncthreads();

  for (int q = tid; q < 2048; q += 256)         // reload Wbuf <- We1
    *(float4*)&Wbuf[q * 4] = *(const float4*)(We1 + q * 4);
  if (tid < 192) {
    int p = tid / 6, s = tid % 6;
    float acc = 0.f;
#pragma unroll 8
    for (int h = 0; h < 128; ++h)
      acc = fmaf(hbuf[p][h], ws2s[h * 6 + s], acc);
    logits_out[((size_t)b * NPTS + pbase + p) * 6 + s] = acc + bs2s[s];
  }
  __syncthreads();

  gemm32x128(confs, Wbuf, b1s, hbuf, tid);      // h1 = relu(conf @ We1 + be1)
  __syncthreads();

  for (int q = tid; q < 2048; q += 256)
    *(float4*)&Wbuf[q * 4] = *(const float4*)(We2 + q * 4);
  __syncthreads();

  // h2 = relu(h1 @ We2 + be2) -> confs
  if (tid < 128) {
    const int pi = (tid >> 4) << 2;
    const int ci = (tid & 15) << 2;
    float acc[4][4] = {};
    for (int k0 = 0; k0 < 128; k0 += 4) {
      alignas(16) float av[4][4], wv[4][4];
#pragma unroll
      for (int r = 0; r < 4; ++r) *(float4*)av[r] = *(const float4*)&hbuf[pi + r][k0];
#pragma unroll
      for (int kk = 0; kk < 4; ++kk) *(float4*)wv[kk] = *(const float4*)&Wbuf[(k0 + kk) * 64 + ci];
#pragma unroll
      for (int kk = 0; kk < 4; ++kk)
#pragma unroll
        for (int r = 0; r < 4; ++r)
#pragma unroll
          for (int c = 0; c < 4; ++c)
            acc[r][c] = fmaf(av[r][kk], wv[kk][c], acc[r][c]);
    }
#pragma unroll
    for (int r = 0; r < 4; ++r)
#pragma unroll
      for (int c = 0; c < 4; ++c)
        confs[pi + r][ci + c] = fmaxf(acc[r][c] + b2s[ci + c], 0.f);
  }
  __syncthreads();

  if (tid < 32) {                               // e = h2 @ We3 + be3
    float acc = 0.f;
#pragma unroll
    for (int k = 0; k < 64; ++k)
      acc = fmaf(confs[tid][k], w3s[k], acc);
    e_out[(size_t)b * NPTS + pbase + tid] = acc + be3s;
  }
}

// ---------------------------------------------------------------------------
// Distance pass 1 (split-j): per (64-row block, 1024-col chunk) top-10
// launch_bounds(256,2): empirically arg N -> VGPR cap 512/(2N); N=2 -> 128.
// ---------------------------------------------------------------------------
#define TOP10_INSERT(d_, j_)                                                  \
  do {                                                                        \
    if (dless((d_), (j_), ld[9], li[9])) {                                    \
      float cd = (d_); int ci = (j_); bool placed = false;                    \
      _Pragma("unroll")                                                       \
      for (int k = 9; k >= 1; --k) {                                          \
        bool up = !placed && dless(cd, ci, ld[k - 1], li[k - 1]);             \
        bool here = !placed && !up;                                           \
        float pd = ld[k - 1]; int pi_ = li[k - 1];                            \
        if (up) { ld[k] = pd; li[k] = pi_; }                                  \
        if (here) { ld[k] = cd; li[k] = ci; placed = true; }                  \
      }                                                                       \
      if (!placed) { ld[0] = cd; li[0] = ci; }                                \
    }                                                                         \
  } while (0)

// micro-GEMM: 4x4 outputs, av staged 16 regs, bv staged 4 regs per column.
// fmaf order (k0 asc, kk asc) identical across all kernels -> bit-identical d.
#define DIST_GEMM(ACC)                                                        \
  do {                                                                        \
    for (int k0 = 0; k0 < 64; k0 += 4) {                                      \
      alignas(16) float av[4][4];                                             \
      _Pragma("unroll")                                                       \
      for (int r = 0; r < 4; ++r)                                             \
        *(float4*)av[r] = *(const float4*)&As[tr + 16 * r][k0];               \
      _Pragma("unroll")                                                       \
      for (int c = 0; c < 4; ++c) {                                           \
        alignas(16) float bv[4];                                              \
        *(float4*)bv = *(const float4*)&Bs[tc + 16 * c][k0];                  \
        _Pragma("unroll")                                                     \
        for (int kk = 0; kk < 4; ++kk)                                        \
          _Pragma("unroll")                                                   \
          for (int r = 0; r < 4; ++r)                                         \
            ACC[r][c] = fmaf(av[r][kk], bv[kk], ACC[r][c]);                   \
      }                                                                       \
    }                                                                         \
  } while (0)

__global__ __launch_bounds__(256, 2) void topk_part_kernel(
    const float* __restrict__ conf, const float* __restrict__ sq_ws,
    float* __restrict__ topd, unsigned short* __restrict__ topi) {
  __shared__ __align__(16) float As[64][68];   // 17.4 KB (reused as mrgD)
  __shared__ __align__(16) float Bs[64][68];   // 17.4 KB (conf tile -> dist; reused as mrgI)
  __shared__ float sqa[64], sqjs[64];

  const int tid = threadIdx.x;
  const int b = blockIdx.z;
  const int i0 = blockIdx.x * 64;
  const int jbase = blockIdx.y * (NPTS / JS);
  const float* confb = conf + (size_t)b * NPTS * 64;
  const float* sqb = sq_ws + (size_t)b * NPTS;

  for (int q = tid; q < 1024; q += 256) {
    int row = q >> 4, k4 = (q & 15) << 2;
    *(float4*)&As[row][k4] = *(const float4*)(confb + (size_t)(i0 + row) * 64 + k4);
  }
  if (tid < 64) sqa[tid] = sqb[i0 + tid];

  const int tc = tid & 15, tr = tid >> 4;
  float ld[10];
  int li[10];
#pragma unroll
  for (int k = 0; k < 10; ++k) { ld[k] = FLT_MAX; li[k] = 0x7fffffff; }

  for (int jt = 0; jt < NPTS / JS / 64; ++jt) {   // 16 tiles of 64
    __syncthreads();   // As ready (jt=0) / previous tile fully consumed
    const int j0 = jbase + jt * 64;
    for (int q = tid; q < 1024; q += 256) {
      int row = q >> 4, k4 = (q & 15) << 2;
      *(float4*)&Bs[row][k4] = *(const float4*)(confb + (size_t)(j0 + row) * 64 + k4);
    }
    if (tid < 64) sqjs[tid] = sqb[j0 + tid];
    __syncthreads();

    float acc[4][4] = {};
    DIST_GEMM(acc);
    __syncthreads();  // everyone done reading Bs(conf)
#pragma unroll
    for (int r = 0; r < 4; ++r)
#pragma unroll
      for (int c = 0; c < 4; ++c) {
        int row = tr + 16 * r, col = tc + 16 * c;
        float d2 = sqa[row] + sqjs[col] - 2.f * acc[r][c];
        Bs[row][col] = sqrtf(fmaxf(d2, EPSC));
      }
    __syncthreads();
    {
      const int row = tid >> 2, q4 = tid & 3;
#pragma unroll
      for (int cc = 0; cc < 4; ++cc) {
        float4 v = *(const float4*)&Bs[row][q4 * 16 + cc * 4];
        const int jb = j0 + q4 * 16 + cc * 4;
        TOP10_INSERT(v.x, jb + 0);
        TOP10_INSERT(v.y, jb + 1);
        TOP10_INSERT(v.z, jb + 2);
        TOP10_INSERT(v.w, jb + 3);
      }
    }
  }
  __syncthreads();

  // merge 4 per-thread sorted lists per row -> chunk top-10, write to ws
  float* mrgD = &As[0][0];       // 64*40 floats
  int* mrgI = (int*)&Bs[0][0];   // 64*40 ints
  {
    const int row = tid >> 2, q4 = tid & 3;
#pragma unroll
    for (int k = 0; k < 10; ++k) {
      mrgD[row * 40 + q4 * 10 + k] = ld[k];
      mrgI[row * 40 + q4 * 10 + k] = li[k];
    }
  }
  __syncthreads();
  if (tid < 64) {
    const int base = tid * 40;
    int h0 = 0, h1 = 0, h2 = 0, h3 = 0;
    const size_t obase = (((size_t)b * NPTS + i0 + tid) * JS + blockIdx.y) * 10;
    for (int k = 0; k < 10; ++k) {
      float bd = FLT_MAX; int bi = 0x7fffffff; int bl = -1;
      { float d = mrgD[base + h0];      int ii = mrgI[base + h0];      if (dless(d, ii, bd, bi)) { bd = d; bi = ii; bl = 0; } }
      { float d = mrgD[base + 10 + h1]; int ii = mrgI[base + 10 + h1]; if (dless(d, ii, bd, bi)) { bd = d; bi = ii; bl = 1; } }
      { float d = mrgD[base + 20 + h2]; int ii = mrgI[base + 20 + h2]; if (dless(d, ii, bd, bi)) { bd = d; bi = ii; bl = 2; } }
      { float d = mrgD[base + 30 + h3]; int ii = mrgI[base + 30 + h3]; if (dless(d, ii, bd, bi)) { bd = d; bi = ii; bl = 3; } }
      h0 += (bl == 0); h1 += (bl == 1); h2 += (bl == 2); h3 += (bl == 3);
      topd[obase + k] = bd;
      topi[obase + k] = (unsigned short)bi;
    }
  }
}

// ---------------------------------------------------------------------------
// Merge JS chunk top-10s per row -> r, is_basin
// ---------------------------------------------------------------------------
__global__ __launch_bounds__(256) void topk_merge_kernel(
    const float* __restrict__ topd, const unsigned short* __restrict__ topi,
    const float* __restrict__ e_in, float* __restrict__ basin_out,
    float* __restrict__ rs_ws) {
  const int g = blockIdx.x * 256 + threadIdx.x;   // 0..16383
  const int b = g >> 12;
  const float* eb = e_in + (size_t)b * NPTS;
  const float* td = topd + (size_t)g * (JS * 10);
  const unsigned short* ti = topi + (size_t)g * (JS * 10);
  const float e_i = eb[g & (NPTS - 1)];
  int h0 = 0, h1 = 0, h2 = 0, h3 = 0;
  bool basin = true;
  float rr = 0.f;
  for (int k = 0; k < 10; ++k) {
    float bd = FLT_MAX; int bi = 0x7fffffff; int bl = -1;
    { float d = td[h0];      int ii = ti[h0];      if (dless(d, ii, bd, bi)) { bd = d; bi = ii; bl = 0; } }
    { float d = td[10 + h1]; int ii = ti[10 + h1]; if (dless(d, ii, bd, bi)) { bd = d; bi = ii; bl = 1; } }
    { float d = td[20 + h2]; int ii = ti[20 + h2]; if (dless(d, ii, bd, bi)) { bd = d; bi = ii; bl = 2; } }
    { float d = td[30 + h3]; int ii = ti[30 + h3]; if (dless(d, ii, bd, bi)) { bd = d; bi = ii; bl = 3; } }
    h0 += (bl == 0); h1 += (bl == 1); h2 += (bl == 2); h3 += (bl == 3);
    rr = bd;
    if (k >= 1) basin = basin && (e_i <= eb[bi]);
  }
  rs_ws[g] = rr;
  basin_out[g] = basin ? 1.f : 0.f;
}

// ---------------------------------------------------------------------------
// Distance pass 2 (split-j): partial masked reductions per chunk.
// Restructured to the (proven no-spill at cap 128) topk shape: GEMM -> dist
// to LDS -> light per-row accumulate (3 regs) -> width-4 shfl reduce.
// ---------------------------------------------------------------------------
__global__ __launch_bounds__(256, 2) void mask_part_kernel(
    const float* __restrict__ conf, const float* __restrict__ sq_ws,
    const float* __restrict__ e_in, const float* __restrict__ rs_ws,
    float* __restrict__ pmax, float* __restrict__ psum, float* __restrict__ pcnt) {
  __shared__ __align__(16) float As[64][68];
  __shared__ __align__(16) float Bs[64][68];
  __shared__ __align__(16) float ejs[64];
  __shared__ float sqa[64], sqjs[64], rsh[64];

  const int tid = threadIdx.x;
  const int b = blockIdx.z;
  const int i0 = blockIdx.x * 64;
  const int jbase = blockIdx.y * (NPTS / JS);
  const float* confb = conf + (size_t)b * NPTS * 64;
  const float* sqb = sq_ws + (size_t)b * NPTS;
  const float* eb = e_in + (size_t)b * NPTS;

  for (int q = tid; q < 1024; q += 256) {
    int rw = q >> 4, k4 = (q & 15) << 2;
    *(float4*)&As[rw][k4] = *(const float4*)(confb + (size_t)(i0 + rw) * 64 + k4);
  }
  if (tid < 64) {
    sqa[tid] = sqb[i0 + tid];
    rsh[tid] = rs_ws[(size_t)b * NPTS + i0 + tid];
  }

  const int tc = tid & 15, tr = tid >> 4;
  const int row = tid >> 2, q4 = tid & 3;

  float am = -FLT_MAX, asum = 0.f, act = 0.f;

  for (int jt = 0; jt < NPTS / JS / 64; ++jt) {
    __syncthreads();   // As/rsh ready (jt=0) / previous tile fully consumed
    const int j0 = jbase + jt * 64;
    for (int q = tid; q < 1024; q += 256) {
      int rw = q >> 4, k4 = (q & 15) << 2;
      *(float4*)&Bs[rw][k4] = *(const float4*)(confb + (size_t)(j0 + rw) * 64 + k4);
    }
    if (tid < 64) { sqjs[tid] = sqb[j0 + tid]; ejs[tid] = eb[j0 + tid]; }
    __syncthreads();

    float acc[4][4] = {};
    DIST_GEMM(acc);
    __syncthreads();  // everyone done reading Bs(conf)
#pragma unroll
    for (int r = 0; r < 4; ++r)
#pragma unroll
      for (int c = 0; c < 4; ++c) {
        int rw = tr + 16 * r, cl = tc + 16 * c;
        float d2 = sqa[rw] + sqjs[cl] - 2.f * acc[r][c];
        Bs[rw][cl] = sqrtf(fmaxf(d2, EPSC));
      }
    __syncthreads();
    {
      const float rr = rsh[row];
#pragma unroll
      for (int cc = 0; cc < 4; ++cc) {
        float4 dv = *(const float4*)&Bs[row][q4 * 16 + cc * 4];
        float4 ev = *(const float4*)&ejs[q4 * 16 + cc * 4];
        if (dv.x < rr) { am = fmaxf(am, ev.x); asum += dv.x; act += 1.f; }
        if (dv.y < rr) { am = fmaxf(am, ev.y); asum += dv.y; act += 1.f; }
        if (dv.z < rr) { am = fmaxf(am, ev.z); asum += dv.z; act += 1.f; }
        if (dv.w < rr) { am = fmaxf(am, ev.w); asum += dv.w; act += 1.f; }
      }
    }
  }

  // reduce across the 4 consecutive lanes sharing a row
#pragma unroll
  for (int off = 2; off >= 1; off >>= 1) {
    am = fmaxf(am, __shfl_xor(am, off, 4));
    asum += __shfl_xor(asum, off, 4);
    act += __shfl_xor(act, off, 4);
  }
  if (q4 == 0) {
    const size_t o = ((size_t)b * NPTS + i0 + row) * JS + blockIdx.y;
    pmax[o] = am;
    psum[o] = asum;
    pcnt[o] = act;
  }
}

__global__ __launch_bounds__(256) void finalize_kernel(
    const float* __restrict__ pmax, const float* __restrict__ psum,
    const float* __restrict__ pcnt, const float* __restrict__ e_in,
    float* __restrict__ depth_out, float* __restrict__ width_out) {
  const int g = blockIdx.x * 256 + threadIdx.x;
  float m = -FLT_MAX, s = 0.f, c = 0.f;
#pragma unroll
  for (int j = 0; j < JS; ++j) {
    m = fmaxf(m, pmax[(size_t)g * JS + j]);
    s += psum[(size_t)g * JS + j];
    c += pcnt[(size_t)g * JS + j];
  }
  depth_out[g] = m - e_in[g];
  width_out[g] = s / c;
}

// ---------------------------------------------------------------------------
// Kernel 3: rank by nd (stable), scatter e into sorted order
// ---------------------------------------------------------------------------
__global__ __launch_bounds__(256) void rank_kernel(
    const float* __restrict__ nd_ws, const float* __restrict__ e_in,
    float* __restrict__ se_ws) {
  __shared__ __align__(16) float ndl[4096];
  const int tid = threadIdx.x;
  const int b = blockIdx.y;
  const int i0 = blockIdx.x * 256;
  const float* ndb = nd_ws + (size_t)b * NPTS;
  for (int q = tid; q < 1024; q += 256)
    *(float4*)&ndl[q * 4] = *(const float4*)(ndb + q * 4);
  __syncthreads();
  const int i = i0 + tid;
  const float ndi = ndl[i];
  int rank = 0;
  for (int j = 0; j < 4096; j += 4) {
    float4 v = *(const float4*)&ndl[j];
    rank += (v.x < ndi) || (v.x == ndi && (j + 0) < i);
    rank += (v.y < ndi) || (v.y == ndi && (j + 1) < i);
    rank += (v.z < ndi) || (v.z == ndi && (j + 2) < i);
    rank += (v.w < ndi) || (v.w == ndi && (j + 3) < i);
  }
  se_ws[(size_t)b * NPTS + rank] = e_in[(size_t)b * NPTS + i];
}

// ---------------------------------------------------------------------------
// Kernel 4: per-batch scalar metrics
// ---------------------------------------------------------------------------
__device__ __forceinline__ float block_sum(float v, float* red, int tid) {
  red[tid] = v;
  __syncthreads();
  for (int s = 512; s > 0; s >>= 1) {
    if (tid < s) red[tid] += red[tid + s];
    __syncthreads();
  }
  float r = red[0];
  __syncthreads();
  return r;
}
__device__ __forceinline__ float block_max(float v, float* red, int tid) {
  red[tid] = v;
  __syncthreads();
  for (int s = 512; s > 0; s >>= 1) {
    if (tid < s) red[tid] = fmaxf(red[tid], red[tid + s]);
    __syncthreads();
  }
  float r = red[0];
  __syncthreads();
  return r;
}

__global__ __launch_bounds__(1024) void metrics_kernel(
    const float* __restrict__ e_in, const float* __restrict__ nd_ws,
    const float* __restrict__ se_ws, float* __restrict__ metrics_out) {
  __shared__ __align__(16) float el[4096], ndl[4096], sel[4096];
  __shared__ float red[1024];
  __shared__ int redi[1024];
  const int tid = threadIdx.x;
  const int b = blockIdx.x;
  const float* eb = e_in + (size_t)b * NPTS;
  const float* ndb = nd_ws + (size_t)b * NPTS;
  const float* seb = se_ws + (size_t)b * NPTS;
  *(float4*)&el[tid * 4] = *(const float4*)(eb + tid * 4);
  *(float4*)&ndl[tid * 4] = *(const float4*)(ndb + tid * 4);
  *(float4*)&sel[tid * 4] = *(const float4*)(seb + tid * 4);
  __syncthreads();

  float pe = 0.f, pnd = 0.f;
  for (int p = tid; p < 4096; p += 1024) { pe += el[p]; pnd += ndl[p]; }
  float me = block_sum(pe, red, tid) / 4096.f;
  float mnd = block_sum(pnd, red, tid) / 4096.f;

  float sxx = 0.f, syy = 0.f, sxy = 0.f, mx = -FLT_MAX;
  float bestv = FLT_MAX;
  int besti = 0x7fffffff;
  for (int p = tid; p < 4096; p += 1024) {
    float de = el[p] - me, dn = ndl[p] - mnd;
    syy += de * de;
    sxx += dn * dn;
    sxy += de * dn;
    mx = fmaxf(mx, el[p]);
    if (ndl[p] < bestv || (ndl[p] == bestv && p < besti)) { bestv = ndl[p]; besti = p; }
  }
  float fr = 0.f;
  for (int p = tid; p < 4095; p += 1024) fr += (sel[p + 1] > sel[p]) ? 1.f : 0.f;

  sxx = block_sum(sxx, red, tid);
  syy = block_sum(syy, red, tid);
  sxy = block_sum(sxy, red, tid);
  mx = block_max(mx, red, tid);
  fr = block_sum(fr, red, tid);

  red[tid] = bestv;
  redi[tid] = besti;
  __syncthreads();
  for (int s = 512; s > 0; s >>= 1) {
    if (tid < s) {
      float ov = red[tid + s];
      int oi = redi[tid + s];
      if (ov < red[tid] || (ov == red[tid] && oi < redi[tid])) { red[tid] = ov; redi[tid] = oi; }
    }
    __syncthreads();
  }
  if (tid == 0) {
    float ne = el[redi[0]];
    metrics_out[b * 5 + 0] = mx - ne;
    metrics_out[b * 5 + 1] = sqrtf(syy / 4095.f);
    metrics_out[b * 5 + 2] = sxy / sqrtf(sxx * syy);
    metrics_out[b * 5 + 3] = fr / 4095.f;
    metrics_out[b * 5 + 4] = ne;
  }
}

// ---------------------------------------------------------------------------
extern "C" void kernel_launch(void* const* d_in, const int* in_sizes, int n_in,
                              void* d_out, int out_size, void* d_ws, size_t ws_size,
                              hipStream_t stream) {
  const float* conf = (const float*)d_in[0];
  const float* native = (const float*)d_in[1];
  const float* We1 = (const float*)d_in[2];
  const float* be1 = (const float*)d_in[3];
  const float* We2 = (const float*)d_in[4];
  const float* be2 = (const float*)d_in[5];
  const float* We3 = (const float*)d_in[6];
  const float* be3 = (const float*)d_in[7];
  const float* Ws1 = (const float*)d_in[8];
  const float* bs1 = (const float*)d_in[9];
  const float* Ws2 = (const float*)d_in[10];
  const float* bs2 = (const float*)d_in[11];

  float* out = (float*)d_out;
  float* e_out = out;                 // [0, 16384)
  float* basin_out = out + BN;        // [16384, 32768)
  float* depth_out = out + 2 * BN;    // [32768, 49152)
  float* width_out = out + 3 * BN;    // [49152, 65536)
  float* logits_out = out + 4 * BN;   // [65536, 163840)
  float* metrics_out = out + 10 * BN; // [163840, 163860)

  // ws layout (floats): sq | nd | se | rs | pmax(4BN) | psum(4BN) | pcnt(4BN)
  //                     | topd(40BN) | topi(40BN ushort = 20BN floats)  = 76*BN floats ≈ 5 MB
  float* wsf = (float*)d_ws;
  float* sq_ws = wsf;
  float* nd_ws = wsf + BN;
  float* se_ws = wsf + 2 * (size_t)BN;
  float* rs_ws = wsf + 3 * (size_t)BN;
  float* pmax = wsf + 4 * (size_t)BN;
  float* psum = wsf + 8 * (size_t)BN;
  float* pcnt = wsf + 12 * (size_t)BN;
  float* topd = wsf + 16 * (size_t)BN;
  unsigned short* topi = (unsigned short*)(wsf + 56 * (size_t)BN);

  mlp_kernel<<<dim3(512), dim3(256), 0, stream>>>(
      conf, native, We1, be1, We2, be2, We3, be3, Ws1, bs1, Ws2, bs2,
      e_out, logits_out, sq_ws, nd_ws);
  topk_part_kernel<<<dim3(64, JS, NBATCH), dim3(256), 0, stream>>>(
      conf, sq_ws, topd, topi);
  topk_merge_kernel<<<dim3(BN / 256), dim3(256), 0, stream>>>(
      topd, topi, e_out, basin_out, rs_ws);
  mask_part_kernel<<<dim3(64, JS, NBATCH), dim3(256), 0, stream>>>(
      conf, sq_ws, e_out, rs_ws, pmax, psum, pcnt);
  finalize_kernel<<<dim3(BN / 256), dim3(256), 0, stream>>>(
      pmax, psum, pcnt, e_out, depth_out, width_out);
  rank_kernel<<<dim3(16, NBATCH), dim3(256), 0, stream>>>(nd_ws, e_out, se_ws);
  metrics_kernel<<<dim3(NBATCH), dim3(1024), 0, stream>>>(e_out, nd_ws, se_ws, metrics_out);
}

// Round 5
// 437.199 us; speedup vs baseline: 12.4762x; 1.6225x over previous
//
#include <hip/hip_runtime.h>
#include <float.h>
#include <math.h>

#define NPTS 4096
#define NBATCH 4
#define BN (NBATCH * NPTS)   // 16384
#define EPSC 1e-12f
#define JS 4                 // j-dimension splits for the topk kernel

__device__ __forceinline__ bool dless(float d1, int i1, float d2, int i2) {
  return (d1 < d2) || ((d1 == d2) && (i1 < i2));
}

// ---------------------------------------------------------------------------
// Kernel 1: fused MLP — e, logits, sq, nd.  512 blocks x 256 thr, 32 pts/block
// ---------------------------------------------------------------------------
__device__ __forceinline__ void gemm32x128(const float (*A)[64], const float* W,
                                           const float* bias, float (*O)[128], int tid) {
  const int pi = (tid >> 5) << 2;   // point quad
  const int ci = (tid & 31) << 2;   // col quad
  float acc[4][4] = {};
  for (int k0 = 0; k0 < 64; k0 += 4) {
    alignas(16) float av[4][4], wv[4][4];
#pragma unroll
    for (int r = 0; r < 4; ++r) *(float4*)av[r] = *(const float4*)&A[pi + r][k0];
#pragma unroll
    for (int kk = 0; kk < 4; ++kk) *(float4*)wv[kk] = *(const float4*)&W[(k0 + kk) * 128 + ci];
#pragma unroll
    for (int kk = 0; kk < 4; ++kk)
#pragma unroll
      for (int r = 0; r < 4; ++r)
#pragma unroll
        for (int c = 0; c < 4; ++c)
          acc[r][c] = fmaf(av[r][kk], wv[kk][c], acc[r][c]);
  }
#pragma unroll
  for (int r = 0; r < 4; ++r)
#pragma unroll
    for (int c = 0; c < 4; ++c)
      O[pi + r][ci + c] = fmaxf(acc[r][c] + bias[ci + c], 0.f);
}

__global__ __launch_bounds__(256) void mlp_kernel(
    const float* __restrict__ conf, const float* __restrict__ native,
    const float* __restrict__ We1, const float* __restrict__ be1,
    const float* __restrict__ We2, const float* __restrict__ be2,
    const float* __restrict__ We3, const float* __restrict__ be3,
    const float* __restrict__ Ws1, const float* __restrict__ bs1,
    const float* __restrict__ Ws2, const float* __restrict__ bs2,
    float* __restrict__ e_out, float* __restrict__ logits_out,
    float* __restrict__ sq_ws, float* __restrict__ nd_ws) {
  __shared__ __align__(16) float Wbuf[8192];       // 32 KB (We1 / We2 / Ws1)
  __shared__ __align__(16) float confs[32][64];    // 8 KB (later reused for h2)
  __shared__ __align__(16) float hbuf[32][128];    // 16 KB (g then h1)
  __shared__ float nat[64];
  __shared__ float b1s[128], b2s[64], w3s[64], bs1s[128], ws2s[768], bs2s[6];
  __shared__ float be3s;

  const int tid = threadIdx.x;
  const int blk = blockIdx.x;       // 0..511
  const int b = blk >> 7;           // 128 blocks per batch
  const int pbase = (blk & 127) * 32;
  const float* confb = conf + ((size_t)b * NPTS + pbase) * 64;

  for (int q = tid; q < 512; q += 256) {
    float4 v = *(const float4*)(confb + q * 4);
    *(float4*)&confs[q >> 4][(q & 15) << 2] = v;
  }
  if (tid < 64) nat[tid] = native[b * 64 + tid];
  if (tid < 128) b1s[tid] = be1[tid];
  if (tid < 64) b2s[tid] = be2[tid];
  if (tid < 64) w3s[tid] = We3[tid];
  if (tid < 128) bs1s[tid] = bs1[tid];
  for (int q = tid; q < 768; q += 256) ws2s[q] = Ws2[q];
  if (tid < 6) bs2s[tid] = bs2[tid];
  if (tid == 0) be3s = be3[0];
  for (int q = tid; q < 2048; q += 256)
    *(float4*)&Wbuf[q * 4] = *(const float4*)(Ws1 + q * 4);
  __syncthreads();

  // sq & nd — numpy-pairwise style: rounded products, 8 accumulators
  if (tid < 32) {
    float rs_[8], rn_[8];
#pragma unroll
    for (int u = 0; u < 8; ++u) {
      float c = confs[tid][u];
      rs_[u] = c * c;
      float d = c - nat[u];
      rn_[u] = d * d;
    }
    for (int d0 = 8; d0 < 64; d0 += 8) {
#pragma unroll
      for (int u = 0; u < 8; ++u) {
        float c = confs[tid][d0 + u];
        rs_[u] += c * c;
        float d = c - nat[d0 + u];
        rn_[u] += d * d;
      }
    }
    float s = ((rs_[0] + rs_[1]) + (rs_[2] + rs_[3])) + ((rs_[4] + rs_[5]) + (rs_[6] + rs_[7]));
    float n = ((rn_[0] + rn_[1]) + (rn_[2] + rn_[3])) + ((rn_[4] + rn_[5]) + (rn_[6] + rn_[7]));
    sq_ws[(size_t)b * NPTS + pbase + tid] = s;
    nd_ws[(size_t)b * NPTS + pbase + tid] = sqrtf(n);
  }

  gemm32x128(confs, Wbuf, bs1s, hbuf, tid);     // g = relu(conf @ Ws1 + bs1)
  __syncthreads();

  for (int q = tid; q < 2048; q += 256)         // reload Wbuf <- We1
    *(float4*)&Wbuf[q * 4] = *(const float4*)(We1 + q * 4);
  if (tid < 192) {
    int p = tid / 6, s = tid % 6;
    float acc = 0.f;
#pragma unroll 8
    for (int h = 0; h < 128; ++h)
      acc = fmaf(hbuf[p][h], ws2s[h * 6 + s], acc);
    logits_out[((size_t)b * NPTS + pbase + p) * 6 + s] = acc + bs2s[s];
  }
  __syncthreads();

  gemm32x128(confs, Wbuf, b1s, hbuf, tid);      // h1 = relu(conf @ We1 + be1)
  __syncthreads();

  for (int q = tid; q < 2048; q += 256)
    *(float4*)&Wbuf[q * 4] = *(const float4*)(We2 + q * 4);
  __syncthreads();

  // h2 = relu(h1 @ We2 + be2) -> confs
  if (tid < 128) {
    const int pi = (tid >> 4) << 2;
    const int ci = (tid & 15) << 2;
    float acc[4][4] = {};
    for (int k0 = 0; k0 < 128; k0 += 4) {
      alignas(16) float av[4][4], wv[4][4];
#pragma unroll
      for (int r = 0; r < 4; ++r) *(float4*)av[r] = *(const float4*)&hbuf[pi + r][k0];
#pragma unroll
      for (int kk = 0; kk < 4; ++kk) *(float4*)wv[kk] = *(const float4*)&Wbuf[(k0 + kk) * 64 + ci];
#pragma unroll
      for (int kk = 0; kk < 4; ++kk)
#pragma unroll
        for (int r = 0; r < 4; ++r)
#pragma unroll
          for (int c = 0; c < 4; ++c)
            acc[r][c] = fmaf(av[r][kk], wv[kk][c], acc[r][c]);
    }
#pragma unroll
    for (int r = 0; r < 4; ++r)
#pragma unroll
      for (int c = 0; c < 4; ++c)
        confs[pi + r][ci + c] = fmaxf(acc[r][c] + b2s[ci + c], 0.f);
  }
  __syncthreads();

  if (tid < 32) {                               // e = h2 @ We3 + be3
    float acc = 0.f;
#pragma unroll
    for (int k = 0; k < 64; ++k)
      acc = fmaf(confs[tid][k], w3s[k], acc);
    e_out[(size_t)b * NPTS + pbase + tid] = acc + be3s;
  }
}

// ---------------------------------------------------------------------------
// Distance pass (split-j): per (64-row block, 1024-col chunk) top-10.
// key64 = (f32bits(d)<<32)|j : u64 order == (d, j) lex order (d >= 0 always).
// Branchless 10-step min/max bubble insert; 1-op float filter against a
// row-wide conservative bound (lex-min of the 4 sibling threads' 10th).
// ---------------------------------------------------------------------------
#define TOPK_INS(d_, j_)                                                      \
  do {                                                                        \
    if ((d_) <= thrf) {                                                       \
      unsigned long long cur =                                                \
          (((unsigned long long)__float_as_uint(d_)) << 32) |                 \
          (unsigned long long)(unsigned)(j_);                                 \
      if (cur < lk[9]) {                                                      \
        _Pragma("unroll")                                                     \
        for (int k = 0; k < 10; ++k) {                                        \
          bool lt = cur < lk[k];                                              \
          unsigned long long mn = lt ? cur : lk[k];                           \
          cur = lt ? lk[k] : cur;                                             \
          lk[k] = mn;                                                         \
        }                                                                     \
      }                                                                       \
    }                                                                         \
  } while (0)

// micro-GEMM: 4x4 outputs, av staged 16 regs, bv staged 4 regs per column.
// fmaf order (k0 asc, kk asc) identical across rounds -> bit-identical d.
#define DIST_GEMM(ACC)                                                        \
  do {                                                                        \
    for (int k0 = 0; k0 < 64; k0 += 4) {                                      \
      alignas(16) float av[4][4];                                             \
      _Pragma("unroll")                                                       \
      for (int r = 0; r < 4; ++r)                                             \
        *(float4*)av[r] = *(const float4*)&As[tr + 16 * r][k0];               \
      _Pragma("unroll")                                                       \
      for (int c = 0; c < 4; ++c) {                                           \
        alignas(16) float bv[4];                                              \
        *(float4*)bv = *(const float4*)&Bs[tc + 16 * c][k0];                  \
        _Pragma("unroll")                                                     \
        for (int kk = 0; kk < 4; ++kk)                                        \
          _Pragma("unroll")                                                   \
          for (int r = 0; r < 4; ++r)                                         \
            ACC[r][c] = fmaf(av[r][kk], bv[kk], ACC[r][c]);                   \
      }                                                                       \
    }                                                                         \
  } while (0)

__global__ __launch_bounds__(256, 2) void topk_part_kernel(
    const float* __restrict__ conf, const float* __restrict__ sq_ws,
    float* __restrict__ topd, unsigned short* __restrict__ topi) {
  __shared__ __align__(16) float As[64][68];   // 17.4 KB (reused as mrgD)
  __shared__ __align__(16) float Bs[64][68];   // 17.4 KB (conf tile -> dist; reused as mrgI)
  __shared__ float sqa[64], sqjs[64];

  const int tid = threadIdx.x;
  const int b = blockIdx.z;
  const int i0 = blockIdx.x * 64;
  const int jbase = blockIdx.y * (NPTS / JS);
  const float* confb = conf + (size_t)b * NPTS * 64;
  const float* sqb = sq_ws + (size_t)b * NPTS;

  for (int q = tid; q < 1024; q += 256) {
    int rw = q >> 4, k4 = (q & 15) << 2;
    *(float4*)&As[rw][k4] = *(const float4*)(confb + (size_t)(i0 + rw) * 64 + k4);
  }
  if (tid < 64) sqa[tid] = sqb[i0 + tid];

  const int tc = tid & 15, tr = tid >> 4;
  const int row = tid >> 2, q4 = tid & 3;

  unsigned long long lk[10];
#pragma unroll
  for (int k = 0; k < 10; ++k) lk[k] = 0x7F7FFFFF7FFFFFFFULL;  // (FLT_MAX, INT_MAX)
  float thrf = FLT_MAX;

  for (int jt = 0; jt < NPTS / JS / 64; ++jt) {   // 16 tiles of 64
    __syncthreads();   // As ready (jt=0) / previous tile fully consumed
    const int j0 = jbase + jt * 64;
    for (int q = tid; q < 1024; q += 256) {
      int rw = q >> 4, k4 = (q & 15) << 2;
      *(float4*)&Bs[rw][k4] = *(const float4*)(confb + (size_t)(j0 + rw) * 64 + k4);
    }
    if (tid < 64) sqjs[tid] = sqb[j0 + tid];
    __syncthreads();

    float acc[4][4] = {};
    DIST_GEMM(acc);
    __syncthreads();  // everyone done reading Bs(conf)
#pragma unroll
    for (int r = 0; r < 4; ++r)
#pragma unroll
      for (int c = 0; c < 4; ++c) {
        int rw = tr + 16 * r, cl = tc + 16 * c;
        float d2 = sqa[rw] + sqjs[cl] - 2.f * acc[r][c];
        Bs[rw][cl] = sqrtf(fmaxf(d2, EPSC));
      }
    __syncthreads();
    {
#pragma unroll
      for (int cc = 0; cc < 4; ++cc) {
        float4 v = *(const float4*)&Bs[row][q4 * 16 + cc * 4];
        const int jb = j0 + q4 * 16 + cc * 4;
        TOPK_INS(v.x, jb + 0);
        TOPK_INS(v.y, jb + 1);
        TOPK_INS(v.z, jb + 2);
        TOPK_INS(v.w, jb + 3);
      }
      // refresh row-wide filter bound: min of the 4 siblings' 10th d
      float t = __uint_as_float((unsigned)(lk[9] >> 32));
      t = fminf(t, __shfl_xor(t, 1, 4));
      t = fminf(t, __shfl_xor(t, 2, 4));
      thrf = t;
    }
  }
  __syncthreads();

  // merge 4 per-thread sorted lists per row -> chunk top-10, write to ws
  float* mrgD = &As[0][0];       // 64*40 floats
  int* mrgI = (int*)&Bs[0][0];   // 64*40 ints
  {
#pragma unroll
    for (int k = 0; k < 10; ++k) {
      mrgD[row * 40 + q4 * 10 + k] = __uint_as_float((unsigned)(lk[k] >> 32));
      mrgI[row * 40 + q4 * 10 + k] = (int)(unsigned)(lk[k] & 0xFFFFFFFFu);
    }
  }
  __syncthreads();
  if (tid < 64) {
    const int base = tid * 40;
    int h0 = 0, h1 = 0, h2 = 0, h3 = 0;
    const size_t obase = (((size_t)b * NPTS + i0 + tid) * JS + blockIdx.y) * 10;
    for (int k = 0; k < 10; ++k) {
      float bd = FLT_MAX; int bi = 0x7fffffff; int bl = -1;
      { float d = mrgD[base + h0];      int ii = mrgI[base + h0];      if (dless(d, ii, bd, bi)) { bd = d; bi = ii; bl = 0; } }
      { float d = mrgD[base + 10 + h1]; int ii = mrgI[base + 10 + h1]; if (dless(d, ii, bd, bi)) { bd = d; bi = ii; bl = 1; } }
      { float d = mrgD[base + 20 + h2]; int ii = mrgI[base + 20 + h2]; if (dless(d, ii, bd, bi)) { bd = d; bi = ii; bl = 2; } }
      { float d = mrgD[base + 30 + h3]; int ii = mrgI[base + 30 + h3]; if (dless(d, ii, bd, bi)) { bd = d; bi = ii; bl = 3; } }
      h0 += (bl == 0); h1 += (bl == 1); h2 += (bl == 2); h3 += (bl == 3);
      topd[obase + k] = bd;
      topi[obase + k] = (unsigned short)bi;
    }
  }
}

// ---------------------------------------------------------------------------
// Merge JS chunk top-10s per row -> r, is_basin, depth, width.
// mask = {d < r} is exactly the members of the top-10 with d < d_9 (<=9+self):
// nothing outside the 10 lex-smallest can have d < d_9.
// ---------------------------------------------------------------------------
__global__ __launch_bounds__(256) void topk_merge_kernel(
    const float* __restrict__ topd, const unsigned short* __restrict__ topi,
    const float* __restrict__ e_in, float* __restrict__ basin_out,
    float* __restrict__ depth_out, float* __restrict__ width_out) {
  const int g = blockIdx.x * 256 + threadIdx.x;   // 0..16383
  const int b = g >> 12;
  const float* eb = e_in + (size_t)b * NPTS;
  const float* td = topd + (size_t)g * (JS * 10);
  const unsigned short* ti = topi + (size_t)g * (JS * 10);
  const float e_i = eb[g & (NPTS - 1)];
  int h0 = 0, h1 = 0, h2 = 0, h3 = 0;
  float dk[10];
  int ik[10];
#pragma unroll
  for (int k = 0; k < 10; ++k) {
    float bd = FLT_MAX; int bi = 0x7fffffff; int bl = -1;
    { float d = td[h0];      int ii = ti[h0];      if (dless(d, ii, bd, bi)) { bd = d; bi = ii; bl = 0; } }
    { float d = td[10 + h1]; int ii = ti[10 + h1]; if (dless(d, ii, bd, bi)) { bd = d; bi = ii; bl = 1; } }
    { float d = td[20 + h2]; int ii = ti[20 + h2]; if (dless(d, ii, bd, bi)) { bd = d; bi = ii; bl = 2; } }
    { float d = td[30 + h3]; int ii = ti[30 + h3]; if (dless(d, ii, bd, bi)) { bd = d; bi = ii; bl = 3; } }
    h0 += (bl == 0); h1 += (bl == 1); h2 += (bl == 2); h3 += (bl == 3);
    dk[k] = bd;
    ik[k] = bi;
  }
  const float r = dk[9];
  bool basin = true;
  float mx = -FLT_MAX, sum = 0.f, cnt = 0.f;
#pragma unroll
  for (int k = 0; k < 10; ++k) {
    float ev = eb[ik[k]];
    if (dk[k] < r) { mx = fmaxf(mx, ev); sum += dk[k]; cnt += 1.f; }
    if (k >= 1) basin = basin && (e_i <= ev);
  }
  basin_out[g] = basin ? 1.f : 0.f;
  depth_out[g] = mx - e_i;
  width_out[g] = sum / cnt;
}

// ---------------------------------------------------------------------------
// Kernel 3: rank by nd (stable), scatter e into sorted order
// ---------------------------------------------------------------------------
__global__ __launch_bounds__(256) void rank_kernel(
    const float* __restrict__ nd_ws, const float* __restrict__ e_in,
    float* __restrict__ se_ws) {
  __shared__ __align__(16) float ndl[4096];
  const int tid = threadIdx.x;
  const int b = blockIdx.y;
  const int i0 = blockIdx.x * 256;
  const float* ndb = nd_ws + (size_t)b * NPTS;
  for (int q = tid; q < 1024; q += 256)
    *(float4*)&ndl[q * 4] = *(const float4*)(ndb + q * 4);
  __syncthreads();
  const int i = i0 + tid;
  const float ndi = ndl[i];
  int rank = 0;
  for (int j = 0; j < 4096; j += 4) {
    float4 v = *(const float4*)&ndl[j];
    rank += (v.x < ndi) || (v.x == ndi && (j + 0) < i);
    rank += (v.y < ndi) || (v.y == ndi && (j + 1) < i);
    rank += (v.z < ndi) || (v.z == ndi && (j + 2) < i);
    rank += (v.w < ndi) || (v.w == ndi && (j + 3) < i);
  }
  se_ws[(size_t)b * NPTS + rank] = e_in[(size_t)b * NPTS + i];
}

// ---------------------------------------------------------------------------
// Kernel 4: per-batch scalar metrics
// ---------------------------------------------------------------------------
__device__ __forceinline__ float block_sum(float v, float* red, int tid) {
  red[tid] = v;
  __syncthreads();
  for (int s = 512; s > 0; s >>= 1) {
    if (tid < s) red[tid] += red[tid + s];
    __syncthreads();
  }
  float r = red[0];
  __syncthreads();
  return r;
}
__device__ __forceinline__ float block_max(float v, float* red, int tid) {
  red[tid] = v;
  __syncthreads();
  for (int s = 512; s > 0; s >>= 1) {
    if (tid < s) red[tid] = fmaxf(red[tid], red[tid + s]);
    __syncthreads();
  }
  float r = red[0];
  __syncthreads();
  return r;
}

__global__ __launch_bounds__(1024) void metrics_kernel(
    const float* __restrict__ e_in, const float* __restrict__ nd_ws,
    const float* __restrict__ se_ws, float* __restrict__ metrics_out) {
  __shared__ __align__(16) float el[4096], ndl[4096], sel[4096];
  __shared__ float red[1024];
  __shared__ int redi[1024];
  const int tid = threadIdx.x;
  const int b = blockIdx.x;
  const float* eb = e_in + (size_t)b * NPTS;
  const float* ndb = nd_ws + (size_t)b * NPTS;
  const float* seb = se_ws + (size_t)b * NPTS;
  *(float4*)&el[tid * 4] = *(const float4*)(eb + tid * 4);
  *(float4*)&ndl[tid * 4] = *(const float4*)(ndb + tid * 4);
  *(float4*)&sel[tid * 4] = *(const float4*)(seb + tid * 4);
  __syncthreads();

  float pe = 0.f, pnd = 0.f;
  for (int p = tid; p < 4096; p += 1024) { pe += el[p]; pnd += ndl[p]; }
  float me = block_sum(pe, red, tid) / 4096.f;
  float mnd = block_sum(pnd, red, tid) / 4096.f;

  float sxx = 0.f, syy = 0.f, sxy = 0.f, mx = -FLT_MAX;
  float bestv = FLT_MAX;
  int besti = 0x7fffffff;
  for (int p = tid; p < 4096; p += 1024) {
    float de = el[p] - me, dn = ndl[p] - mnd;
    syy += de * de;
    sxx += dn * dn;
    sxy += de * dn;
    mx = fmaxf(mx, el[p]);
    if (ndl[p] < bestv || (ndl[p] == bestv && p < besti)) { bestv = ndl[p]; besti = p; }
  }
  float fr = 0.f;
  for (int p = tid; p < 4095; p += 1024) fr += (sel[p + 1] > sel[p]) ? 1.f : 0.f;

  sxx = block_sum(sxx, red, tid);
  syy = block_sum(syy, red, tid);
  sxy = block_sum(sxy, red, tid);
  mx = block_max(mx, red, tid);
  fr = block_sum(fr, red, tid);

  red[tid] = bestv;
  redi[tid] = besti;
  __syncthreads();
  for (int s = 512; s > 0; s >>= 1) {
    if (tid < s) {
      float ov = red[tid + s];
      int oi = redi[tid + s];
      if (ov < red[tid] || (ov == red[tid] && oi < redi[tid])) { red[tid] = ov; redi[tid] = oi; }
    }
    __syncthreads();
  }
  if (tid == 0) {
    float ne = el[redi[0]];
    metrics_out[b * 5 + 0] = mx - ne;
    metrics_out[b * 5 + 1] = sqrtf(syy / 4095.f);
    metrics_out[b * 5 + 2] = sxy / sqrtf(sxx * syy);
    metrics_out[b * 5 + 3] = fr / 4095.f;
    metrics_out[b * 5 + 4] = ne;
  }
}

// ---------------------------------------------------------------------------
extern "C" void kernel_launch(void* const* d_in, const int* in_sizes, int n_in,
                              void* d_out, int out_size, void* d_ws, size_t ws_size,
                              hipStream_t stream) {
  const float* conf = (const float*)d_in[0];
  const float* native = (const float*)d_in[1];
  const float* We1 = (const float*)d_in[2];
  const float* be1 = (const float*)d_in[3];
  const float* We2 = (const float*)d_in[4];
  const float* be2 = (const float*)d_in[5];
  const float* We3 = (const float*)d_in[6];
  const float* be3 = (const float*)d_in[7];
  const float* Ws1 = (const float*)d_in[8];
  const float* bs1 = (const float*)d_in[9];
  const float* Ws2 = (const float*)d_in[10];
  const float* bs2 = (const float*)d_in[11];

  float* out = (float*)d_out;
  float* e_out = out;                 // [0, 16384)
  float* basin_out = out + BN;        // [16384, 32768)
  float* depth_out = out + 2 * BN;    // [32768, 49152)
  float* width_out = out + 3 * BN;    // [49152, 65536)
  float* logits_out = out + 4 * BN;   // [65536, 163840)
  float* metrics_out = out + 10 * BN; // [163840, 163860)

  // ws layout (floats): sq | nd | se | topd(40BN) | topi(40BN ushort = 20BN)
  float* wsf = (float*)d_ws;
  float* sq_ws = wsf;
  float* nd_ws = wsf + BN;
  float* se_ws = wsf + 2 * (size_t)BN;
  float* topd = wsf + 3 * (size_t)BN;
  unsigned short* topi = (unsigned short*)(wsf + 43 * (size_t)BN);

  mlp_kernel<<<dim3(512), dim3(256), 0, stream>>>(
      conf, native, We1, be1, We2, be2, We3, be3, Ws1, bs1, Ws2, bs2,
      e_out, logits_out, sq_ws, nd_ws);
  topk_part_kernel<<<dim3(64, JS, NBATCH), dim3(256), 0, stream>>>(
      conf, sq_ws, topd, topi);
  topk_merge_kernel<<<dim3(BN / 256), dim3(256), 0, stream>>>(
      topd, topi, e_out, basin_out, depth_out, width_out);
  rank_kernel<<<dim3(16, NBATCH), dim3(256), 0, stream>>>(nd_ws, e_out, se_ws);
  metrics_kernel<<<dim3(NBATCH), dim3(1024), 0, stream>>>(e_out, nd_ws, se_ws, metrics_out);
}

// Round 6
// 376.692 us; speedup vs baseline: 14.4802x; 1.1606x over previous
//
#include <hip/hip_runtime.h>
#include <float.h>
#include <math.h>

#define NPTS 4096
#define NBATCH 4
#define BN (NBATCH * NPTS)   // 16384
#define EPSC 1e-12f
#define JS 4                 // j-dimension splits for the topk kernel

__device__ __forceinline__ bool dless(float d1, int i1, float d2, int i2) {
  return (d1 < d2) || ((d1 == d2) && (i1 < i2));
}

// ---------------------------------------------------------------------------
// Kernel 1: fused MLP — e, logits, sq, nd.  512 blocks x 256 thr, 32 pts/block
// ---------------------------------------------------------------------------
__device__ __forceinline__ void gemm32x128(const float (*A)[64], const float* W,
                                           const float* bias, float (*O)[128], int tid) {
  const int pi = (tid >> 5) << 2;   // point quad
  const int ci = (tid & 31) << 2;   // col quad
  float acc[4][4] = {};
  for (int k0 = 0; k0 < 64; k0 += 4) {
    alignas(16) float av[4][4], wv[4][4];
#pragma unroll
    for (int r = 0; r < 4; ++r) *(float4*)av[r] = *(const float4*)&A[pi + r][k0];
#pragma unroll
    for (int kk = 0; kk < 4; ++kk) *(float4*)wv[kk] = *(const float4*)&W[(k0 + kk) * 128 + ci];
#pragma unroll
    for (int kk = 0; kk < 4; ++kk)
#pragma unroll
      for (int r = 0; r < 4; ++r)
#pragma unroll
        for (int c = 0; c < 4; ++c)
          acc[r][c] = fmaf(av[r][kk], wv[kk][c], acc[r][c]);
  }
#pragma unroll
  for (int r = 0; r < 4; ++r)
#pragma unroll
    for (int c = 0; c < 4; ++c)
      O[pi + r][ci + c] = fmaxf(acc[r][c] + bias[ci + c], 0.f);
}

__global__ __launch_bounds__(256) void mlp_kernel(
    const float* __restrict__ conf, const float* __restrict__ native,
    const float* __restrict__ We1, const float* __restrict__ be1,
    const float* __restrict__ We2, const float* __restrict__ be2,
    const float* __restrict__ We3, const float* __restrict__ be3,
    const float* __restrict__ Ws1, const float* __restrict__ bs1,
    const float* __restrict__ Ws2, const float* __restrict__ bs2,
    float* __restrict__ e_out, float* __restrict__ logits_out,
    float* __restrict__ sq_ws, float* __restrict__ nd_ws) {
  __shared__ __align__(16) float Wbuf[8192];       // 32 KB (We1 / We2 / Ws1)
  __shared__ __align__(16) float confs[32][64];    // 8 KB (later reused for h2)
  __shared__ __align__(16) float hbuf[32][128];    // 16 KB (g then h1)
  __shared__ float nat[64];
  __shared__ float b1s[128], b2s[64], w3s[64], bs1s[128], ws2s[768], bs2s[6];
  __shared__ float be3s;

  const int tid = threadIdx.x;
  const int blk = blockIdx.x;       // 0..511
  const int b = blk >> 7;           // 128 blocks per batch
  const int pbase = (blk & 127) * 32;
  const float* confb = conf + ((size_t)b * NPTS + pbase) * 64;

  for (int q = tid; q < 512; q += 256) {
    float4 v = *(const float4*)(confb + q * 4);
    *(float4*)&confs[q >> 4][(q & 15) << 2] = v;
  }
  if (tid < 64) nat[tid] = native[b * 64 + tid];
  if (tid < 128) b1s[tid] = be1[tid];
  if (tid < 64) b2s[tid] = be2[tid];
  if (tid < 64) w3s[tid] = We3[tid];
  if (tid < 128) bs1s[tid] = bs1[tid];
  for (int q = tid; q < 768; q += 256) ws2s[q] = Ws2[q];
  if (tid < 6) bs2s[tid] = bs2[tid];
  if (tid == 0) be3s = be3[0];
  for (int q = tid; q < 2048; q += 256)
    *(float4*)&Wbuf[q * 4] = *(const float4*)(Ws1 + q * 4);
  __syncthreads();

  // sq & nd — numpy-pairwise style: rounded products, 8 accumulators
  if (tid < 32) {
    float rs_[8], rn_[8];
#pragma unroll
    for (int u = 0; u < 8; ++u) {
      float c = confs[tid][u];
      rs_[u] = c * c;
      float d = c - nat[u];
      rn_[u] = d * d;
    }
    for (int d0 = 8; d0 < 64; d0 += 8) {
#pragma unroll
      for (int u = 0; u < 8; ++u) {
        float c = confs[tid][d0 + u];
        rs_[u] += c * c;
        float d = c - nat[d0 + u];
        rn_[u] += d * d;
      }
    }
    float s = ((rs_[0] + rs_[1]) + (rs_[2] + rs_[3])) + ((rs_[4] + rs_[5]) + (rs_[6] + rs_[7]));
    float n = ((rn_[0] + rn_[1]) + (rn_[2] + rn_[3])) + ((rn_[4] + rn_[5]) + (rn_[6] + rn_[7]));
    sq_ws[(size_t)b * NPTS + pbase + tid] = s;
    nd_ws[(size_t)b * NPTS + pbase + tid] = sqrtf(n);
  }

  gemm32x128(confs, Wbuf, bs1s, hbuf, tid);     // g = relu(conf @ Ws1 + bs1)
  __syncthreads();

  for (int q = tid; q < 2048; q += 256)         // reload Wbuf <- We1
    *(float4*)&Wbuf[q * 4] = *(const float4*)(We1 + q * 4);
  if (tid < 192) {
    int p = tid / 6, s = tid % 6;
    float acc = 0.f;
#pragma unroll 8
    for (int h = 0; h < 128; ++h)
      acc = fmaf(hbuf[p][h], ws2s[h * 6 + s], acc);
    logits_out[((size_t)b * NPTS + pbase + p) * 6 + s] = acc + bs2s[s];
  }
  __syncthreads();

  gemm32x128(confs, Wbuf, b1s, hbuf, tid);      // h1 = relu(conf @ We1 + be1)
  __syncthreads();

  for (int q = tid; q < 2048; q += 256)
    *(float4*)&Wbuf[q * 4] = *(const float4*)(We2 + q * 4);
  __syncthreads();

  // h2 = relu(h1 @ We2 + be2) -> confs
  if (tid < 128) {
    const int pi = (tid >> 4) << 2;
    const int ci = (tid & 15) << 2;
    float acc[4][4] = {};
    for (int k0 = 0; k0 < 128; k0 += 4) {
      alignas(16) float av[4][4], wv[4][4];
#pragma unroll
      for (int r = 0; r < 4; ++r) *(float4*)av[r] = *(const float4*)&hbuf[pi + r][k0];
#pragma unroll
      for (int kk = 0; kk < 4; ++kk) *(float4*)wv[kk] = *(const float4*)&Wbuf[(k0 + kk) * 64 + ci];
#pragma unroll
      for (int kk = 0; kk < 4; ++kk)
#pragma unroll
        for (int r = 0; r < 4; ++r)
#pragma unroll
          for (int c = 0; c < 4; ++c)
            acc[r][c] = fmaf(av[r][kk], wv[kk][c], acc[r][c]);
    }
#pragma unroll
    for (int r = 0; r < 4; ++r)
#pragma unroll
      for (int c = 0; c < 4; ++c)
        confs[pi + r][ci + c] = fmaxf(acc[r][c] + b2s[ci + c], 0.f);
  }
  __syncthreads();

  if (tid < 32) {                               // e = h2 @ We3 + be3
    float acc = 0.f;
#pragma unroll
    for (int k = 0; k < 64; ++k)
      acc = fmaf(confs[tid][k], w3s[k], acc);
    e_out[(size_t)b * NPTS + pbase + tid] = acc + be3s;
  }
}

// ---------------------------------------------------------------------------
// Distance pass (split-j): per (64-row block, 1024-col chunk) top-10.
// key64 = (f32bits(d)<<32)|j : u64 order == (d, j) lex order (d >= 0 always).
// launch_bounds(256,1): cap 256 VGPRs (observed mapping cap = 512/(2N)) —
// lets av/acc/lk stay register-resident; 64-reg squeeze caused re-reads.
// Separate Ds buffer: GEMM reads Bs, dist writes Ds -> 2 syncs/tile (was 4).
// ---------------------------------------------------------------------------
#define TOPK_INS(d_, j_)                                                      \
  do {                                                                        \
    if ((d_) <= thrf) {                                                       \
      unsigned long long cur =                                                \
          (((unsigned long long)__float_as_uint(d_)) << 32) |                 \
          (unsigned long long)(unsigned)(j_);                                 \
      if (cur < lk[9]) {                                                      \
        _Pragma("unroll")                                                     \
        for (int k = 0; k < 10; ++k) {                                        \
          bool lt = cur < lk[k];                                              \
          unsigned long long mn = lt ? cur : lk[k];                           \
          cur = lt ? lk[k] : cur;                                             \
          lk[k] = mn;                                                         \
        }                                                                     \
      }                                                                       \
    }                                                                         \
  } while (0)

// micro-GEMM: 4x4 outputs, av staged 16 regs, bv staged 4 regs per column.
// fmaf order (k0 asc, kk asc) identical across rounds -> bit-identical d.
#define DIST_GEMM(ACC)                                                        \
  do {                                                                        \
    for (int k0 = 0; k0 < 64; k0 += 4) {                                      \
      alignas(16) float av[4][4];                                             \
      _Pragma("unroll")                                                       \
      for (int r = 0; r < 4; ++r)                                             \
        *(float4*)av[r] = *(const float4*)&As[tr + 16 * r][k0];               \
      _Pragma("unroll")                                                       \
      for (int c = 0; c < 4; ++c) {                                           \
        alignas(16) float bv[4];                                              \
        *(float4*)bv = *(const float4*)&Bs[tc + 16 * c][k0];                  \
        _Pragma("unroll")                                                     \
        for (int kk = 0; kk < 4; ++kk)                                        \
          _Pragma("unroll")                                                   \
          for (int r = 0; r < 4; ++r)                                         \
            ACC[r][c] = fmaf(av[r][kk], bv[kk], ACC[r][c]);                   \
      }                                                                       \
    }                                                                         \
  } while (0)

__global__ __launch_bounds__(256, 1) void topk_part_kernel(
    const float* __restrict__ conf, const float* __restrict__ sq_ws,
    float* __restrict__ topd, unsigned short* __restrict__ topi) {
  __shared__ __align__(16) float As[64][68];   // 17.4 KB conf rows (reused as mrgD)
  __shared__ __align__(16) float Bs[64][68];   // 17.4 KB conf cols (reused as mrgI)
  __shared__ __align__(16) float Ds[64][68];   // 17.4 KB dist tile
  __shared__ float sqa[64], sqjs[64];

  const int tid = threadIdx.x;
  const int b = blockIdx.z;
  const int i0 = blockIdx.x * 64;
  const int jbase = blockIdx.y * (NPTS / JS);
  const float* confb = conf + (size_t)b * NPTS * 64;
  const float* sqb = sq_ws + (size_t)b * NPTS;

  for (int q = tid; q < 1024; q += 256) {
    int rw = q >> 4, k4 = (q & 15) << 2;
    *(float4*)&As[rw][k4] = *(const float4*)(confb + (size_t)(i0 + rw) * 64 + k4);
  }
  if (tid < 64) sqa[tid] = sqb[i0 + tid];

  const int tc = tid & 15, tr = tid >> 4;
  const int row = tid >> 2, q4 = tid & 3;

  unsigned long long lk[10];
#pragma unroll
  for (int k = 0; k < 10; ++k) lk[k] = 0x7F7FFFFF7FFFFFFFULL;  // (FLT_MAX, INT_MAX)
  float thrf = FLT_MAX;

  for (int jt = 0; jt < NPTS / JS / 64; ++jt) {   // 16 tiles of 64
    const int j0 = jbase + jt * 64;
    for (int q = tid; q < 1024; q += 256) {
      int rw = q >> 4, k4 = (q & 15) << 2;
      *(float4*)&Bs[rw][k4] = *(const float4*)(confb + (size_t)(j0 + rw) * 64 + k4);
    }
    if (tid < 64) sqjs[tid] = sqb[j0 + tid];
    __syncthreads();   // Bs/sqjs ready (covers As/sqa on jt=0)

    float acc[4][4] = {};
    DIST_GEMM(acc);
#pragma unroll
    for (int r = 0; r < 4; ++r)
#pragma unroll
      for (int c = 0; c < 4; ++c) {
        int rw = tr + 16 * r, cl = tc + 16 * c;
        float d2 = sqa[rw] + sqjs[cl] - 2.f * acc[r][c];
        Ds[rw][cl] = sqrtf(fmaxf(d2, EPSC));
      }
    __syncthreads();   // Ds ready; Bs fully consumed (safe to restage next iter)
    {
#pragma unroll
      for (int cc = 0; cc < 4; ++cc) {
        float4 v = *(const float4*)&Ds[row][q4 * 16 + cc * 4];
        const int jb = j0 + q4 * 16 + cc * 4;
        TOPK_INS(v.x, jb + 0);
        TOPK_INS(v.y, jb + 1);
        TOPK_INS(v.z, jb + 2);
        TOPK_INS(v.w, jb + 3);
      }
      // refresh row-wide filter bound: min of the 4 siblings' 10th d
      float t = __uint_as_float((unsigned)(lk[9] >> 32));
      t = fminf(t, __shfl_xor(t, 1, 4));
      t = fminf(t, __shfl_xor(t, 2, 4));
      thrf = t;
    }
  }
  __syncthreads();

  // merge 4 per-thread sorted lists per row -> chunk top-10, write to ws
  float* mrgD = &As[0][0];       // 64*40 floats
  int* mrgI = (int*)&Bs[0][0];   // 64*40 ints
  {
#pragma unroll
    for (int k = 0; k < 10; ++k) {
      mrgD[row * 40 + q4 * 10 + k] = __uint_as_float((unsigned)(lk[k] >> 32));
      mrgI[row * 40 + q4 * 10 + k] = (int)(unsigned)(lk[k] & 0xFFFFFFFFu);
    }
  }
  __syncthreads();
  if (tid < 64) {
    const int base = tid * 40;
    int h0 = 0, h1 = 0, h2 = 0, h3 = 0;
    const size_t obase = (((size_t)b * NPTS + i0 + tid) * JS + blockIdx.y) * 10;
    for (int k = 0; k < 10; ++k) {
      float bd = FLT_MAX; int bi = 0x7fffffff; int bl = -1;
      { float d = mrgD[base + h0];      int ii = mrgI[base + h0];      if (dless(d, ii, bd, bi)) { bd = d; bi = ii; bl = 0; } }
      { float d = mrgD[base + 10 + h1]; int ii = mrgI[base + 10 + h1]; if (dless(d, ii, bd, bi)) { bd = d; bi = ii; bl = 1; } }
      { float d = mrgD[base + 20 + h2]; int ii = mrgI[base + 20 + h2]; if (dless(d, ii, bd, bi)) { bd = d; bi = ii; bl = 2; } }
      { float d = mrgD[base + 30 + h3]; int ii = mrgI[base + 30 + h3]; if (dless(d, ii, bd, bi)) { bd = d; bi = ii; bl = 3; } }
      h0 += (bl == 0); h1 += (bl == 1); h2 += (bl == 2); h3 += (bl == 3);
      topd[obase + k] = bd;
      topi[obase + k] = (unsigned short)bi;
    }
  }
}

// ---------------------------------------------------------------------------
// Merge JS chunk top-10s per row -> r, is_basin, depth, width.
// mask = {d < r} is exactly the members of the top-10 with d < d_9 (<=9+self):
// nothing outside the 10 lex-smallest can have d < d_9.
// ---------------------------------------------------------------------------
__global__ __launch_bounds__(256) void topk_merge_kernel(
    const float* __restrict__ topd, const unsigned short* __restrict__ topi,
    const float* __restrict__ e_in, float* __restrict__ basin_out,
    float* __restrict__ depth_out, float* __restrict__ width_out) {
  const int g = blockIdx.x * 256 + threadIdx.x;   // 0..16383
  const int b = g >> 12;
  const float* eb = e_in + (size_t)b * NPTS;
  const float* td = topd + (size_t)g * (JS * 10);
  const unsigned short* ti = topi + (size_t)g * (JS * 10);
  const float e_i = eb[g & (NPTS - 1)];
  int h0 = 0, h1 = 0, h2 = 0, h3 = 0;
  float dk[10];
  int ik[10];
#pragma unroll
  for (int k = 0; k < 10; ++k) {
    float bd = FLT_MAX; int bi = 0x7fffffff; int bl = -1;
    { float d = td[h0];      int ii = ti[h0];      if (dless(d, ii, bd, bi)) { bd = d; bi = ii; bl = 0; } }
    { float d = td[10 + h1]; int ii = ti[10 + h1]; if (dless(d, ii, bd, bi)) { bd = d; bi = ii; bl = 1; } }
    { float d = td[20 + h2]; int ii = ti[20 + h2]; if (dless(d, ii, bd, bi)) { bd = d; bi = ii; bl = 2; } }
    { float d = td[30 + h3]; int ii = ti[30 + h3]; if (dless(d, ii, bd, bi)) { bd = d; bi = ii; bl = 3; } }
    h0 += (bl == 0); h1 += (bl == 1); h2 += (bl == 2); h3 += (bl == 3);
    dk[k] = bd;
    ik[k] = bi;
  }
  const float r = dk[9];
  bool basin = true;
  float mx = -FLT_MAX, sum = 0.f, cnt = 0.f;
#pragma unroll
  for (int k = 0; k < 10; ++k) {
    float ev = eb[ik[k]];
    if (dk[k] < r) { mx = fmaxf(mx, ev); sum += dk[k]; cnt += 1.f; }
    if (k >= 1) basin = basin && (e_i <= ev);
  }
  basin_out[g] = basin ? 1.f : 0.f;
  depth_out[g] = mx - e_i;
  width_out[g] = sum / cnt;
}

// ---------------------------------------------------------------------------
// Kernel 3: rank by nd (stable), scatter e into sorted order.
// 4 threads per i, each scans a 1024-j partition; exact integer rank sum.
// ---------------------------------------------------------------------------
__global__ __launch_bounds__(256) void rank_kernel(
    const float* __restrict__ nd_ws, const float* __restrict__ e_in,
    float* __restrict__ se_ws) {
  __shared__ __align__(16) float ndl[4096];
  const int tid = threadIdx.x;
  const int b = blockIdx.y;
  const int i0 = blockIdx.x * 64;
  const float* ndb = nd_ws + (size_t)b * NPTS;
  for (int q = tid; q < 1024; q += 256)
    *(float4*)&ndl[q * 4] = *(const float4*)(ndb + q * 4);
  __syncthreads();
  const int i = i0 + (tid >> 2);
  const int qp = tid & 3;
  const float ndi = ndl[i];
  int rank = 0;
  for (int j = qp * 1024; j < qp * 1024 + 1024; j += 4) {
    float4 v = *(const float4*)&ndl[j];
    rank += (v.x < ndi) || (v.x == ndi && (j + 0) < i);
    rank += (v.y < ndi) || (v.y == ndi && (j + 1) < i);
    rank += (v.z < ndi) || (v.z == ndi && (j + 2) < i);
    rank += (v.w < ndi) || (v.w == ndi && (j + 3) < i);
  }
  rank += __shfl_xor(rank, 1, 4);
  rank += __shfl_xor(rank, 2, 4);
  if (qp == 0) se_ws[(size_t)b * NPTS + rank] = e_in[(size_t)b * NPTS + i];
}

// ---------------------------------------------------------------------------
// Kernel 4: per-batch scalar metrics
// ---------------------------------------------------------------------------
__device__ __forceinline__ float block_sum(float v, float* red, int tid) {
  red[tid] = v;
  __syncthreads();
  for (int s = 512; s > 0; s >>= 1) {
    if (tid < s) red[tid] += red[tid + s];
    __syncthreads();
  }
  float r = red[0];
  __syncthreads();
  return r;
}
__device__ __forceinline__ float block_max(float v, float* red, int tid) {
  red[tid] = v;
  __syncthreads();
  for (int s = 512; s > 0; s >>= 1) {
    if (tid < s) red[tid] = fmaxf(red[tid], red[tid + s]);
    __syncthreads();
  }
  float r = red[0];
  __syncthreads();
  return r;
}

__global__ __launch_bounds__(1024) void metrics_kernel(
    const float* __restrict__ e_in, const float* __restrict__ nd_ws,
    const float* __restrict__ se_ws, float* __restrict__ metrics_out) {
  __shared__ __align__(16) float el[4096], ndl[4096], sel[4096];
  __shared__ float red[1024];
  __shared__ int redi[1024];
  const int tid = threadIdx.x;
  const int b = blockIdx.x;
  const float* eb = e_in + (size_t)b * NPTS;
  const float* ndb = nd_ws + (size_t)b * NPTS;
  const float* seb = se_ws + (size_t)b * NPTS;
  *(float4*)&el[tid * 4] = *(const float4*)(eb + tid * 4);
  *(float4*)&ndl[tid * 4] = *(const float4*)(ndb + tid * 4);
  *(float4*)&sel[tid * 4] = *(const float4*)(seb + tid * 4);
  __syncthreads();

  float pe = 0.f, pnd = 0.f;
  for (int p = tid; p < 4096; p += 1024) { pe += el[p]; pnd += ndl[p]; }
  float me = block_sum(pe, red, tid) / 4096.f;
  float mnd = block_sum(pnd, red, tid) / 4096.f;

  float sxx = 0.f, syy = 0.f, sxy = 0.f, mx = -FLT_MAX;
  float bestv = FLT_MAX;
  int besti = 0x7fffffff;
  for (int p = tid; p < 4096; p += 1024) {
    float de = el[p] - me, dn = ndl[p] - mnd;
    syy += de * de;
    sxx += dn * dn;
    sxy += de * dn;
    mx = fmaxf(mx, el[p]);
    if (ndl[p] < bestv || (ndl[p] == bestv && p < besti)) { bestv = ndl[p]; besti = p; }
  }
  float fr = 0.f;
  for (int p = tid; p < 4095; p += 1024) fr += (sel[p + 1] > sel[p]) ? 1.f : 0.f;

  sxx = block_sum(sxx, red, tid);
  syy = block_sum(syy, red, tid);
  sxy = block_sum(sxy, red, tid);
  mx = block_max(mx, red, tid);
  fr = block_sum(fr, red, tid);

  red[tid] = bestv;
  redi[tid] = besti;
  __syncthreads();
  for (int s = 512; s > 0; s >>= 1) {
    if (tid < s) {
      float ov = red[tid + s];
      int oi = redi[tid + s];
      if (ov < red[tid] || (ov == red[tid] && oi < redi[tid])) { red[tid] = ov; redi[tid] = oi; }
    }
    __syncthreads();
  }
  if (tid == 0) {
    float ne = el[redi[0]];
    metrics_out[b * 5 + 0] = mx - ne;
    metrics_out[b * 5 + 1] = sqrtf(syy / 4095.f);
    metrics_out[b * 5 + 2] = sxy / sqrtf(sxx * syy);
    metrics_out[b * 5 + 3] = fr / 4095.f;
    metrics_out[b * 5 + 4] = ne;
  }
}

// ---------------------------------------------------------------------------
extern "C" void kernel_launch(void* const* d_in, const int* in_sizes, int n_in,
                              void* d_out, int out_size, void* d_ws, size_t ws_size,
                              hipStream_t stream) {
  const float* conf = (const float*)d_in[0];
  const float* native = (const float*)d_in[1];
  const float* We1 = (const float*)d_in[2];
  const float* be1 = (const float*)d_in[3];
  const float* We2 = (const float*)d_in[4];
  const float* be2 = (const float*)d_in[5];
  const float* We3 = (const float*)d_in[6];
  const float* be3 = (const float*)d_in[7];
  const float* Ws1 = (const float*)d_in[8];
  const float* bs1 = (const float*)d_in[9];
  const float* Ws2 = (const float*)d_in[10];
  const float* bs2 = (const float*)d_in[11];

  float* out = (float*)d_out;
  float* e_out = out;                 // [0, 16384)
  float* basin_out = out + BN;        // [16384, 32768)
  float* depth_out = out + 2 * BN;    // [32768, 49152)
  float* width_out = out + 3 * BN;    // [49152, 65536)
  float* logits_out = out + 4 * BN;   // [65536, 163840)
  float* metrics_out = out + 10 * BN; // [163840, 163860)

  // ws layout (floats): sq | nd | se | topd(40BN) | topi(40BN ushort = 20BN)
  float* wsf = (float*)d_ws;
  float* sq_ws = wsf;
  float* nd_ws = wsf + BN;
  float* se_ws = wsf + 2 * (size_t)BN;
  float* topd = wsf + 3 * (size_t)BN;
  unsigned short* topi = (unsigned short*)(wsf + 43 * (size_t)BN);

  mlp_kernel<<<dim3(512), dim3(256), 0, stream>>>(
      conf, native, We1, be1, We2, be2, We3, be3, Ws1, bs1, Ws2, bs2,
      e_out, logits_out, sq_ws, nd_ws);
  topk_part_kernel<<<dim3(64, JS, NBATCH), dim3(256), 0, stream>>>(
      conf, sq_ws, topd, topi);
  topk_merge_kernel<<<dim3(BN / 256), dim3(256), 0, stream>>>(
      topd, topi, e_out, basin_out, depth_out, width_out);
  rank_kernel<<<dim3(64, NBATCH), dim3(256), 0, stream>>>(nd_ws, e_out, se_ws);
  metrics_kernel<<<dim3(NBATCH), dim3(1024), 0, stream>>>(e_out, nd_ws, se_ws, metrics_out);
}

// Round 7
// 327.982 us; speedup vs baseline: 16.6307x; 1.1485x over previous
//
#include <hip/hip_runtime.h>
#include <float.h>
#include <math.h>

#define NPTS 4096
#define NBATCH 4
#define BN (NBATCH * NPTS)   // 16384
#define EPSC 1e-12f
#define JS 4                 // j-dimension splits for the topk kernel

typedef __attribute__((ext_vector_type(8))) short bfrag;   // 8 bf16 (4 VGPR) MFMA operand
typedef __attribute__((ext_vector_type(4))) short bhalf;   // 8B half-fragment
typedef __attribute__((ext_vector_type(4))) float f32x4;   // MFMA accumulator

#define MFMA(A, B, C) __builtin_amdgcn_mfma_f32_16x16x32_bf16((A), (B), (C), 0, 0, 0)

__device__ __forceinline__ bool dless(float d1, int i1, float d2, int i2) {
  return (d1 < d2) || ((d1 == d2) && (i1 < i2));
}

// RN-even fp32->bf16 (branch-free), and back
__device__ __forceinline__ unsigned short f2bf(float x) {
  unsigned b = __float_as_uint(x);
  return (unsigned short)((b + 0x7FFFu + ((b >> 16) & 1u)) >> 16);
}
__device__ __forceinline__ float bf2f(unsigned short u) {
  return __uint_as_float(((unsigned)u) << 16);
}
// exact-ish 3-way split: x ~= bf(x0)+bf(x1)+bf(x2), residual ~2^-25|x|
__device__ __forceinline__ void bf3(float x, unsigned short& u0, unsigned short& u1,
                                    unsigned short& u2) {
  u0 = f2bf(x);
  float r = x - bf2f(u0);
  u1 = f2bf(r);
  r = r - bf2f(u1);
  u2 = f2bf(r);
}

// ---------------------------------------------------------------------------
// Kernel 1: fused MLP — e, logits, sq, nd.  512 blocks x 256 thr, 32 pts/block
// ---------------------------------------------------------------------------
__device__ __forceinline__ void gemm32x128(const float (*A)[64], const float* W,
                                           const float* bias, float (*O)[128], int tid) {
  const int pi = (tid >> 5) << 2;   // point quad
  const int ci = (tid & 31) << 2;   // col quad
  float acc[4][4] = {};
  for (int k0 = 0; k0 < 64; k0 += 4) {
    alignas(16) float av[4][4], wv[4][4];
#pragma unroll
    for (int r = 0; r < 4; ++r) *(float4*)av[r] = *(const float4*)&A[pi + r][k0];
#pragma unroll
    for (int kk = 0; kk < 4; ++kk) *(float4*)wv[kk] = *(const float4*)&W[(k0 + kk) * 128 + ci];
#pragma unroll
    for (int kk = 0; kk < 4; ++kk)
#pragma unroll
      for (int r = 0; r < 4; ++r)
#pragma unroll
        for (int c = 0; c < 4; ++c)
          acc[r][c] = fmaf(av[r][kk], wv[kk][c], acc[r][c]);
  }
#pragma unroll
  for (int r = 0; r < 4; ++r)
#pragma unroll
    for (int c = 0; c < 4; ++c)
      O[pi + r][ci + c] = fmaxf(acc[r][c] + bias[ci + c], 0.f);
}

__global__ __launch_bounds__(256) void mlp_kernel(
    const float* __restrict__ conf, const float* __restrict__ native,
    const float* __restrict__ We1, const float* __restrict__ be1,
    const float* __restrict__ We2, const float* __restrict__ be2,
    const float* __restrict__ We3, const float* __restrict__ be3,
    const float* __restrict__ Ws1, const float* __restrict__ bs1,
    const float* __restrict__ Ws2, const float* __restrict__ bs2,
    float* __restrict__ e_out, float* __restrict__ logits_out,
    float* __restrict__ sq_ws, float* __restrict__ nd_ws) {
  __shared__ __align__(16) float Wbuf[8192];       // 32 KB (We1 / We2 / Ws1)
  __shared__ __align__(16) float confs[32][64];    // 8 KB (later reused for h2)
  __shared__ __align__(16) float hbuf[32][128];    // 16 KB (g then h1)
  __shared__ float nat[64];
  __shared__ float b1s[128], b2s[64], w3s[64], bs1s[128], ws2s[768], bs2s[6];
  __shared__ float be3s;

  const int tid = threadIdx.x;
  const int blk = blockIdx.x;       // 0..511
  const int b = blk >> 7;           // 128 blocks per batch
  const int pbase = (blk & 127) * 32;
  const float* confb = conf + ((size_t)b * NPTS + pbase) * 64;

  for (int q = tid; q < 512; q += 256) {
    float4 v = *(const float4*)(confb + q * 4);
    *(float4*)&confs[q >> 4][(q & 15) << 2] = v;
  }
  if (tid < 64) nat[tid] = native[b * 64 + tid];
  if (tid < 128) b1s[tid] = be1[tid];
  if (tid < 64) b2s[tid] = be2[tid];
  if (tid < 64) w3s[tid] = We3[tid];
  if (tid < 128) bs1s[tid] = bs1[tid];
  for (int q = tid; q < 768; q += 256) ws2s[q] = Ws2[q];
  if (tid < 6) bs2s[tid] = bs2[tid];
  if (tid == 0) be3s = be3[0];
  for (int q = tid; q < 2048; q += 256)
    *(float4*)&Wbuf[q * 4] = *(const float4*)(Ws1 + q * 4);
  __syncthreads();

  // sq & nd — numpy-pairwise style: rounded products, 8 accumulators
  if (tid < 32) {
    float rs_[8], rn_[8];
#pragma unroll
    for (int u = 0; u < 8; ++u) {
      float c = confs[tid][u];
      rs_[u] = c * c;
      float d = c - nat[u];
      rn_[u] = d * d;
    }
    for (int d0 = 8; d0 < 64; d0 += 8) {
#pragma unroll
      for (int u = 0; u < 8; ++u) {
        float c = confs[tid][d0 + u];
        rs_[u] += c * c;
        float d = c - nat[d0 + u];
        rn_[u] += d * d;
      }
    }
    float s = ((rs_[0] + rs_[1]) + (rs_[2] + rs_[3])) + ((rs_[4] + rs_[5]) + (rs_[6] + rs_[7]));
    float n = ((rn_[0] + rn_[1]) + (rn_[2] + rn_[3])) + ((rn_[4] + rn_[5]) + (rn_[6] + rn_[7]));
    sq_ws[(size_t)b * NPTS + pbase + tid] = s;
    nd_ws[(size_t)b * NPTS + pbase + tid] = sqrtf(n);
  }

  gemm32x128(confs, Wbuf, bs1s, hbuf, tid);     // g = relu(conf @ Ws1 + bs1)
  __syncthreads();

  for (int q = tid; q < 2048; q += 256)         // reload Wbuf <- We1
    *(float4*)&Wbuf[q * 4] = *(const float4*)(We1 + q * 4);
  if (tid < 192) {
    int p = tid / 6, s = tid % 6;
    float acc = 0.f;
#pragma unroll 8
    for (int h = 0; h < 128; ++h)
      acc = fmaf(hbuf[p][h], ws2s[h * 6 + s], acc);
    logits_out[((size_t)b * NPTS + pbase + p) * 6 + s] = acc + bs2s[s];
  }
  __syncthreads();

  gemm32x128(confs, Wbuf, b1s, hbuf, tid);      // h1 = relu(conf @ We1 + be1)
  __syncthreads();

  for (int q = tid; q < 2048; q += 256)
    *(float4*)&Wbuf[q * 4] = *(const float4*)(We2 + q * 4);
  __syncthreads();

  // h2 = relu(h1 @ We2 + be2) -> confs
  if (tid < 128) {
    const int pi = (tid >> 4) << 2;
    const int ci = (tid & 15) << 2;
    float acc[4][4] = {};
    for (int k0 = 0; k0 < 128; k0 += 4) {
      alignas(16) float av[4][4], wv[4][4];
#pragma unroll
      for (int r = 0; r < 4; ++r) *(float4*)av[r] = *(const float4*)&hbuf[pi + r][k0];
#pragma unroll
      for (int kk = 0; kk < 4; ++kk) *(float4*)wv[kk] = *(const float4*)&Wbuf[(k0 + kk) * 64 + ci];
#pragma unroll
      for (int kk = 0; kk < 4; ++kk)
#pragma unroll
        for (int r = 0; r < 4; ++r)
#pragma unroll
          for (int c = 0; c < 4; ++c)
            acc[r][c] = fmaf(av[r][kk], wv[kk][c], acc[r][c]);
    }
#pragma unroll
    for (int r = 0; r < 4; ++r)
#pragma unroll
      for (int c = 0; c < 4; ++c)
        confs[pi + r][ci + c] = fmaxf(acc[r][c] + b2s[ci + c], 0.f);
  }
  __syncthreads();

  if (tid < 32) {                               // e = h2 @ We3 + be3
    float acc = 0.f;
#pragma unroll
    for (int k = 0; k < 64; ++k)
      acc = fmaf(confs[tid][k], w3s[k], acc);
    e_out[(size_t)b * NPTS + pbase + tid] = acc + be3s;
  }
}

// ---------------------------------------------------------------------------
// Distance pass (split-j), bf16x3 MFMA edition.
// S ~= A0B0 + A0B1 + A1B0 + A0B2 + A1B1 + A2B0 (residual ~2^-25, below the
// fp32-reorder noise we already carry vs the numpy reference).
// LDS ushort tiles, row stride 204 (16 rows x 204 us): 2xds_read_b64 frag
// loads are 8B-aligned and ~2-way-conflict-free (free per m136).
// D-frag mapping (m89): col = lane&15, row = (lane>>4)*4 + reg.
// ---------------------------------------------------------------------------
#define TOPK_INS(d_, j_)                                                      \
  do {                                                                        \
    if ((d_) <= thrf) {                                                       \
      unsigned long long cur =                                                \
          (((unsigned long long)__float_as_uint(d_)) << 32) |                 \
          (unsigned long long)(unsigned)(j_);                                 \
      if (cur < lk[9]) {                                                      \
        _Pragma("unroll")                                                     \
        for (int k = 0; k < 10; ++k) {                                        \
          bool lt = cur < lk[k];                                              \
          unsigned long long mn = lt ? cur : lk[k];                           \
          cur = lt ? lk[k] : cur;                                             \
          lk[k] = mn;                                                         \
        }                                                                     \
      }                                                                       \
    }                                                                         \
  } while (0)

// stage 64 fp32 conf rows -> bf16x3 LDS tile (levels at +0/+64/+128 us per row)
__device__ __forceinline__ void stage3(unsigned short* dst, const float* confb,
                                       int row0, int tid) {
  for (int q = tid; q < 1024; q += 256) {
    const int rw = q >> 4, k4 = (q & 15) << 2;
    float4 v = *(const float4*)(confb + (size_t)(row0 + rw) * 64 + k4);
    unsigned short x0, x1, x2, y0, y1, y2, z0, z1, z2, w0, w1, w2;
    bf3(v.x, x0, x1, x2);
    bf3(v.y, y0, y1, y2);
    bf3(v.z, z0, z1, z2);
    bf3(v.w, w0, w1, w2);
    const int ub = rw * 204 + k4;
    *(bhalf*)&dst[ub] = (bhalf){(short)x0, (short)y0, (short)z0, (short)w0};
    *(bhalf*)&dst[ub + 64] = (bhalf){(short)x1, (short)y1, (short)z1, (short)w1};
    *(bhalf*)&dst[ub + 128] = (bhalf){(short)x2, (short)y2, (short)z2, (short)w2};
  }
}

__device__ __forceinline__ bfrag ldfrag(const unsigned short* p) {
  bhalf lo = *(const bhalf*)p;        // 8B aligned
  bhalf hi = *(const bhalf*)(p + 4);  // +8B
  return __builtin_shufflevector(lo, hi, 0, 1, 2, 3, 4, 5, 6, 7);
}

__global__ __launch_bounds__(256, 1) void topk_part_kernel(
    const float* __restrict__ conf, const float* __restrict__ sq_ws,
    float* __restrict__ topd, unsigned short* __restrict__ topi) {
  // AU: A bf16x3 tile during init, then dist tile Ds[64][68]f, then mrgD
  // BU: B bf16x3 tile per j-tile, then mrgI
  __shared__ __align__(16) unsigned short AU[64 * 204];  // 26112 B
  __shared__ __align__(16) unsigned short BU[64 * 204];  // 26112 B
  __shared__ float sqa[64], sqjs[64];

  const int tid = threadIdx.x;
  const int b = blockIdx.z;
  const int i0 = blockIdx.x * 64;
  const int jbase = blockIdx.y * (NPTS / JS);
  const float* confb = conf + (size_t)b * NPTS * 64;
  const float* sqb = sq_ws + (size_t)b * NPTS;
  float* Dsf = (float*)AU;   // [64][68] dist tile (17408 B <= 26112)

  stage3(AU, confb, i0, tid);
  if (tid < 64) sqa[tid] = sqb[i0 + tid];
  __syncthreads();

  const int l = tid & 63, w = tid >> 6;   // lane, wave (wave w owns rows 16w..16w+15)
  const int cl = l & 15, g = l >> 4;

  // A-fragments: 6 (level p, k-half h), resident for the whole block
  const int abase = (16 * w + cl) * 204 + g * 8;
  const bfrag a00 = ldfrag(&AU[abase + 0]);
  const bfrag a01 = ldfrag(&AU[abase + 32]);
  const bfrag a10 = ldfrag(&AU[abase + 64]);
  const bfrag a11 = ldfrag(&AU[abase + 96]);
  const bfrag a20 = ldfrag(&AU[abase + 128]);
  const bfrag a21 = ldfrag(&AU[abase + 160]);
  float sqar[4];
#pragma unroll
  for (int e = 0; e < 4; ++e) sqar[e] = sqa[16 * w + 4 * g + e];

  const int irow = tid >> 2, q4 = tid & 3;   // insert-phase mapping (4 thr/row)

  unsigned long long lk[10];
#pragma unroll
  for (int k = 0; k < 10; ++k) lk[k] = 0x7F7FFFFF7FFFFFFFULL;  // (FLT_MAX, INT_MAX)
  float thrf = FLT_MAX;

  for (int jt = 0; jt < NPTS / JS / 64; ++jt) {   // 16 tiles of 64
    const int j0 = jbase + jt * 64;
    stage3(BU, confb, j0, tid);                   // a-frag reads done before this
    if (tid < 64) sqjs[tid] = sqb[j0 + tid];      // completes by the barrier below
    __syncthreads();   // BU/sqjs ready; prev Ds fully consumed by insert phase

    // ---- MFMA: 4 col-subtiles of 16, 12 k-steps each (6 B-frags, 2x reuse)
#pragma unroll
    for (int c = 0; c < 4; ++c) {
      const unsigned short* bp = &BU[(16 * c + cl) * 204 + g * 8];
      const bfrag b00 = ldfrag(bp + 0);
      const bfrag b01 = ldfrag(bp + 32);
      const bfrag b10 = ldfrag(bp + 64);
      const bfrag b11 = ldfrag(bp + 96);
      const bfrag b20 = ldfrag(bp + 128);
      const bfrag b21 = ldfrag(bp + 160);
      f32x4 acc = {0.f, 0.f, 0.f, 0.f};
      acc = MFMA(a00, b00, acc); acc = MFMA(a01, b01, acc);   // A0*B0
      acc = MFMA(a00, b10, acc); acc = MFMA(a01, b11, acc);   // A0*B1
      acc = MFMA(a10, b00, acc); acc = MFMA(a11, b01, acc);   // A1*B0
      acc = MFMA(a00, b20, acc); acc = MFMA(a01, b21, acc);   // A0*B2
      acc = MFMA(a10, b10, acc); acc = MFMA(a11, b11, acc);   // A1*B1
      acc = MFMA(a20, b00, acc); acc = MFMA(a21, b01, acc);   // A2*B0
      const int col = 16 * c + cl;
      const float sj = sqjs[col];
#pragma unroll
      for (int e = 0; e < 4; ++e) {
        const int rw = 16 * w + 4 * g + e;
        float d2 = fmaf(-2.f, acc[e], sqar[e] + sj);
        Dsf[rw * 68 + col] = sqrtf(fmaxf(d2, EPSC));
      }
    }
    __syncthreads();   // Ds ready; BU consumed (next stage3 may overwrite)

    // ---- insert phase (unchanged structure)
    {
#pragma unroll
      for (int cc = 0; cc < 4; ++cc) {
        float4 v = *(const float4*)&Dsf[irow * 68 + q4 * 16 + cc * 4];
        const int jb = j0 + q4 * 16 + cc * 4;
        TOPK_INS(v.x, jb + 0);
        TOPK_INS(v.y, jb + 1);
        TOPK_INS(v.z, jb + 2);
        TOPK_INS(v.w, jb + 3);
      }
      // refresh row-wide filter bound: min of the 4 siblings' 10th d
      float t = __uint_as_float((unsigned)(lk[9] >> 32));
      t = fminf(t, __shfl_xor(t, 1, 4));
      t = fminf(t, __shfl_xor(t, 2, 4));
      thrf = t;
    }
  }
  __syncthreads();

  // merge 4 per-thread sorted lists per row -> chunk top-10, write to ws
  float* mrgD = (float*)AU;   // 2560 floats
  int* mrgI = (int*)BU;       // 2560 ints
  {
#pragma unroll
    for (int k = 0; k < 10; ++k) {
      mrgD[irow * 40 + q4 * 10 + k] = __uint_as_float((unsigned)(lk[k] >> 32));
      mrgI[irow * 40 + q4 * 10 + k] = (int)(unsigned)(lk[k] & 0xFFFFFFFFu);
    }
  }
  __syncthreads();
  if (tid < 64) {
    const int base = tid * 40;
    int h0 = 0, h1 = 0, h2 = 0, h3 = 0;
    const size_t obase = (((size_t)b * NPTS + i0 + tid) * JS + blockIdx.y) * 10;
    for (int k = 0; k < 10; ++k) {
      float bd = FLT_MAX; int bi = 0x7fffffff; int bl = -1;
      { float d = mrgD[base + h0];      int ii = mrgI[base + h0];      if (dless(d, ii, bd, bi)) { bd = d; bi = ii; bl = 0; } }
      { float d = mrgD[base + 10 + h1]; int ii = mrgI[base + 10 + h1]; if (dless(d, ii, bd, bi)) { bd = d; bi = ii; bl = 1; } }
      { float d = mrgD[base + 20 + h2]; int ii = mrgI[base + 20 + h2]; if (dless(d, ii, bd, bi)) { bd = d; bi = ii; bl = 2; } }
      { float d = mrgD[base + 30 + h3]; int ii = mrgI[base + 30 + h3]; if (dless(d, ii, bd, bi)) { bd = d; bi = ii; bl = 3; } }
      h0 += (bl == 0); h1 += (bl == 1); h2 += (bl == 2); h3 += (bl == 3);
      topd[obase + k] = bd;
      topi[obase + k] = (unsigned short)bi;
    }
  }
}

// ---------------------------------------------------------------------------
// Merge JS chunk top-10s per row -> r, is_basin, depth, width.
// mask = {d < r} is exactly the members of the top-10 with d < d_9.
// ---------------------------------------------------------------------------
__global__ __launch_bounds__(256) void topk_merge_kernel(
    const float* __restrict__ topd, const unsigned short* __restrict__ topi,
    const float* __restrict__ e_in, float* __restrict__ basin_out,
    float* __restrict__ depth_out, float* __restrict__ width_out) {
  const int g = blockIdx.x * 256 + threadIdx.x;   // 0..16383
  const int b = g >> 12;
  const float* eb = e_in + (size_t)b * NPTS;
  const float* td = topd + (size_t)g * (JS * 10);
  const unsigned short* ti = topi + (size_t)g * (JS * 10);
  const float e_i = eb[g & (NPTS - 1)];
  int h0 = 0, h1 = 0, h2 = 0, h3 = 0;
  float dk[10];
  int ik[10];
#pragma unroll
  for (int k = 0; k < 10; ++k) {
    float bd = FLT_MAX; int bi = 0x7fffffff; int bl = -1;
    { float d = td[h0];      int ii = ti[h0];      if (dless(d, ii, bd, bi)) { bd = d; bi = ii; bl = 0; } }
    { float d = td[10 + h1]; int ii = ti[10 + h1]; if (dless(d, ii, bd, bi)) { bd = d; bi = ii; bl = 1; } }
    { float d = td[20 + h2]; int ii = ti[20 + h2]; if (dless(d, ii, bd, bi)) { bd = d; bi = ii; bl = 2; } }
    { float d = td[30 + h3]; int ii = ti[30 + h3]; if (dless(d, ii, bd, bi)) { bd = d; bi = ii; bl = 3; } }
    h0 += (bl == 0); h1 += (bl == 1); h2 += (bl == 2); h3 += (bl == 3);
    dk[k] = bd;
    ik[k] = bi;
  }
  const float r = dk[9];
  bool basin = true;
  float mx = -FLT_MAX, sum = 0.f, cnt = 0.f;
#pragma unroll
  for (int k = 0; k < 10; ++k) {
    float ev = eb[ik[k]];
    if (dk[k] < r) { mx = fmaxf(mx, ev); sum += dk[k]; cnt += 1.f; }
    if (k >= 1) basin = basin && (e_i <= ev);
  }
  basin_out[g] = basin ? 1.f : 0.f;
  depth_out[g] = mx - e_i;
  width_out[g] = sum / cnt;
}

// ---------------------------------------------------------------------------
// Kernel 3: rank by nd (stable), scatter e into sorted order.
// ---------------------------------------------------------------------------
__global__ __launch_bounds__(256) void rank_kernel(
    const float* __restrict__ nd_ws, const float* __restrict__ e_in,
    float* __restrict__ se_ws) {
  __shared__ __align__(16) float ndl[4096];
  const int tid = threadIdx.x;
  const int b = blockIdx.y;
  const int i0 = blockIdx.x * 64;
  const float* ndb = nd_ws + (size_t)b * NPTS;
  for (int q = tid; q < 1024; q += 256)
    *(float4*)&ndl[q * 4] = *(const float4*)(ndb + q * 4);
  __syncthreads();
  const int i = i0 + (tid >> 2);
  const int qp = tid & 3;
  const float ndi = ndl[i];
  int rank = 0;
  for (int j = qp * 1024; j < qp * 1024 + 1024; j += 4) {
    float4 v = *(const float4*)&ndl[j];
    rank += (v.x < ndi) || (v.x == ndi && (j + 0) < i);
    rank += (v.y < ndi) || (v.y == ndi && (j + 1) < i);
    rank += (v.z < ndi) || (v.z == ndi && (j + 2) < i);
    rank += (v.w < ndi) || (v.w == ndi && (j + 3) < i);
  }
  rank += __shfl_xor(rank, 1, 4);
  rank += __shfl_xor(rank, 2, 4);
  if (qp == 0) se_ws[(size_t)b * NPTS + rank] = e_in[(size_t)b * NPTS + i];
}

// ---------------------------------------------------------------------------
// Kernel 4: per-batch scalar metrics
// ---------------------------------------------------------------------------
__device__ __forceinline__ float block_sum(float v, float* red, int tid) {
  red[tid] = v;
  __syncthreads();
  for (int s = 512; s > 0; s >>= 1) {
    if (tid < s) red[tid] += red[tid + s];
    __syncthreads();
  }
  float r = red[0];
  __syncthreads();
  return r;
}
__device__ __forceinline__ float block_max(float v, float* red, int tid) {
  red[tid] = v;
  __syncthreads();
  for (int s = 512; s > 0; s >>= 1) {
    if (tid < s) red[tid] = fmaxf(red[tid], red[tid + s]);
    __syncthreads();
  }
  float r = red[0];
  __syncthreads();
  return r;
}

__global__ __launch_bounds__(1024) void metrics_kernel(
    const float* __restrict__ e_in, const float* __restrict__ nd_ws,
    const float* __restrict__ se_ws, float* __restrict__ metrics_out) {
  __shared__ __align__(16) float el[4096], ndl[4096], sel[4096];
  __shared__ float red[1024];
  __shared__ int redi[1024];
  const int tid = threadIdx.x;
  const int b = blockIdx.x;
  const float* eb = e_in + (size_t)b * NPTS;
  const float* ndb = nd_ws + (size_t)b * NPTS;
  const float* seb = se_ws + (size_t)b * NPTS;
  *(float4*)&el[tid * 4] = *(const float4*)(eb + tid * 4);
  *(float4*)&ndl[tid * 4] = *(const float4*)(ndb + tid * 4);
  *(float4*)&sel[tid * 4] = *(const float4*)(seb + tid * 4);
  __syncthreads();

  float pe = 0.f, pnd = 0.f;
  for (int p = tid; p < 4096; p += 1024) { pe += el[p]; pnd += ndl[p]; }
  float me = block_sum(pe, red, tid) / 4096.f;
  float mnd = block_sum(pnd, red, tid) / 4096.f;

  float sxx = 0.f, syy = 0.f, sxy = 0.f, mx = -FLT_MAX;
  float bestv = FLT_MAX;
  int besti = 0x7fffffff;
  for (int p = tid; p < 4096; p += 1024) {
    float de = el[p] - me, dn = ndl[p] - mnd;
    syy += de * de;
    sxx += dn * dn;
    sxy += de * dn;
    mx = fmaxf(mx, el[p]);
    if (ndl[p] < bestv || (ndl[p] == bestv && p < besti)) { bestv = ndl[p]; besti = p; }
  }
  float fr = 0.f;
  for (int p = tid; p < 4095; p += 1024) fr += (sel[p + 1] > sel[p]) ? 1.f : 0.f;

  sxx = block_sum(sxx, red, tid);
  syy = block_sum(syy, red, tid);
  sxy = block_sum(sxy, red, tid);
  mx = block_max(mx, red, tid);
  fr = block_sum(fr, red, tid);

  red[tid] = bestv;
  redi[tid] = besti;
  __syncthreads();
  for (int s = 512; s > 0; s >>= 1) {
    if (tid < s) {
      float ov = red[tid + s];
      int oi = redi[tid + s];
      if (ov < red[tid] || (ov == red[tid] && oi < redi[tid])) { red[tid] = ov; redi[tid] = oi; }
    }
    __syncthreads();
  }
  if (tid == 0) {
    float ne = el[redi[0]];
    metrics_out[b * 5 + 0] = mx - ne;
    metrics_out[b * 5 + 1] = sqrtf(syy / 4095.f);
    metrics_out[b * 5 + 2] = sxy / sqrtf(sxx * syy);
    metrics_out[b * 5 + 3] = fr / 4095.f;
    metrics_out[b * 5 + 4] = ne;
  }
}

// ---------------------------------------------------------------------------
extern "C" void kernel_launch(void* const* d_in, const int* in_sizes, int n_in,
                              void* d_out, int out_size, void* d_ws, size_t ws_size,
                              hipStream_t stream) {
  const float* conf = (const float*)d_in[0];
  const float* native = (const float*)d_in[1];
  const float* We1 = (const float*)d_in[2];
  const float* be1 = (const float*)d_in[3];
  const float* We2 = (const float*)d_in[4];
  const float* be2 = (const float*)d_in[5];
  const float* We3 = (const float*)d_in[6];
  const float* be3 = (const float*)d_in[7];
  const float* Ws1 = (const float*)d_in[8];
  const float* bs1 = (const float*)d_in[9];
  const float* Ws2 = (const float*)d_in[10];
  const float* bs2 = (const float*)d_in[11];

  float* out = (float*)d_out;
  float* e_out = out;                 // [0, 16384)
  float* basin_out = out + BN;        // [16384, 32768)
  float* depth_out = out + 2 * BN;    // [32768, 49152)
  float* width_out = out + 3 * BN;    // [49152, 65536)
  float* logits_out = out + 4 * BN;   // [65536, 163840)
  float* metrics_out = out + 10 * BN; // [163840, 163860)

  // ws layout (floats): sq | nd | se | topd(40BN) | topi(40BN ushort = 20BN)
  float* wsf = (float*)d_ws;
  float* sq_ws = wsf;
  float* nd_ws = wsf + BN;
  float* se_ws = wsf + 2 * (size_t)BN;
  float* topd = wsf + 3 * (size_t)BN;
  unsigned short* topi = (unsigned short*)(wsf + 43 * (size_t)BN);

  mlp_kernel<<<dim3(512), dim3(256), 0, stream>>>(
      conf, native, We1, be1, We2, be2, We3, be3, Ws1, bs1, Ws2, bs2,
      e_out, logits_out, sq_ws, nd_ws);
  topk_part_kernel<<<dim3(64, JS, NBATCH), dim3(256), 0, stream>>>(
      conf, sq_ws, topd, topi);
  topk_merge_kernel<<<dim3(BN / 256), dim3(256), 0, stream>>>(
      topd, topi, e_out, basin_out, depth_out, width_out);
  rank_kernel<<<dim3(64, NBATCH), dim3(256), 0, stream>>>(nd_ws, e_out, se_ws);
  metrics_kernel<<<dim3(NBATCH), dim3(1024), 0, stream>>>(e_out, nd_ws, se_ws, metrics_out);
}

// Round 8
// 308.282 us; speedup vs baseline: 17.6935x; 1.0639x over previous
//
#include <hip/hip_runtime.h>
#include <float.h>
#include <math.h>

#define NPTS 4096
#define NBATCH 4
#define BN (NBATCH * NPTS)   // 16384
#define EPSC 1e-12f
#define JS 4                 // j-dimension splits for the topk kernel
#define CSTRIDE 204          // ushort row stride of the bf16x3 image (conflict-free frag reads)

typedef __attribute__((ext_vector_type(8))) short bfrag;   // 8 bf16 (4 VGPR) MFMA operand
typedef __attribute__((ext_vector_type(4))) short bhalf;   // 8B half-fragment
typedef __attribute__((ext_vector_type(4))) float f32x4;   // MFMA accumulator

#define MFMA(A, B, C) __builtin_amdgcn_mfma_f32_16x16x32_bf16((A), (B), (C), 0, 0, 0)

__device__ __forceinline__ bool dless(float d1, int i1, float d2, int i2) {
  return (d1 < d2) || ((d1 == d2) && (i1 < i2));
}

// RN-even fp32->bf16 (branch-free), and back
__device__ __forceinline__ unsigned short f2bf(float x) {
  unsigned b = __float_as_uint(x);
  return (unsigned short)((b + 0x7FFFu + ((b >> 16) & 1u)) >> 16);
}
__device__ __forceinline__ float bf2f(unsigned short u) {
  return __uint_as_float(((unsigned)u) << 16);
}
// exact-ish 3-way split: x ~= bf(x0)+bf(x1)+bf(x2), residual ~2^-25|x|
__device__ __forceinline__ void bf3(float x, unsigned short& u0, unsigned short& u1,
                                    unsigned short& u2) {
  u0 = f2bf(x);
  float r = x - bf2f(u0);
  u1 = f2bf(r);
  r = r - bf2f(u1);
  u2 = f2bf(r);
}

// ---------------------------------------------------------------------------
// Kernel 0: one-shot bf16x3 decomposition of conf into the padded LDS image.
// Row = 192 ushorts (levels at +0/+64/+128) padded to CSTRIDE=204; tiles of 64
// rows are then flat-copyable (26112 B, 16B-granular) into LDS.
// ---------------------------------------------------------------------------
__global__ __launch_bounds__(256) void bf3_kernel(
    const float* __restrict__ conf, unsigned short* __restrict__ cbf) {
  const int g = blockIdx.x * 256 + threadIdx.x;   // one thread per 4 values
  const int pt = g >> 4;                          // point 0..BN-1
  const int k4 = (g & 15) << 2;
  float4 v = *(const float4*)(conf + (size_t)pt * 64 + k4);
  unsigned short x0, x1, x2, y0, y1, y2, z0, z1, z2, w0, w1, w2;
  bf3(v.x, x0, x1, x2);
  bf3(v.y, y0, y1, y2);
  bf3(v.z, z0, z1, z2);
  bf3(v.w, w0, w1, w2);
  unsigned short* dst = cbf + (size_t)pt * CSTRIDE + k4;
  *(bhalf*)&dst[0] = (bhalf){(short)x0, (short)y0, (short)z0, (short)w0};
  *(bhalf*)&dst[64] = (bhalf){(short)x1, (short)y1, (short)z1, (short)w1};
  *(bhalf*)&dst[128] = (bhalf){(short)x2, (short)y2, (short)z2, (short)w2};
}

// ---------------------------------------------------------------------------
// Kernel 1: fused MLP — e, logits, sq, nd.  512 blocks x 256 thr, 32 pts/block
// ---------------------------------------------------------------------------
__device__ __forceinline__ void gemm32x128(const float (*A)[64], const float* W,
                                           const float* bias, float (*O)[128], int tid) {
  const int pi = (tid >> 5) << 2;   // point quad
  const int ci = (tid & 31) << 2;   // col quad
  float acc[4][4] = {};
  for (int k0 = 0; k0 < 64; k0 += 4) {
    alignas(16) float av[4][4], wv[4][4];
#pragma unroll
    for (int r = 0; r < 4; ++r) *(float4*)av[r] = *(const float4*)&A[pi + r][k0];
#pragma unroll
    for (int kk = 0; kk < 4; ++kk) *(float4*)wv[kk] = *(const float4*)&W[(k0 + kk) * 128 + ci];
#pragma unroll
    for (int kk = 0; kk < 4; ++kk)
#pragma unroll
      for (int r = 0; r < 4; ++r)
#pragma unroll
        for (int c = 0; c < 4; ++c)
          acc[r][c] = fmaf(av[r][kk], wv[kk][c], acc[r][c]);
  }
#pragma unroll
  for (int r = 0; r < 4; ++r)
#pragma unroll
    for (int c = 0; c < 4; ++c)
      O[pi + r][ci + c] = fmaxf(acc[r][c] + bias[ci + c], 0.f);
}

__global__ __launch_bounds__(256) void mlp_kernel(
    const float* __restrict__ conf, const float* __restrict__ native,
    const float* __restrict__ We1, const float* __restrict__ be1,
    const float* __restrict__ We2, const float* __restrict__ be2,
    const float* __restrict__ We3, const float* __restrict__ be3,
    const float* __restrict__ Ws1, const float* __restrict__ bs1,
    const float* __restrict__ Ws2, const float* __restrict__ bs2,
    float* __restrict__ e_out, float* __restrict__ logits_out,
    float* __restrict__ sq_ws, float* __restrict__ nd_ws) {
  __shared__ __align__(16) float Wbuf[8192];       // 32 KB (We1 / We2 / Ws1)
  __shared__ __align__(16) float confs[32][64];    // 8 KB (later reused for h2)
  __shared__ __align__(16) float hbuf[32][128];    // 16 KB (g then h1)
  __shared__ float nat[64];
  __shared__ float b1s[128], b2s[64], w3s[64], bs1s[128], ws2s[768], bs2s[6];
  __shared__ float be3s;

  const int tid = threadIdx.x;
  const int blk = blockIdx.x;       // 0..511
  const int b = blk >> 7;           // 128 blocks per batch
  const int pbase = (blk & 127) * 32;
  const float* confb = conf + ((size_t)b * NPTS + pbase) * 64;

  for (int q = tid; q < 512; q += 256) {
    float4 v = *(const float4*)(confb + q * 4);
    *(float4*)&confs[q >> 4][(q & 15) << 2] = v;
  }
  if (tid < 64) nat[tid] = native[b * 64 + tid];
  if (tid < 128) b1s[tid] = be1[tid];
  if (tid < 64) b2s[tid] = be2[tid];
  if (tid < 64) w3s[tid] = We3[tid];
  if (tid < 128) bs1s[tid] = bs1[tid];
  for (int q = tid; q < 768; q += 256) ws2s[q] = Ws2[q];
  if (tid < 6) bs2s[tid] = bs2[tid];
  if (tid == 0) be3s = be3[0];
  for (int q = tid; q < 2048; q += 256)
    *(float4*)&Wbuf[q * 4] = *(const float4*)(Ws1 + q * 4);
  __syncthreads();

  // sq & nd — numpy-pairwise style: rounded products, 8 accumulators
  if (tid < 32) {
    float rs_[8], rn_[8];
#pragma unroll
    for (int u = 0; u < 8; ++u) {
      float c = confs[tid][u];
      rs_[u] = c * c;
      float d = c - nat[u];
      rn_[u] = d * d;
    }
    for (int d0 = 8; d0 < 64; d0 += 8) {
#pragma unroll
      for (int u = 0; u < 8; ++u) {
        float c = confs[tid][d0 + u];
        rs_[u] += c * c;
        float d = c - nat[d0 + u];
        rn_[u] += d * d;
      }
    }
    float s = ((rs_[0] + rs_[1]) + (rs_[2] + rs_[3])) + ((rs_[4] + rs_[5]) + (rs_[6] + rs_[7]));
    float n = ((rn_[0] + rn_[1]) + (rn_[2] + rn_[3])) + ((rn_[4] + rn_[5]) + (rn_[6] + rn_[7]));
    sq_ws[(size_t)b * NPTS + pbase + tid] = s;
    nd_ws[(size_t)b * NPTS + pbase + tid] = sqrtf(n);
  }

  gemm32x128(confs, Wbuf, bs1s, hbuf, tid);     // g = relu(conf @ Ws1 + bs1)
  __syncthreads();

  for (int q = tid; q < 2048; q += 256)         // reload Wbuf <- We1
    *(float4*)&Wbuf[q * 4] = *(const float4*)(We1 + q * 4);
  if (tid < 192) {
    int p = tid / 6, s = tid % 6;
    float acc = 0.f;
#pragma unroll 8
    for (int h = 0; h < 128; ++h)
      acc = fmaf(hbuf[p][h], ws2s[h * 6 + s], acc);
    logits_out[((size_t)b * NPTS + pbase + p) * 6 + s] = acc + bs2s[s];
  }
  __syncthreads();

  gemm32x128(confs, Wbuf, b1s, hbuf, tid);      // h1 = relu(conf @ We1 + be1)
  __syncthreads();

  for (int q = tid; q < 2048; q += 256)
    *(float4*)&Wbuf[q * 4] = *(const float4*)(We2 + q * 4);
  __syncthreads();

  // h2 = relu(h1 @ We2 + be2) -> confs
  if (tid < 128) {
    const int pi = (tid >> 4) << 2;
    const int ci = (tid & 15) << 2;
    float acc[4][4] = {};
    for (int k0 = 0; k0 < 128; k0 += 4) {
      alignas(16) float av[4][4], wv[4][4];
#pragma unroll
      for (int r = 0; r < 4; ++r) *(float4*)av[r] = *(const float4*)&hbuf[pi + r][k0];
#pragma unroll
      for (int kk = 0; kk < 4; ++kk) *(float4*)wv[kk] = *(const float4*)&Wbuf[(k0 + kk) * 64 + ci];
#pragma unroll
      for (int kk = 0; kk < 4; ++kk)
#pragma unroll
        for (int r = 0; r < 4; ++r)
#pragma unroll
          for (int c = 0; c < 4; ++c)
            acc[r][c] = fmaf(av[r][kk], wv[kk][c], acc[r][c]);
    }
#pragma unroll
    for (int r = 0; r < 4; ++r)
#pragma unroll
      for (int c = 0; c < 4; ++c)
        confs[pi + r][ci + c] = fmaxf(acc[r][c] + b2s[ci + c], 0.f);
  }
  __syncthreads();

  if (tid < 32) {                               // e = h2 @ We3 + be3
    float acc = 0.f;
#pragma unroll
    for (int k = 0; k < 64; ++k)
      acc = fmaf(confs[tid][k], w3s[k], acc);
    e_out[(size_t)b * NPTS + pbase + tid] = acc + be3s;
  }
}

// ---------------------------------------------------------------------------
// Distance pass (split-j), bf16x3 MFMA edition, d2-keyed.
// S ~= A0B0 + A0B1 + A1B0 + A0B2 + A1B1 + A2B0 (residual ~2^-25).
// Keys are cd2 = max(d2, EPSC): sqrt is monotone on [eps,inf) so (cd2,j) lex
// order == (d,j) lex order; sqrt deferred to the merge kernel (<=40/point).
// Staging is a flat 16B copy of the precomputed bf16x3 image (no VALU).
// D-frag mapping (m89): col = lane&15, row = (lane>>4)*4 + reg.
// ---------------------------------------------------------------------------
#define TOPK_INS(d_, j_)                                                      \
  do {                                                                        \
    if ((d_) <= thrf) {                                                       \
      unsigned long long cur =                                                \
          (((unsigned long long)__float_as_uint(d_)) << 32) |                 \
          (unsigned long long)(unsigned)(j_);                                 \
      if (cur < lk[9]) {                                                      \
        _Pragma("unroll")                                                     \
        for (int k = 0; k < 10; ++k) {                                        \
          bool lt = cur < lk[k];                                              \
          unsigned long long mn = lt ? cur : lk[k];                           \
          cur = lt ? lk[k] : cur;                                             \
          lk[k] = mn;                                                         \
        }                                                                     \
      }                                                                       \
    }                                                                         \
  } while (0)

__device__ __forceinline__ bfrag ldfrag(const unsigned short* p) {
  bhalf lo = *(const bhalf*)p;        // 8B aligned
  bhalf hi = *(const bhalf*)(p + 4);  // +8B
  return __builtin_shufflevector(lo, hi, 0, 1, 2, 3, 4, 5, 6, 7);
}

__global__ __launch_bounds__(256, 1) void topk_part_kernel(
    const unsigned short* __restrict__ cbf, const float* __restrict__ sq_ws,
    float* __restrict__ topd, unsigned short* __restrict__ topi) {
  // AU: A bf16x3 tile during init, then cd2 tile Ds[64][68]f, then mrgD
  // BU: B bf16x3 tile per j-tile, then mrgI
  __shared__ __align__(16) unsigned short AU[64 * CSTRIDE];  // 26112 B
  __shared__ __align__(16) unsigned short BU[64 * CSTRIDE];  // 26112 B
  __shared__ float sqa[64], sqjs[64];

  const int tid = threadIdx.x;
  const int b = blockIdx.z;
  const int i0 = blockIdx.x * 64;
  const int jbase = blockIdx.y * (NPTS / JS);
  const unsigned short* cbfb = cbf + (size_t)b * NPTS * CSTRIDE;
  const float* sqb = sq_ws + (size_t)b * NPTS;
  float* Dsf = (float*)AU;   // [64][68] cd2 tile (17408 B <= 26112)

  // flat 16B copy: 64 rows x 204 us = 26112 B = 1632 chunks
  {
    const float4* src = (const float4*)(cbfb + (size_t)i0 * CSTRIDE);
    float4* dst = (float4*)AU;
    for (int q = tid; q < 1632; q += 256) dst[q] = src[q];
  }
  if (tid < 64) sqa[tid] = sqb[i0 + tid];
  __syncthreads();

  const int l = tid & 63, w = tid >> 6;   // lane, wave (wave w owns rows 16w..16w+15)
  const int cl = l & 15, g = l >> 4;

  // A-fragments: 6 (level p, k-half h), resident for the whole block
  const int abase = (16 * w + cl) * CSTRIDE + g * 8;
  const bfrag a00 = ldfrag(&AU[abase + 0]);
  const bfrag a01 = ldfrag(&AU[abase + 32]);
  const bfrag a10 = ldfrag(&AU[abase + 64]);
  const bfrag a11 = ldfrag(&AU[abase + 96]);
  const bfrag a20 = ldfrag(&AU[abase + 128]);
  const bfrag a21 = ldfrag(&AU[abase + 160]);
  float sqar[4];
#pragma unroll
  for (int e = 0; e < 4; ++e) sqar[e] = sqa[16 * w + 4 * g + e];

  const int irow = tid >> 2, q4 = tid & 3;   // insert-phase mapping (4 thr/row)

  unsigned long long lk[10];
#pragma unroll
  for (int k = 0; k < 10; ++k) lk[k] = 0x7F7FFFFF7FFFFFFFULL;  // (FLT_MAX, INT_MAX)
  float thrf = FLT_MAX;

  for (int jt = 0; jt < NPTS / JS / 64; ++jt) {   // 16 tiles of 64
    const int j0 = jbase + jt * 64;
    {
      const float4* src = (const float4*)(cbfb + (size_t)j0 * CSTRIDE);
      float4* dst = (float4*)BU;
      for (int q = tid; q < 1632; q += 256) dst[q] = src[q];
    }
    if (tid < 64) sqjs[tid] = sqb[j0 + tid];
    __syncthreads();   // BU/sqjs ready; prev Ds fully consumed by insert phase

    // ---- MFMA: 4 col-subtiles of 16, 12 k-steps each (6 B-frags, 2x reuse)
#pragma unroll
    for (int c = 0; c < 4; ++c) {
      const unsigned short* bp = &BU[(16 * c + cl) * CSTRIDE + g * 8];
      const bfrag b00 = ldfrag(bp + 0);
      const bfrag b01 = ldfrag(bp + 32);
      const bfrag b10 = ldfrag(bp + 64);
      const bfrag b11 = ldfrag(bp + 96);
      const bfrag b20 = ldfrag(bp + 128);
      const bfrag b21 = ldfrag(bp + 160);
      f32x4 acc = {0.f, 0.f, 0.f, 0.f};
      acc = MFMA(a00, b00, acc); acc = MFMA(a01, b01, acc);   // A0*B0
      acc = MFMA(a00, b10, acc); acc = MFMA(a01, b11, acc);   // A0*B1
      acc = MFMA(a10, b00, acc); acc = MFMA(a11, b01, acc);   // A1*B0
      acc = MFMA(a00, b20, acc); acc = MFMA(a01, b21, acc);   // A0*B2
      acc = MFMA(a10, b10, acc); acc = MFMA(a11, b11, acc);   // A1*B1
      acc = MFMA(a20, b00, acc); acc = MFMA(a21, b01, acc);   // A2*B0
      const int col = 16 * c + cl;
      const float sj = sqjs[col];
#pragma unroll
      for (int e = 0; e < 4; ++e) {
        const int rw = 16 * w + 4 * g + e;
        float d2 = fmaf(-2.f, acc[e], sqar[e] + sj);
        Dsf[rw * 68 + col] = fmaxf(d2, EPSC);   // cd2 (sqrt deferred)
      }
    }
    __syncthreads();   // Ds ready; BU consumed (next copy may overwrite)

    // ---- insert phase (keys are cd2; same lex order as d)
    {
#pragma unroll
      for (int cc = 0; cc < 4; ++cc) {
        float4 v = *(const float4*)&Dsf[irow * 68 + q4 * 16 + cc * 4];
        const int jb = j0 + q4 * 16 + cc * 4;
        TOPK_INS(v.x, jb + 0);
        TOPK_INS(v.y, jb + 1);
        TOPK_INS(v.z, jb + 2);
        TOPK_INS(v.w, jb + 3);
      }
      // refresh row-wide filter bound: min of the 4 siblings' 10th cd2
      float t = __uint_as_float((unsigned)(lk[9] >> 32));
      t = fminf(t, __shfl_xor(t, 1, 4));
      t = fminf(t, __shfl_xor(t, 2, 4));
      thrf = t;
    }
  }
  __syncthreads();

  // merge 4 per-thread sorted lists per row -> chunk top-10 (cd2), write to ws
  float* mrgD = (float*)AU;   // 2560 floats
  int* mrgI = (int*)BU;       // 2560 ints
  {
#pragma unroll
    for (int k = 0; k < 10; ++k) {
      mrgD[irow * 40 + q4 * 10 + k] = __uint_as_float((unsigned)(lk[k] >> 32));
      mrgI[irow * 40 + q4 * 10 + k] = (int)(unsigned)(lk[k] & 0xFFFFFFFFu);
    }
  }
  __syncthreads();
  if (tid < 64) {
    const int base = tid * 40;
    int h0 = 0, h1 = 0, h2 = 0, h3 = 0;
    const size_t obase = (((size_t)b * NPTS + i0 + tid) * JS + blockIdx.y) * 10;
    for (int k = 0; k < 10; ++k) {
      float bd = FLT_MAX; int bi = 0x7fffffff; int bl = -1;
      { float d = mrgD[base + h0];      int ii = mrgI[base + h0];      if (dless(d, ii, bd, bi)) { bd = d; bi = ii; bl = 0; } }
      { float d = mrgD[base + 10 + h1]; int ii = mrgI[base + 10 + h1]; if (dless(d, ii, bd, bi)) { bd = d; bi = ii; bl = 1; } }
      { float d = mrgD[base + 20 + h2]; int ii = mrgI[base + 20 + h2]; if (dless(d, ii, bd, bi)) { bd = d; bi = ii; bl = 2; } }
      { float d = mrgD[base + 30 + h3]; int ii = mrgI[base + 30 + h3]; if (dless(d, ii, bd, bi)) { bd = d; bi = ii; bl = 3; } }
      h0 += (bl == 0); h1 += (bl == 1); h2 += (bl == 2); h3 += (bl == 3);
      topd[obase + k] = bd;                    // cd2
      topi[obase + k] = (unsigned short)bi;
    }
  }
}

// ---------------------------------------------------------------------------
// Merge JS chunk top-10s per row -> r, is_basin, depth, width.
// Inputs are cd2; mask cd2 < r2 == d < r; width uses sqrt(cd2) (= ref d bits).
// ---------------------------------------------------------------------------
__global__ __launch_bounds__(256) void topk_merge_kernel(
    const float* __restrict__ topd, const unsigned short* __restrict__ topi,
    const float* __restrict__ e_in, float* __restrict__ basin_out,
    float* __restrict__ depth_out, float* __restrict__ width_out) {
  const int g = blockIdx.x * 256 + threadIdx.x;   // 0..16383
  const int b = g >> 12;
  const float* eb = e_in + (size_t)b * NPTS;
  const float* td = topd + (size_t)g * (JS * 10);
  const unsigned short* ti = topi + (size_t)g * (JS * 10);
  const float e_i = eb[g & (NPTS - 1)];
  int h0 = 0, h1 = 0, h2 = 0, h3 = 0;
  float dk[10];
  int ik[10];
#pragma unroll
  for (int k = 0; k < 10; ++k) {
    float bd = FLT_MAX; int bi = 0x7fffffff; int bl = -1;
    { float d = td[h0];      int ii = ti[h0];      if (dless(d, ii, bd, bi)) { bd = d; bi = ii; bl = 0; } }
    { float d = td[10 + h1]; int ii = ti[10 + h1]; if (dless(d, ii, bd, bi)) { bd = d; bi = ii; bl = 1; } }
    { float d = td[20 + h2]; int ii = ti[20 + h2]; if (dless(d, ii, bd, bi)) { bd = d; bi = ii; bl = 2; } }
    { float d = td[30 + h3]; int ii = ti[30 + h3]; if (dless(d, ii, bd, bi)) { bd = d; bi = ii; bl = 3; } }
    h0 += (bl == 0); h1 += (bl == 1); h2 += (bl == 2); h3 += (bl == 3);
    dk[k] = bd;
    ik[k] = bi;
  }
  const float r2 = dk[9];
  bool basin = true;
  float mx = -FLT_MAX, sum = 0.f, cnt = 0.f;
#pragma unroll
  for (int k = 0; k < 10; ++k) {
    float ev = eb[ik[k]];
    if (dk[k] < r2) { mx = fmaxf(mx, ev); sum += sqrtf(dk[k]); cnt += 1.f; }
    if (k >= 1) basin = basin && (e_i <= ev);
  }
  basin_out[g] = basin ? 1.f : 0.f;
  depth_out[g] = mx - e_i;
  width_out[g] = sum / cnt;
}

// ---------------------------------------------------------------------------
// Kernel 3: rank by nd (stable), scatter e into sorted order.
// ---------------------------------------------------------------------------
__global__ __launch_bounds__(256) void rank_kernel(
    const float* __restrict__ nd_ws, const float* __restrict__ e_in,
    float* __restrict__ se_ws) {
  __shared__ __align__(16) float ndl[4096];
  const int tid = threadIdx.x;
  const int b = blockIdx.y;
  const int i0 = blockIdx.x * 64;
  const float* ndb = nd_ws + (size_t)b * NPTS;
  for (int q = tid; q < 1024; q += 256)
    *(float4*)&ndl[q * 4] = *(const float4*)(ndb + q * 4);
  __syncthreads();
  const int i = i0 + (tid >> 2);
  const int qp = tid & 3;
  const float ndi = ndl[i];
  int rank = 0;
  for (int j = qp * 1024; j < qp * 1024 + 1024; j += 4) {
    float4 v = *(const float4*)&ndl[j];
    rank += (v.x < ndi) || (v.x == ndi && (j + 0) < i);
    rank += (v.y < ndi) || (v.y == ndi && (j + 1) < i);
    rank += (v.z < ndi) || (v.z == ndi && (j + 2) < i);
    rank += (v.w < ndi) || (v.w == ndi && (j + 3) < i);
  }
  rank += __shfl_xor(rank, 1, 4);
  rank += __shfl_xor(rank, 2, 4);
  if (qp == 0) se_ws[(size_t)b * NPTS + rank] = e_in[(size_t)b * NPTS + i];
}

// ---------------------------------------------------------------------------
// Kernel 4: per-batch scalar metrics
// ---------------------------------------------------------------------------
__device__ __forceinline__ float block_sum(float v, float* red, int tid) {
  red[tid] = v;
  __syncthreads();
  for (int s = 512; s > 0; s >>= 1) {
    if (tid < s) red[tid] += red[tid + s];
    __syncthreads();
  }
  float r = red[0];
  __syncthreads();
  return r;
}
__device__ __forceinline__ float block_max(float v, float* red, int tid) {
  red[tid] = v;
  __syncthreads();
  for (int s = 512; s > 0; s >>= 1) {
    if (tid < s) red[tid] = fmaxf(red[tid], red[tid + s]);
    __syncthreads();
  }
  float r = red[0];
  __syncthreads();
  return r;
}

__global__ __launch_bounds__(1024) void metrics_kernel(
    const float* __restrict__ e_in, const float* __restrict__ nd_ws,
    const float* __restrict__ se_ws, float* __restrict__ metrics_out) {
  __shared__ __align__(16) float el[4096], ndl[4096], sel[4096];
  __shared__ float red[1024];
  __shared__ int redi[1024];
  const int tid = threadIdx.x;
  const int b = blockIdx.x;
  const float* eb = e_in + (size_t)b * NPTS;
  const float* ndb = nd_ws + (size_t)b * NPTS;
  const float* seb = se_ws + (size_t)b * NPTS;
  *(float4*)&el[tid * 4] = *(const float4*)(eb + tid * 4);
  *(float4*)&ndl[tid * 4] = *(const float4*)(ndb + tid * 4);
  *(float4*)&sel[tid * 4] = *(const float4*)(seb + tid * 4);
  __syncthreads();

  float pe = 0.f, pnd = 0.f;
  for (int p = tid; p < 4096; p += 1024) { pe += el[p]; pnd += ndl[p]; }
  float me = block_sum(pe, red, tid) / 4096.f;
  float mnd = block_sum(pnd, red, tid) / 4096.f;

  float sxx = 0.f, syy = 0.f, sxy = 0.f, mx = -FLT_MAX;
  float bestv = FLT_MAX;
  int besti = 0x7fffffff;
  for (int p = tid; p < 4096; p += 1024) {
    float de = el[p] - me, dn = ndl[p] - mnd;
    syy += de * de;
    sxx += dn * dn;
    sxy += de * dn;
    mx = fmaxf(mx, el[p]);
    if (ndl[p] < bestv || (ndl[p] == bestv && p < besti)) { bestv = ndl[p]; besti = p; }
  }
  float fr = 0.f;
  for (int p = tid; p < 4095; p += 1024) fr += (sel[p + 1] > sel[p]) ? 1.f : 0.f;

  sxx = block_sum(sxx, red, tid);
  syy = block_sum(syy, red, tid);
  sxy = block_sum(sxy, red, tid);
  mx = block_max(mx, red, tid);
  fr = block_sum(fr, red, tid);

  red[tid] = bestv;
  redi[tid] = besti;
  __syncthreads();
  for (int s = 512; s > 0; s >>= 1) {
    if (tid < s) {
      float ov = red[tid + s];
      int oi = redi[tid + s];
      if (ov < red[tid] || (ov == red[tid] && oi < redi[tid])) { red[tid] = ov; redi[tid] = oi; }
    }
    __syncthreads();
  }
  if (tid == 0) {
    float ne = el[redi[0]];
    metrics_out[b * 5 + 0] = mx - ne;
    metrics_out[b * 5 + 1] = sqrtf(syy / 4095.f);
    metrics_out[b * 5 + 2] = sxy / sqrtf(sxx * syy);
    metrics_out[b * 5 + 3] = fr / 4095.f;
    metrics_out[b * 5 + 4] = ne;
  }
}

// ---------------------------------------------------------------------------
extern "C" void kernel_launch(void* const* d_in, const int* in_sizes, int n_in,
                              void* d_out, int out_size, void* d_ws, size_t ws_size,
                              hipStream_t stream) {
  const float* conf = (const float*)d_in[0];
  const float* native = (const float*)d_in[1];
  const float* We1 = (const float*)d_in[2];
  const float* be1 = (const float*)d_in[3];
  const float* We2 = (const float*)d_in[4];
  const float* be2 = (const float*)d_in[5];
  const float* We3 = (const float*)d_in[6];
  const float* be3 = (const float*)d_in[7];
  const float* Ws1 = (const float*)d_in[8];
  const float* bs1 = (const float*)d_in[9];
  const float* Ws2 = (const float*)d_in[10];
  const float* bs2 = (const float*)d_in[11];

  float* out = (float*)d_out;
  float* e_out = out;                 // [0, 16384)
  float* basin_out = out + BN;        // [16384, 32768)
  float* depth_out = out + 2 * BN;    // [32768, 49152)
  float* width_out = out + 3 * BN;    // [49152, 65536)
  float* logits_out = out + 4 * BN;   // [65536, 163840)
  float* metrics_out = out + 10 * BN; // [163840, 163860)

  // ws layout (floats): sq | nd | se | topd(40BN) | topi(20BN) | cbf(102BN)
  float* wsf = (float*)d_ws;
  float* sq_ws = wsf;
  float* nd_ws = wsf + BN;
  float* se_ws = wsf + 2 * (size_t)BN;
  float* topd = wsf + 3 * (size_t)BN;
  unsigned short* topi = (unsigned short*)(wsf + 43 * (size_t)BN);
  unsigned short* cbf = (unsigned short*)(wsf + 63 * (size_t)BN);

  bf3_kernel<<<dim3(BN * 16 / 256), dim3(256), 0, stream>>>(conf, cbf);
  mlp_kernel<<<dim3(512), dim3(256), 0, stream>>>(
      conf, native, We1, be1, We2, be2, We3, be3, Ws1, bs1, Ws2, bs2,
      e_out, logits_out, sq_ws, nd_ws);
  topk_part_kernel<<<dim3(64, JS, NBATCH), dim3(256), 0, stream>>>(
      cbf, sq_ws, topd, topi);
  topk_merge_kernel<<<dim3(BN / 256), dim3(256), 0, stream>>>(
      topd, topi, e_out, basin_out, depth_out, width_out);
  rank_kernel<<<dim3(64, NBATCH), dim3(256), 0, stream>>>(nd_ws, e_out, se_ws);
  metrics_kernel<<<dim3(NBATCH), dim3(1024), 0, stream>>>(e_out, nd_ws, se_ws, metrics_out);
}

// Round 9
// 275.054 us; speedup vs baseline: 19.8310x; 1.1208x over previous
//
#include <hip/hip_runtime.h>
#include <float.h>
#include <math.h>

#define NPTS 4096
#define NBATCH 4
#define BN (NBATCH * NPTS)   // 16384
#define EPSC 1e-12f
#define JS 4                 // j-dimension splits for the topk kernel
#define CSTRIDE 204          // ushort row stride of the bf16x3 image (conflict-free frag reads)

typedef __attribute__((ext_vector_type(8))) short bfrag;   // 8 bf16 (4 VGPR) MFMA operand
typedef __attribute__((ext_vector_type(4))) short bhalf;   // 8B half-fragment
typedef __attribute__((ext_vector_type(4))) float f32x4;   // MFMA accumulator

#define MFMA(A, B, C) __builtin_amdgcn_mfma_f32_16x16x32_bf16((A), (B), (C), 0, 0, 0)

__device__ __forceinline__ bool dless(float d1, int i1, float d2, int i2) {
  return (d1 < d2) || ((d1 == d2) && (i1 < i2));
}

// RN-even fp32->bf16 (branch-free), and back
__device__ __forceinline__ unsigned short f2bf(float x) {
  unsigned b = __float_as_uint(x);
  return (unsigned short)((b + 0x7FFFu + ((b >> 16) & 1u)) >> 16);
}
__device__ __forceinline__ float bf2f(unsigned short u) {
  return __uint_as_float(((unsigned)u) << 16);
}
// exact-ish 3-way split: x ~= bf(x0)+bf(x1)+bf(x2), residual ~2^-25|x|
__device__ __forceinline__ void bf3(float x, unsigned short& u0, unsigned short& u1,
                                    unsigned short& u2) {
  u0 = f2bf(x);
  float r = x - bf2f(u0);
  u1 = f2bf(r);
  r = r - bf2f(u1);
  u2 = f2bf(r);
}

// ---------------------------------------------------------------------------
// Kernel 0: one-shot bf16x3 decomposition of conf into the padded LDS image.
// ---------------------------------------------------------------------------
__global__ __launch_bounds__(256) void bf3_kernel(
    const float* __restrict__ conf, unsigned short* __restrict__ cbf) {
  const int g = blockIdx.x * 256 + threadIdx.x;   // one thread per 4 values
  const int pt = g >> 4;                          // point 0..BN-1
  const int k4 = (g & 15) << 2;
  float4 v = *(const float4*)(conf + (size_t)pt * 64 + k4);
  unsigned short x0, x1, x2, y0, y1, y2, z0, z1, z2, w0, w1, w2;
  bf3(v.x, x0, x1, x2);
  bf3(v.y, y0, y1, y2);
  bf3(v.z, z0, z1, z2);
  bf3(v.w, w0, w1, w2);
  unsigned short* dst = cbf + (size_t)pt * CSTRIDE + k4;
  *(bhalf*)&dst[0] = (bhalf){(short)x0, (short)y0, (short)z0, (short)w0};
  *(bhalf*)&dst[64] = (bhalf){(short)x1, (short)y1, (short)z1, (short)w1};
  *(bhalf*)&dst[128] = (bhalf){(short)x2, (short)y2, (short)z2, (short)w2};
}

// ---------------------------------------------------------------------------
// Kernel 1: fused MLP — e, logits, sq, nd.  512 blocks x 256 thr, 32 pts/block
// ---------------------------------------------------------------------------
__device__ __forceinline__ void gemm32x128(const float (*A)[64], const float* W,
                                           const float* bias, float (*O)[128], int tid) {
  const int pi = (tid >> 5) << 2;   // point quad
  const int ci = (tid & 31) << 2;   // col quad
  float acc[4][4] = {};
  for (int k0 = 0; k0 < 64; k0 += 4) {
    alignas(16) float av[4][4], wv[4][4];
#pragma unroll
    for (int r = 0; r < 4; ++r) *(float4*)av[r] = *(const float4*)&A[pi + r][k0];
#pragma unroll
    for (int kk = 0; kk < 4; ++kk) *(float4*)wv[kk] = *(const float4*)&W[(k0 + kk) * 128 + ci];
#pragma unroll
    for (int kk = 0; kk < 4; ++kk)
#pragma unroll
      for (int r = 0; r < 4; ++r)
#pragma unroll
        for (int c = 0; c < 4; ++c)
          acc[r][c] = fmaf(av[r][kk], wv[kk][c], acc[r][c]);
  }
#pragma unroll
  for (int r = 0; r < 4; ++r)
#pragma unroll
    for (int c = 0; c < 4; ++c)
      O[pi + r][ci + c] = fmaxf(acc[r][c] + bias[ci + c], 0.f);
}

__global__ __launch_bounds__(256) void mlp_kernel(
    const float* __restrict__ conf, const float* __restrict__ native,
    const float* __restrict__ We1, const float* __restrict__ be1,
    const float* __restrict__ We2, const float* __restrict__ be2,
    const float* __restrict__ We3, const float* __restrict__ be3,
    const float* __restrict__ Ws1, const float* __restrict__ bs1,
    const float* __restrict__ Ws2, const float* __restrict__ bs2,
    float* __restrict__ e_out, float* __restrict__ logits_out,
    float* __restrict__ sq_ws, float* __restrict__ nd_ws) {
  __shared__ __align__(16) float Wbuf[8192];       // 32 KB (We1 / We2 / Ws1)
  __shared__ __align__(16) float confs[32][64];    // 8 KB (later reused for h2)
  __shared__ __align__(16) float hbuf[32][128];    // 16 KB (g then h1)
  __shared__ float nat[64];
  __shared__ float b1s[128], b2s[64], w3s[64], bs1s[128], ws2s[768], bs2s[6];
  __shared__ float be3s;

  const int tid = threadIdx.x;
  const int blk = blockIdx.x;       // 0..511
  const int b = blk >> 7;           // 128 blocks per batch
  const int pbase = (blk & 127) * 32;
  const float* confb = conf + ((size_t)b * NPTS + pbase) * 64;

  for (int q = tid; q < 512; q += 256) {
    float4 v = *(const float4*)(confb + q * 4);
    *(float4*)&confs[q >> 4][(q & 15) << 2] = v;
  }
  if (tid < 64) nat[tid] = native[b * 64 + tid];
  if (tid < 128) b1s[tid] = be1[tid];
  if (tid < 64) b2s[tid] = be2[tid];
  if (tid < 64) w3s[tid] = We3[tid];
  if (tid < 128) bs1s[tid] = bs1[tid];
  for (int q = tid; q < 768; q += 256) ws2s[q] = Ws2[q];
  if (tid < 6) bs2s[tid] = bs2[tid];
  if (tid == 0) be3s = be3[0];
  for (int q = tid; q < 2048; q += 256)
    *(float4*)&Wbuf[q * 4] = *(const float4*)(Ws1 + q * 4);
  __syncthreads();

  // sq & nd — numpy-pairwise style: rounded products, 8 accumulators
  if (tid < 32) {
    float rs_[8], rn_[8];
#pragma unroll
    for (int u = 0; u < 8; ++u) {
      float c = confs[tid][u];
      rs_[u] = c * c;
      float d = c - nat[u];
      rn_[u] = d * d;
    }
    for (int d0 = 8; d0 < 64; d0 += 8) {
#pragma unroll
      for (int u = 0; u < 8; ++u) {
        float c = confs[tid][d0 + u];
        rs_[u] += c * c;
        float d = c - nat[d0 + u];
        rn_[u] += d * d;
      }
    }
    float s = ((rs_[0] + rs_[1]) + (rs_[2] + rs_[3])) + ((rs_[4] + rs_[5]) + (rs_[6] + rs_[7]));
    float n = ((rn_[0] + rn_[1]) + (rn_[2] + rn_[3])) + ((rn_[4] + rn_[5]) + (rn_[6] + rn_[7]));
    sq_ws[(size_t)b * NPTS + pbase + tid] = s;
    nd_ws[(size_t)b * NPTS + pbase + tid] = sqrtf(n);
  }

  gemm32x128(confs, Wbuf, bs1s, hbuf, tid);     // g = relu(conf @ Ws1 + bs1)
  __syncthreads();

  for (int q = tid; q < 2048; q += 256)         // reload Wbuf <- We1
    *(float4*)&Wbuf[q * 4] = *(const float4*)(We1 + q * 4);
  if (tid < 192) {
    int p = tid / 6, s = tid % 6;
    float acc = 0.f;
#pragma unroll 8
    for (int h = 0; h < 128; ++h)
      acc = fmaf(hbuf[p][h], ws2s[h * 6 + s], acc);
    logits_out[((size_t)b * NPTS + pbase + p) * 6 + s] = acc + bs2s[s];
  }
  __syncthreads();

  gemm32x128(confs, Wbuf, b1s, hbuf, tid);      // h1 = relu(conf @ We1 + be1)
  __syncthreads();

  for (int q = tid; q < 2048; q += 256)
    *(float4*)&Wbuf[q * 4] = *(const float4*)(We2 + q * 4);
  __syncthreads();

  // h2 = relu(h1 @ We2 + be2) -> confs
  if (tid < 128) {
    const int pi = (tid >> 4) << 2;
    const int ci = (tid & 15) << 2;
    float acc[4][4] = {};
    for (int k0 = 0; k0 < 128; k0 += 4) {
      alignas(16) float av[4][4], wv[4][4];
#pragma unroll
      for (int r = 0; r < 4; ++r) *(float4*)av[r] = *(const float4*)&hbuf[pi + r][k0];
#pragma unroll
      for (int kk = 0; kk < 4; ++kk) *(float4*)wv[kk] = *(const float4*)&Wbuf[(k0 + kk) * 64 + ci];
#pragma unroll
      for (int kk = 0; kk < 4; ++kk)
#pragma unroll
        for (int r = 0; r < 4; ++r)
#pragma unroll
          for (int c = 0; c < 4; ++c)
            acc[r][c] = fmaf(av[r][kk], wv[kk][c], acc[r][c]);
    }
#pragma unroll
    for (int r = 0; r < 4; ++r)
#pragma unroll
      for (int c = 0; c < 4; ++c)
        confs[pi + r][ci + c] = fmaxf(acc[r][c] + b2s[ci + c], 0.f);
  }
  __syncthreads();

  if (tid < 32) {                               // e = h2 @ We3 + be3
    float acc = 0.f;
#pragma unroll
    for (int k = 0; k < 64; ++k)
      acc = fmaf(confs[tid][k], w3s[k], acc);
    e_out[(size_t)b * NPTS + pbase + tid] = acc + be3s;
  }
}

// ---------------------------------------------------------------------------
// Distance pass (split-j), bf16x3 MFMA, d2-keyed, queued top-10 insert.
// Queue: branchless nibble FIFO of passing candidate ids (OR-neutral on fail);
// drain bubbles only K = wave-max(cnt) times per tile instead of wave-any per
// candidate step. FIFO preserves ascending-j order -> selection bit-identical.
// ---------------------------------------------------------------------------
__device__ __forceinline__ bfrag ldfrag(const unsigned short* p) {
  bhalf lo = *(const bhalf*)p;        // 8B aligned
  bhalf hi = *(const bhalf*)(p + 4);  // +8B
  return __builtin_shufflevector(lo, hi, 0, 1, 2, 3, 4, 5, 6, 7);
}

__global__ __launch_bounds__(256, 1) void topk_part_kernel(
    const unsigned short* __restrict__ cbf, const float* __restrict__ sq_ws,
    float* __restrict__ topd, unsigned short* __restrict__ topi) {
  __shared__ __align__(16) unsigned short AU[64 * CSTRIDE];  // 26112 B (A tile -> Ds -> mrgD)
  __shared__ __align__(16) unsigned short BU[64 * CSTRIDE];  // 26112 B (B tile -> mrgI)
  __shared__ float sqa[64], sqjs[64];

  const int tid = threadIdx.x;
  const int b = blockIdx.z;
  const int i0 = blockIdx.x * 64;
  const int jbase = blockIdx.y * (NPTS / JS);
  const unsigned short* cbfb = cbf + (size_t)b * NPTS * CSTRIDE;
  const float* sqb = sq_ws + (size_t)b * NPTS;
  float* Dsf = (float*)AU;   // [64][68] cd2 tile (17408 B <= 26112)

  {
    const float4* src = (const float4*)(cbfb + (size_t)i0 * CSTRIDE);
    float4* dst = (float4*)AU;
    for (int q = tid; q < 1632; q += 256) dst[q] = src[q];
  }
  if (tid < 64) sqa[tid] = sqb[i0 + tid];
  __syncthreads();

  const int l = tid & 63, w = tid >> 6;   // lane, wave (wave w owns rows 16w..16w+15)
  const int cl = l & 15, g = l >> 4;

  // A-fragments: 6 (level p, k-half h), resident for the whole block
  const int abase = (16 * w + cl) * CSTRIDE + g * 8;
  const bfrag a00 = ldfrag(&AU[abase + 0]);
  const bfrag a01 = ldfrag(&AU[abase + 32]);
  const bfrag a10 = ldfrag(&AU[abase + 64]);
  const bfrag a11 = ldfrag(&AU[abase + 96]);
  const bfrag a20 = ldfrag(&AU[abase + 128]);
  const bfrag a21 = ldfrag(&AU[abase + 160]);
  float sqar[4];
#pragma unroll
  for (int e = 0; e < 4; ++e) sqar[e] = sqa[16 * w + 4 * g + e];

  const int irow = tid >> 2, q4 = tid & 3;   // insert-phase mapping (4 thr/row)

  unsigned long long lk[10];
#pragma unroll
  for (int k = 0; k < 10; ++k) lk[k] = 0x7F7FFFFF7FFFFFFFULL;  // (FLT_MAX, INT_MAX)
  float thrf = FLT_MAX;

  for (int jt = 0; jt < NPTS / JS / 64; ++jt) {   // 16 tiles of 64
    const int j0 = jbase + jt * 64;
    {
      const float4* src = (const float4*)(cbfb + (size_t)j0 * CSTRIDE);
      float4* dst = (float4*)BU;
      for (int q = tid; q < 1632; q += 256) dst[q] = src[q];
    }
    if (tid < 64) sqjs[tid] = sqb[j0 + tid];
    __syncthreads();   // BU/sqjs ready; prev Ds fully consumed by insert phase

    // ---- MFMA: 4 col-subtiles of 16, 12 k-steps each (6 B-frags, 2x reuse)
#pragma unroll
    for (int c = 0; c < 4; ++c) {
      const unsigned short* bp = &BU[(16 * c + cl) * CSTRIDE + g * 8];
      const bfrag b00 = ldfrag(bp + 0);
      const bfrag b01 = ldfrag(bp + 32);
      const bfrag b10 = ldfrag(bp + 64);
      const bfrag b11 = ldfrag(bp + 96);
      const bfrag b20 = ldfrag(bp + 128);
      const bfrag b21 = ldfrag(bp + 160);
      f32x4 acc = {0.f, 0.f, 0.f, 0.f};
      acc = MFMA(a00, b00, acc); acc = MFMA(a01, b01, acc);   // A0*B0
      acc = MFMA(a00, b10, acc); acc = MFMA(a01, b11, acc);   // A0*B1
      acc = MFMA(a10, b00, acc); acc = MFMA(a11, b01, acc);   // A1*B0
      acc = MFMA(a00, b20, acc); acc = MFMA(a01, b21, acc);   // A0*B2
      acc = MFMA(a10, b10, acc); acc = MFMA(a11, b11, acc);   // A1*B1
      acc = MFMA(a20, b00, acc); acc = MFMA(a21, b01, acc);   // A2*B0
      const int col = 16 * c + cl;
      const float sj = sqjs[col];
#pragma unroll
      for (int e = 0; e < 4; ++e) {
        const int rw = 16 * w + 4 * g + e;
        float d2 = fmaf(-2.f, acc[e], sqar[e] + sj);
        Dsf[rw * 68 + col] = fmaxf(d2, EPSC);   // cd2 (sqrt deferred)
      }
    }
    __syncthreads();   // Ds ready; BU consumed (next copy may overwrite)

    // ---- queue phase: branchless nibble FIFO of passing candidate ids
    unsigned long long pend = 0;
    int cnt = 0;
#pragma unroll
    for (int cc = 0; cc < 4; ++cc) {
      float4 v = *(const float4*)&Dsf[irow * 68 + q4 * 16 + cc * 4];
#pragma unroll
      for (int e = 0; e < 4; ++e) {
        float d = (e == 0) ? v.x : (e == 1) ? v.y : (e == 2) ? v.z : v.w;
        int m = (d <= thrf) ? 1 : 0;
        // fail writes 0 (OR-neutral at this slot; later passer ORs its id in)
        pend |= ((unsigned long long)(m ? (cc * 4 + e) : 0)) << (4 * cnt);
        cnt += m;
      }
    }

    // ---- drain: K = wave-max(cnt) bubbles, FIFO (ascending j preserved)
    int K = cnt;
#pragma unroll
    for (int off = 32; off >= 1; off >>= 1) K = max(K, __shfl_xor(K, off, 64));
    for (int k = 0; k < K; ++k) {
      const bool act = (k < cnt);
      const int id = (int)(pend & 15);
      pend >>= 4;
      const int col = q4 * 16 + id;
      const float d = Dsf[irow * 68 + col];   // harmless read for inactive lanes
      if (act) {
        unsigned long long cur =
            (((unsigned long long)__float_as_uint(d)) << 32) |
            (unsigned long long)(unsigned)(j0 + col);
        if (cur < lk[9]) {
#pragma unroll
          for (int kk = 0; kk < 10; ++kk) {
            bool lt = cur < lk[kk];
            unsigned long long mn = lt ? cur : lk[kk];
            cur = lt ? lk[kk] : cur;
            lk[kk] = mn;
          }
        }
      }
    }

    // refresh row-wide filter bound: min of the 4 siblings' 10th cd2
    float t = __uint_as_float((unsigned)(lk[9] >> 32));
    t = fminf(t, __shfl_xor(t, 1, 4));
    t = fminf(t, __shfl_xor(t, 2, 4));
    thrf = t;
  }
  __syncthreads();

  // merge 4 per-thread sorted lists per row -> chunk top-10 (cd2), write to ws
  float* mrgD = (float*)AU;   // 2560 floats
  int* mrgI = (int*)BU;       // 2560 ints
  {
#pragma unroll
    for (int k = 0; k < 10; ++k) {
      mrgD[irow * 40 + q4 * 10 + k] = __uint_as_float((unsigned)(lk[k] >> 32));
      mrgI[irow * 40 + q4 * 10 + k] = (int)(unsigned)(lk[k] & 0xFFFFFFFFu);
    }
  }
  __syncthreads();
  if (tid < 64) {
    const int base = tid * 40;
    int h0 = 0, h1 = 0, h2 = 0, h3 = 0;
    const size_t obase = (((size_t)b * NPTS + i0 + tid) * JS + blockIdx.y) * 10;
    for (int k = 0; k < 10; ++k) {
      float bd = FLT_MAX; int bi = 0x7fffffff; int bl = -1;
      { float d = mrgD[base + h0];      int ii = mrgI[base + h0];      if (dless(d, ii, bd, bi)) { bd = d; bi = ii; bl = 0; } }
      { float d = mrgD[base + 10 + h1]; int ii = mrgI[base + 10 + h1]; if (dless(d, ii, bd, bi)) { bd = d; bi = ii; bl = 1; } }
      { float d = mrgD[base + 20 + h2]; int ii = mrgI[base + 20 + h2]; if (dless(d, ii, bd, bi)) { bd = d; bi = ii; bl = 2; } }
      { float d = mrgD[base + 30 + h3]; int ii = mrgI[base + 30 + h3]; if (dless(d, ii, bd, bi)) { bd = d; bi = ii; bl = 3; } }
      h0 += (bl == 0); h1 += (bl == 1); h2 += (bl == 2); h3 += (bl == 3);
      topd[obase + k] = bd;                    // cd2
      topi[obase + k] = (unsigned short)bi;
    }
  }
}

// ---------------------------------------------------------------------------
// Merge JS chunk top-10s per row -> r, is_basin, depth, width.
// Inputs are cd2; mask cd2 < r2 == d < r; width uses sqrt(cd2) (= ref d bits).
// ---------------------------------------------------------------------------
__global__ __launch_bounds__(256) void topk_merge_kernel(
    const float* __restrict__ topd, const unsigned short* __restrict__ topi,
    const float* __restrict__ e_in, float* __restrict__ basin_out,
    float* __restrict__ depth_out, float* __restrict__ width_out) {
  const int g = blockIdx.x * 256 + threadIdx.x;   // 0..16383
  const int b = g >> 12;
  const float* eb = e_in + (size_t)b * NPTS;
  const float* td = topd + (size_t)g * (JS * 10);
  const unsigned short* ti = topi + (size_t)g * (JS * 10);
  const float e_i = eb[g & (NPTS - 1)];
  int h0 = 0, h1 = 0, h2 = 0, h3 = 0;
  float dk[10];
  int ik[10];
#pragma unroll
  for (int k = 0; k < 10; ++k) {
    float bd = FLT_MAX; int bi = 0x7fffffff; int bl = -1;
    { float d = td[h0];      int ii = ti[h0];      if (dless(d, ii, bd, bi)) { bd = d; bi = ii; bl = 0; } }
    { float d = td[10 + h1]; int ii = ti[10 + h1]; if (dless(d, ii, bd, bi)) { bd = d; bi = ii; bl = 1; } }
    { float d = td[20 + h2]; int ii = ti[20 + h2]; if (dless(d, ii, bd, bi)) { bd = d; bi = ii; bl = 2; } }
    { float d = td[30 + h3]; int ii = ti[30 + h3]; if (dless(d, ii, bd, bi)) { bd = d; bi = ii; bl = 3; } }
    h0 += (bl == 0); h1 += (bl == 1); h2 += (bl == 2); h3 += (bl == 3);
    dk[k] = bd;
    ik[k] = bi;
  }
  const float r2 = dk[9];
  bool basin = true;
  float mx = -FLT_MAX, sum = 0.f, cnt = 0.f;
#pragma unroll
  for (int k = 0; k < 10; ++k) {
    float ev = eb[ik[k]];
    if (dk[k] < r2) { mx = fmaxf(mx, ev); sum += sqrtf(dk[k]); cnt += 1.f; }
    if (k >= 1) basin = basin && (e_i <= ev);
  }
  basin_out[g] = basin ? 1.f : 0.f;
  depth_out[g] = mx - e_i;
  width_out[g] = sum / cnt;
}

// ---------------------------------------------------------------------------
// Kernel 3: rank by nd (stable), scatter e into sorted order.
// ---------------------------------------------------------------------------
__global__ __launch_bounds__(256) void rank_kernel(
    const float* __restrict__ nd_ws, const float* __restrict__ e_in,
    float* __restrict__ se_ws) {
  __shared__ __align__(16) float ndl[4096];
  const int tid = threadIdx.x;
  const int b = blockIdx.y;
  const int i0 = blockIdx.x * 64;
  const float* ndb = nd_ws + (size_t)b * NPTS;
  for (int q = tid; q < 1024; q += 256)
    *(float4*)&ndl[q * 4] = *(const float4*)(ndb + q * 4);
  __syncthreads();
  const int i = i0 + (tid >> 2);
  const int qp = tid & 3;
  const float ndi = ndl[i];
  int rank = 0;
  for (int j = qp * 1024; j < qp * 1024 + 1024; j += 4) {
    float4 v = *(const float4*)&ndl[j];
    rank += (v.x < ndi) || (v.x == ndi && (j + 0) < i);
    rank += (v.y < ndi) || (v.y == ndi && (j + 1) < i);
    rank += (v.z < ndi) || (v.z == ndi && (j + 2) < i);
    rank += (v.w < ndi) || (v.w == ndi && (j + 3) < i);
  }
  rank += __shfl_xor(rank, 1, 4);
  rank += __shfl_xor(rank, 2, 4);
  if (qp == 0) se_ws[(size_t)b * NPTS + rank] = e_in[(size_t)b * NPTS + i];
}

// ---------------------------------------------------------------------------
// Kernel 4: per-batch scalar metrics
// ---------------------------------------------------------------------------
__device__ __forceinline__ float block_sum(float v, float* red, int tid) {
  red[tid] = v;
  __syncthreads();
  for (int s = 512; s > 0; s >>= 1) {
    if (tid < s) red[tid] += red[tid + s];
    __syncthreads();
  }
  float r = red[0];
  __syncthreads();
  return r;
}
__device__ __forceinline__ float block_max(float v, float* red, int tid) {
  red[tid] = v;
  __syncthreads();
  for (int s = 512; s > 0; s >>= 1) {
    if (tid < s) red[tid] = fmaxf(red[tid], red[tid + s]);
    __syncthreads();
  }
  float r = red[0];
  __syncthreads();
  return r;
}

__global__ __launch_bounds__(1024) void metrics_kernel(
    const float* __restrict__ e_in, const float* __restrict__ nd_ws,
    const float* __restrict__ se_ws, float* __restrict__ metrics_out) {
  __shared__ __align__(16) float el[4096], ndl[4096], sel[4096];
  __shared__ float red[1024];
  __shared__ int redi[1024];
  const int tid = threadIdx.x;
  const int b = blockIdx.x;
  const float* eb = e_in + (size_t)b * NPTS;
  const float* ndb = nd_ws + (size_t)b * NPTS;
  const float* seb = se_ws + (size_t)b * NPTS;
  *(float4*)&el[tid * 4] = *(const float4*)(eb + tid * 4);
  *(float4*)&ndl[tid * 4] = *(const float4*)(ndb + tid * 4);
  *(float4*)&sel[tid * 4] = *(const float4*)(seb + tid * 4);
  __syncthreads();

  float pe = 0.f, pnd = 0.f;
  for (int p = tid; p < 4096; p += 1024) { pe += el[p]; pnd += ndl[p]; }
  float me = block_sum(pe, red, tid) / 4096.f;
  float mnd = block_sum(pnd, red, tid) / 4096.f;

  float sxx = 0.f, syy = 0.f, sxy = 0.f, mx = -FLT_MAX;
  float bestv = FLT_MAX;
  int besti = 0x7fffffff;
  for (int p = tid; p < 4096; p += 1024) {
    float de = el[p] - me, dn = ndl[p] - mnd;
    syy += de * de;
    sxx += dn * dn;
    sxy += de * dn;
    mx = fmaxf(mx, el[p]);
    if (ndl[p] < bestv || (ndl[p] == bestv && p < besti)) { bestv = ndl[p]; besti = p; }
  }
  float fr = 0.f;
  for (int p = tid; p < 4095; p += 1024) fr += (sel[p + 1] > sel[p]) ? 1.f : 0.f;

  sxx = block_sum(sxx, red, tid);
  syy = block_sum(syy, red, tid);
  sxy = block_sum(sxy, red, tid);
  mx = block_max(mx, red, tid);
  fr = block_sum(fr, red, tid);

  red[tid] = bestv;
  redi[tid] = besti;
  __syncthreads();
  for (int s = 512; s > 0; s >>= 1) {
    if (tid < s) {
      float ov = red[tid + s];
      int oi = redi[tid + s];
      if (ov < red[tid] || (ov == red[tid] && oi < redi[tid])) { red[tid] = ov; redi[tid] = oi; }
    }
    __syncthreads();
  }
  if (tid == 0) {
    float ne = el[redi[0]];
    metrics_out[b * 5 + 0] = mx - ne;
    metrics_out[b * 5 + 1] = sqrtf(syy / 4095.f);
    metrics_out[b * 5 + 2] = sxy / sqrtf(sxx * syy);
    metrics_out[b * 5 + 3] = fr / 4095.f;
    metrics_out[b * 5 + 4] = ne;
  }
}

// ---------------------------------------------------------------------------
extern "C" void kernel_launch(void* const* d_in, const int* in_sizes, int n_in,
                              void* d_out, int out_size, void* d_ws, size_t ws_size,
                              hipStream_t stream) {
  const float* conf = (const float*)d_in[0];
  const float* native = (const float*)d_in[1];
  const float* We1 = (const float*)d_in[2];
  const float* be1 = (const float*)d_in[3];
  const float* We2 = (const float*)d_in[4];
  const float* be2 = (const float*)d_in[5];
  const float* We3 = (const float*)d_in[6];
  const float* be3 = (const float*)d_in[7];
  const float* Ws1 = (const float*)d_in[8];
  const float* bs1 = (const float*)d_in[9];
  const float* Ws2 = (const float*)d_in[10];
  const float* bs2 = (const float*)d_in[11];

  float* out = (float*)d_out;
  float* e_out = out;                 // [0, 16384)
  float* basin_out = out + BN;        // [16384, 32768)
  float* depth_out = out + 2 * BN;    // [32768, 49152)
  float* width_out = out + 3 * BN;    // [49152, 65536)
  float* logits_out = out + 4 * BN;   // [65536, 163840)
  float* metrics_out = out + 10 * BN; // [163840, 163860)

  // ws layout (floats): sq | nd | se | topd(40BN) | topi(20BN) | cbf(102BN)
  float* wsf = (float*)d_ws;
  float* sq_ws = wsf;
  float* nd_ws = wsf + BN;
  float* se_ws = wsf + 2 * (size_t)BN;
  float* topd = wsf + 3 * (size_t)BN;
  unsigned short* topi = (unsigned short*)(wsf + 43 * (size_t)BN);
  unsigned short* cbf = (unsigned short*)(wsf + 63 * (size_t)BN);

  bf3_kernel<<<dim3(BN * 16 / 256), dim3(256), 0, stream>>>(conf, cbf);
  mlp_kernel<<<dim3(512), dim3(256), 0, stream>>>(
      conf, native, We1, be1, We2, be2, We3, be3, Ws1, bs1, Ws2, bs2,
      e_out, logits_out, sq_ws, nd_ws);
  topk_part_kernel<<<dim3(64, JS, NBATCH), dim3(256), 0, stream>>>(
      cbf, sq_ws, topd, topi);
  topk_merge_kernel<<<dim3(BN / 256), dim3(256), 0, stream>>>(
      topd, topi, e_out, basin_out, depth_out, width_out);
  rank_kernel<<<dim3(64, NBATCH), dim3(256), 0, stream>>>(nd_ws, e_out, se_ws);
  metrics_kernel<<<dim3(NBATCH), dim3(1024), 0, stream>>>(e_out, nd_ws, se_ws, metrics_out);
}